// Round 9
// baseline (450.457 us; speedup 1.0000x reference)
//
#include <hip/hip_runtime.h>

// EnhancedGNN on MI355X.
// R12: algebraic fusion for hidden layers: agg(h W) = (agg h) W. mmB deleted;
//      per layer: k_bnapply (hs = BN(G)*dinv + hs_res, streaming ~10us) then
//      k_aggmm (agg64-style gather of hs + per-wave 64x64 matvec from LDS-staged
//      W, one barrier). Removes 2x ~40us mm + 2x 25.6MB T writes. bnmmout uses
//      rd=sqrt(deg+1) to recover unscaled residual. Layer 1 + output unchanged.

#define NN 100000
#define NE 1200000
#define NBATCH 64
#define IND 128
#define HID 64
#define EPSF 1e-5f
#define NBUCK 782   // ceil(100000/128)
#define NPB 128     // nodes per bucket; bucket(d) = d >> 7

// ---------------- graph prep: bucket histogram ----------------
__global__ void k_ehist(const int* __restrict__ dst, int* __restrict__ gbh) {
  __shared__ int lh[NBUCK];
  int tid = threadIdx.x;
  for (int i = tid; i < NBUCK; i += 256) lh[i] = 0;
  __syncthreads();
  int base = blockIdx.x * 4096;
#pragma unroll
  for (int j = 0; j < 16; j++) {
    int e = base + j * 256 + tid;
    if (e < NE) atomicAdd(&lh[dst[e] >> 7], 1);
  }
  __syncthreads();
  for (int i = tid; i < NBUCK; i += 256) {
    int v = lh[i];
    if (v) atomicAdd(&gbh[i], v);
  }
}

// exclusive scan of 782 bucket counts -> bbase[0..NBUCK], bcur=bbase
__global__ void k_escan(const int* __restrict__ gbh, int* __restrict__ bbase,
                        int* __restrict__ bcur) {
  __shared__ int a[256];
  int tid = threadIdx.x;
  int loc[4];
  int tsum = 0;
  for (int j = 0; j < 4; j++) {
    int idx = tid * 4 + j;
    int v = (idx < NBUCK) ? gbh[idx] : 0;
    loc[j] = tsum;
    tsum += v;
  }
  a[tid] = tsum;
  __syncthreads();
  for (int off = 1; off < 256; off <<= 1) {
    int v = (tid >= off) ? a[tid - off] : 0;
    __syncthreads();
    a[tid] += v;
    __syncthreads();
  }
  int excl = a[tid] - tsum;
  for (int j = 0; j < 4; j++) {
    int idx = tid * 4 + j;
    if (idx < NBUCK) {
      int v = excl + loc[j];
      bbase[idx] = v;
      bcur[idx] = v;
    }
  }
  if (tid == 255) bbase[NBUCK] = a[255];
}

// scatter (src,dst) pairs into bucket-contiguous ebuf; LDS-aggregated cursor grabs
__global__ void k_escatter(const int* __restrict__ src, const int* __restrict__ dst,
                           int* __restrict__ bcur, unsigned long long* __restrict__ ebuf) {
  __shared__ int lh[NBUCK];
  __shared__ int lbase[NBUCK];
  int tid = threadIdx.x;
  for (int i = tid; i < NBUCK; i += 256) lh[i] = 0;
  __syncthreads();
  int base = blockIdx.x * 4096;
  int sv[16], dv[16], rk[16];
#pragma unroll
  for (int j = 0; j < 16; j++) {
    int e = base + j * 256 + tid;
    if (e < NE) {
      sv[j] = src[e];
      dv[j] = dst[e];
      rk[j] = atomicAdd(&lh[dv[j] >> 7], 1);
    } else {
      dv[j] = -1;
    }
  }
  __syncthreads();
  for (int i = tid; i < NBUCK; i += 256) {
    int v = lh[i];
    lbase[i] = v ? atomicAdd(&bcur[i], v) : 0;
  }
  __syncthreads();
#pragma unroll
  for (int j = 0; j < 16; j++) {
    if (dv[j] >= 0) {
      int b = dv[j] >> 7;
      ebuf[lbase[b] + rk[j]] =
          (unsigned long long)(unsigned)sv[j] | ((unsigned long long)(unsigned)dv[j] << 32);
    }
  }
}

// one block per bucket: local hist -> deg/dinv/rd, local scan -> rowp, fill -> col
__global__ void k_bucket_csr(const unsigned long long* __restrict__ ebuf,
                             const int* __restrict__ bbase, int* __restrict__ deg,
                             int* __restrict__ rowp, float* __restrict__ dinv,
                             float* __restrict__ rd, int* __restrict__ col) {
  __shared__ int ldeg[NPB];
  __shared__ int lcur[NPB];
  __shared__ int sred[NPB];
  int b = blockIdx.x, tid = threadIdx.x;
  int nbase = b * NPB;
  int e0 = bbase[b], e1 = bbase[b + 1];
  if (tid < NPB) ldeg[tid] = 0;
  __syncthreads();
  for (int e = e0 + tid; e < e1; e += 256) {
    int d = (int)(ebuf[e] >> 32) - nbase;
    atomicAdd(&ldeg[d], 1);
  }
  __syncthreads();
  if (tid < NPB) sred[tid] = ldeg[tid];
  __syncthreads();
  for (int off = 1; off < NPB; off <<= 1) {
    int v = 0;
    if (tid < NPB && tid >= off) v = sred[tid - off];
    __syncthreads();
    if (tid < NPB) sred[tid] += v;
    __syncthreads();
  }
  if (tid < NPB) {
    int excl = sred[tid] - ldeg[tid];
    lcur[tid] = excl;
    int gn = nbase + tid;
    if (gn < NN) {
      int dg = ldeg[tid];
      deg[gn] = dg;
      rowp[gn] = e0 + excl;
      dinv[gn] = rsqrtf((float)dg + 1.0f);
      rd[gn] = sqrtf((float)dg + 1.0f);
    }
  }
  __syncthreads();
  for (int e = e0 + tid; e < e1; e += 256) {
    unsigned long long p = ebuf[e];
    int s = (int)(unsigned)p;
    int d = (int)(p >> 32) - nbase;
    int r = atomicAdd(&lcur[d], 1);
    col[e0 + r] = s;
  }
}

// ---------------- mm A: X[nrows,128] @ W[128,64] -> T * dinv[row] --------------
// 64 rows/block, 4 threads/row (col-quarter per wave, readfirstlane -> s_load W).
__global__ __launch_bounds__(256) void k_mmA(const float* __restrict__ X,
                                             const float* __restrict__ W,
                                             const float* __restrict__ dinv,
                                             float* __restrict__ T, int nrows) {
  __shared__ float xs[64 * 65];
  int tid = threadIdx.x;
  int rbase = blockIdx.x * 64;
  int q4 = __builtin_amdgcn_readfirstlane(tid >> 6);  // wave-uniform col quarter
  int r = tid & 63;
  int r65 = r * 65;
  float4 acc[4];
#pragma unroll
  for (int j = 0; j < 4; j++) acc[j] = {0.f, 0.f, 0.f, 0.f};

  for (int ch = 0; ch < 2; ch++) {
#pragma unroll
    for (int i = 0; i < 4; i++) {
      int f = i * 256 + tid;
      int rr = f >> 4, kq = f & 15;
      int gr = rbase + rr;
      int grc = gr < nrows ? gr : nrows - 1;
      float4 v = *(const float4*)(X + (size_t)grc * 128 + ch * 64 + 4 * kq);
      float* p = xs + rr * 65 + 4 * kq;
      p[0] = v.x; p[1] = v.y; p[2] = v.z; p[3] = v.w;
    }
    __syncthreads();
    const float* Wb = W + ch * 64 * 64 + q4 * 16;
#pragma unroll 4
    for (int k = 0; k < 64; k++) {
      float xk = xs[r65 + k];
      const float4* wr = (const float4*)(Wb + (size_t)k * 64);
#pragma unroll
      for (int j = 0; j < 4; j++) {
        float4 wv = wr[j];
        acc[j].x = fmaf(xk, wv.x, acc[j].x);
        acc[j].y = fmaf(xk, wv.y, acc[j].y);
        acc[j].z = fmaf(xk, wv.z, acc[j].z);
        acc[j].w = fmaf(xk, wv.w, acc[j].w);
      }
    }
    if (ch == 0) __syncthreads();
  }

  int row = rbase + r;
  if (row < nrows) {
    float dv = dinv[row];
    float4* t4 = (float4*)(T + (size_t)row * 64 + q4 * 16);
#pragma unroll
    for (int j = 0; j < 4; j++) {
      float4 o = acc[j];
      o.x *= dv; o.y *= dv; o.z *= dv; o.w *= dv;
      t4[j] = o;
    }
  }
}

// ---------------- aggregation (HID=64): wave/node, 16 edges in flight --------------
// T is pre-scaled by dinv[row]: o = di*(sum T'[src] + T'[node]) + bias
__global__ void k_agg64(const float* __restrict__ T, const int* __restrict__ row_start,
                        const int* __restrict__ cnt, const int* __restrict__ col,
                        const float* __restrict__ dinv, const float* __restrict__ bias,
                        float* __restrict__ G, int relu) {
  int lane = threadIdx.x & 63;
  int wv = threadIdx.x >> 6;
  int node = blockIdx.x * 4 + wv;
  if (node >= NN) return;
  int grp = lane >> 4;
  int q = lane & 15;
  int s = row_start[node];
  int c = cnt[node];
  float4 acc = {0.f, 0.f, 0.f, 0.f};
  for (int i = 0; i < c; i += 16) {
    int j0 = i + grp, j1 = j0 + 4, j2 = j0 + 8, j3 = j0 + 12;
    int s0 = col[s + (j0 < c ? j0 : 0)];
    int s1 = col[s + (j1 < c ? j1 : 0)];
    int s2 = col[s + (j2 < c ? j2 : 0)];
    int s3 = col[s + (j3 < c ? j3 : 0)];
    float4 t0 = ((const float4*)(T + (size_t)s0 * 64))[q];
    float4 t1 = ((const float4*)(T + (size_t)s1 * 64))[q];
    float4 t2 = ((const float4*)(T + (size_t)s2 * 64))[q];
    float4 t3 = ((const float4*)(T + (size_t)s3 * 64))[q];
    float w0 = j0 < c ? 1.f : 0.f;
    float w1 = j1 < c ? 1.f : 0.f;
    float w2 = j2 < c ? 1.f : 0.f;
    float w3 = j3 < c ? 1.f : 0.f;
    acc.x = fmaf(w0, t0.x, acc.x); acc.y = fmaf(w0, t0.y, acc.y);
    acc.z = fmaf(w0, t0.z, acc.z); acc.w = fmaf(w0, t0.w, acc.w);
    acc.x = fmaf(w1, t1.x, acc.x); acc.y = fmaf(w1, t1.y, acc.y);
    acc.z = fmaf(w1, t1.z, acc.z); acc.w = fmaf(w1, t1.w, acc.w);
    acc.x = fmaf(w2, t2.x, acc.x); acc.y = fmaf(w2, t2.y, acc.y);
    acc.z = fmaf(w2, t2.z, acc.z); acc.w = fmaf(w2, t2.w, acc.w);
    acc.x = fmaf(w3, t3.x, acc.x); acc.y = fmaf(w3, t3.y, acc.y);
    acc.z = fmaf(w3, t3.z, acc.z); acc.w = fmaf(w3, t3.w, acc.w);
  }
  acc.x += __shfl_xor(acc.x, 16, 64);
  acc.y += __shfl_xor(acc.y, 16, 64);
  acc.z += __shfl_xor(acc.z, 16, 64);
  acc.w += __shfl_xor(acc.w, 16, 64);
  acc.x += __shfl_xor(acc.x, 32, 64);
  acc.y += __shfl_xor(acc.y, 32, 64);
  acc.z += __shfl_xor(acc.z, 32, 64);
  acc.w += __shfl_xor(acc.w, 32, 64);
  if (grp == 0) {
    float di = dinv[node];
    float4 ts = ((const float4*)(T + (size_t)node * 64))[q];
    float4 bs = ((const float4*)bias)[q];
    float4 o;
    o.x = (acc.x + ts.x) * di + bs.x;
    o.y = (acc.y + ts.y) * di + bs.y;
    o.z = (acc.z + ts.z) * di + bs.z;
    o.w = (acc.w + ts.w) * di + bs.w;
    if (relu) {
      o.x = fmaxf(o.x, 0.f);
      o.y = fmaxf(o.y, 0.f);
      o.z = fmaxf(o.z, 0.f);
      o.w = fmaxf(o.w, 0.f);
    }
    ((float4*)(G + (size_t)node * 64))[q] = o;
  }
}

// ------- bnapply: Hs[r] = BN(G[r]) * dinv[r] (+ resS[r], already scaled) -------
__global__ __launch_bounds__(256) void k_bnapply(const float* __restrict__ G,
                                                 const double* __restrict__ st,
                                                 const float* __restrict__ gamma,
                                                 const float* __restrict__ beta,
                                                 const float* __restrict__ resS,
                                                 const float* __restrict__ dinv,
                                                 float* __restrict__ Hs) {
  __shared__ float scl[128];
  int tid = threadIdx.x;
  if (tid < 64) {
    double m = st[tid] / (double)NN;
    double var = st[64 + tid] / (double)NN - m * m;
    float scale = gamma[tid] * rsqrtf((float)var + EPSF);
    scl[tid] = scale;
    scl[64 + tid] = beta[tid] - (float)m * scale;
  }
  __syncthreads();
  int idx = blockIdx.x * 256 + tid;   // float4 index over NN*16
  if (idx >= NN * 16) return;
  int r = idx >> 4, kq = idx & 15;
  float4 v = ((const float4*)G)[idx];
  float4 s = ((const float4*)scl)[kq];
  float4 sh = ((const float4*)(scl + 64))[kq];
  float di = dinv[r];
  v.x = (v.x * s.x + sh.x) * di;
  v.y = (v.y * s.y + sh.y) * di;
  v.z = (v.z * s.z + sh.z) * di;
  v.w = (v.w * s.w + sh.w) * di;
  if (resS != nullptr) {
    float4 rr = ((const float4*)resS)[idx];
    v.x += rr.x; v.y += rr.y; v.z += rr.z; v.w += rr.w;
  }
  ((float4*)Hs)[idx] = v;
}

// ------- aggmm: G = relu((agg Hs) @ W + bias). Gather like agg64, then per-wave
// 64x64 matvec from LDS-staged W (lane j owns output col j). One barrier. -------
__global__ __launch_bounds__(256) void k_aggmm(const float* __restrict__ Hs,
                                               const int* __restrict__ row_start,
                                               const int* __restrict__ cnt,
                                               const int* __restrict__ col,
                                               const float* __restrict__ dinv,
                                               const float* __restrict__ bias,
                                               const float* __restrict__ W,
                                               float* __restrict__ G) {
  __shared__ float Wl[64 * 64];
  __shared__ float vL[4][64];
  int tid = threadIdx.x;
#pragma unroll
  for (int i = 0; i < 4; i++)
    ((float4*)Wl)[i * 256 + tid] = ((const float4*)W)[i * 256 + tid];

  int lane = tid & 63;
  int wv = tid >> 6;
  int node = blockIdx.x * 4 + wv;   // grid = NN/4 exactly
  int grp = lane >> 4;
  int q = lane & 15;
  int s = row_start[node];
  int c = cnt[node];
  float4 acc = {0.f, 0.f, 0.f, 0.f};
  for (int i = 0; i < c; i += 16) {
    int j0 = i + grp, j1 = j0 + 4, j2 = j0 + 8, j3 = j0 + 12;
    int s0 = col[s + (j0 < c ? j0 : 0)];
    int s1 = col[s + (j1 < c ? j1 : 0)];
    int s2 = col[s + (j2 < c ? j2 : 0)];
    int s3 = col[s + (j3 < c ? j3 : 0)];
    float4 t0 = ((const float4*)(Hs + (size_t)s0 * 64))[q];
    float4 t1 = ((const float4*)(Hs + (size_t)s1 * 64))[q];
    float4 t2 = ((const float4*)(Hs + (size_t)s2 * 64))[q];
    float4 t3 = ((const float4*)(Hs + (size_t)s3 * 64))[q];
    float w0 = j0 < c ? 1.f : 0.f;
    float w1 = j1 < c ? 1.f : 0.f;
    float w2 = j2 < c ? 1.f : 0.f;
    float w3 = j3 < c ? 1.f : 0.f;
    acc.x = fmaf(w0, t0.x, acc.x); acc.y = fmaf(w0, t0.y, acc.y);
    acc.z = fmaf(w0, t0.z, acc.z); acc.w = fmaf(w0, t0.w, acc.w);
    acc.x = fmaf(w1, t1.x, acc.x); acc.y = fmaf(w1, t1.y, acc.y);
    acc.z = fmaf(w1, t1.z, acc.z); acc.w = fmaf(w1, t1.w, acc.w);
    acc.x = fmaf(w2, t2.x, acc.x); acc.y = fmaf(w2, t2.y, acc.y);
    acc.z = fmaf(w2, t2.z, acc.z); acc.w = fmaf(w2, t2.w, acc.w);
    acc.x = fmaf(w3, t3.x, acc.x); acc.y = fmaf(w3, t3.y, acc.y);
    acc.z = fmaf(w3, t3.z, acc.z); acc.w = fmaf(w3, t3.w, acc.w);
  }
  acc.x += __shfl_xor(acc.x, 16, 64);
  acc.y += __shfl_xor(acc.y, 16, 64);
  acc.z += __shfl_xor(acc.z, 16, 64);
  acc.w += __shfl_xor(acc.w, 16, 64);
  acc.x += __shfl_xor(acc.x, 32, 64);
  acc.y += __shfl_xor(acc.y, 32, 64);
  acc.z += __shfl_xor(acc.z, 32, 64);
  acc.w += __shfl_xor(acc.w, 32, 64);
  if (grp == 0) {
    float di = dinv[node];
    float4 ts = ((const float4*)(Hs + (size_t)node * 64))[q];
    float4 v;
    v.x = (acc.x + ts.x) * di;
    v.y = (acc.y + ts.y) * di;
    v.z = (acc.z + ts.z) * di;
    v.w = (acc.w + ts.w) * di;
    ((float4*)vL[wv])[q] = v;
  }
  __syncthreads();  // W staging + vL visibility

  const float* vw = vL[wv];
  float y = 0.f;
#pragma unroll 8
  for (int k = 0; k < 64; k++) y = fmaf(vw[k], Wl[k * 64 + lane], y);
  y += bias[lane];
  y = fmaxf(y, 0.f);
  G[(size_t)node * 64 + lane] = y;
}

// ---------------- BN stats (float4 vectorized) ----------------
__global__ __launch_bounds__(256) void k_stats(const float* __restrict__ H,
                                               double* __restrict__ st) {
  int q = threadIdx.x & 15;   // feature quarter (4 floats)
  int rg = threadIdx.x >> 4;  // 16 row-groups per block
  float4 s1 = {0.f, 0.f, 0.f, 0.f};
  float4 s2 = {0.f, 0.f, 0.f, 0.f};
  for (int r = blockIdx.x * 16 + rg; r < NN; r += gridDim.x * 16) {
    float4 v = *(const float4*)(H + (size_t)r * 64 + q * 4);
    s1.x += v.x; s1.y += v.y; s1.z += v.z; s1.w += v.w;
    s2.x = fmaf(v.x, v.x, s2.x); s2.y = fmaf(v.y, v.y, s2.y);
    s2.z = fmaf(v.z, v.z, s2.z); s2.w = fmaf(v.w, v.w, s2.w);
  }
  __shared__ float a[16][16][8];
  a[rg][q][0] = s1.x; a[rg][q][1] = s1.y; a[rg][q][2] = s1.z; a[rg][q][3] = s1.w;
  a[rg][q][4] = s2.x; a[rg][q][5] = s2.y; a[rg][q][6] = s2.z; a[rg][q][7] = s2.w;
  __syncthreads();
  int tid = threadIdx.x;
  if (tid < 128) {
    int f = tid & 63;        // feature
    int which = tid >> 6;    // 0 = sum, 1 = sumsq
    int qq = f >> 2, jj = (f & 3) + which * 4;
    float t = 0.f;
#pragma unroll
    for (int g = 0; g < 16; g++) t += a[g][qq][jj];
    unsafeAtomicAdd(&st[which * 64 + f], (double)t);
  }
}

// --- fused: BN3 + residual (h2s*rd) + matmul 64->2, T2 *= dinv ---
__global__ void k_bnmmout(const float* __restrict__ G, const double* __restrict__ st,
                          const float* __restrict__ gamma, const float* __restrict__ beta,
                          const float* __restrict__ resS, const float* __restrict__ W,
                          const float* __restrict__ dinv, const float* __restrict__ rd,
                          float* __restrict__ T2, int nrows) {
  __shared__ float Wl[128];
  __shared__ float scl[128];
  int tid = threadIdx.x;
  if (tid < 32) ((float4*)Wl)[tid] = ((const float4*)W)[tid];
  else if (tid >= 64 && tid < 128) {
    int f = tid - 64;
    double m = st[f] / (double)NN;
    double var = st[64 + f] / (double)NN - m * m;
    float scale = gamma[f] * rsqrtf((float)var + EPSF);
    scl[f] = scale;
    scl[64 + f] = beta[f] - (float)m * scale;
  }
  __syncthreads();
  int row = blockIdx.x * 256 + tid;
  if (row >= nrows) return;
  const float4* g4 = (const float4*)(G + (size_t)row * 64);
  const float4* r4 = (const float4*)(resS + (size_t)row * 64);
  float rdv = rd[row];
  float a0 = 0.f, a1 = 0.f;
#pragma unroll
  for (int q = 0; q < 16; q++) {
    float4 v = g4[q];
    float4 rr = r4[q];
    float4 s = ((const float4*)scl)[q];
    float4 sh = ((const float4*)(scl + 64))[q];
    float h0 = v.x * s.x + sh.x + rr.x * rdv;
    float h1 = v.y * s.y + sh.y + rr.y * rdv;
    float h2 = v.z * s.z + sh.z + rr.z * rdv;
    float h3 = v.w * s.w + sh.w + rr.w * rdv;
    const float* wk = Wl + q * 8;
    a0 = fmaf(h0, wk[0], a0); a1 = fmaf(h0, wk[1], a1);
    a0 = fmaf(h1, wk[2], a0); a1 = fmaf(h1, wk[3], a1);
    a0 = fmaf(h2, wk[4], a0); a1 = fmaf(h2, wk[5], a1);
    a0 = fmaf(h3, wk[6], a0); a1 = fmaf(h3, wk[7], a1);
  }
  float dv = dinv[row];
  T2[(size_t)row * 2 + 0] = a0 * dv;
  T2[(size_t)row * 2 + 1] = a1 * dv;
}

// ---- fused final aggregation (dim 2, T2 pre-scaled) + pool + ticket finalize ----
__global__ void k_agg2pool(const float* __restrict__ T2, const int* __restrict__ rowp,
                           const int* __restrict__ cnt, const int* __restrict__ col,
                           const float* __restrict__ dinv, const float* __restrict__ bias,
                           const int* __restrict__ batch, float* __restrict__ pool,
                           int* __restrict__ pcnt, int* __restrict__ tick,
                           float* __restrict__ out, int nblk) {
  __shared__ float pl[128];
  __shared__ int pc[64];
  __shared__ int lastflag;
  int tid = threadIdx.x;
  if (tid < 128) pl[tid] = 0.f;
  if (tid < 64) pc[tid] = 0;
  __syncthreads();
  int node = blockIdx.x * 256 + tid;
  if (node < NN) {
    int s = rowp[node];
    int c = cnt[node];
    float a0 = 0.f, a1 = 0.f;
    for (int i = 0; i < c; i += 4) {
      int j0 = i, j1 = i + 1, j2 = i + 2, j3 = i + 3;
      int s0 = col[s + j0];
      int sA = col[s + (j1 < c ? j1 : j0)];
      int sB = col[s + (j2 < c ? j2 : j0)];
      int sC = col[s + (j3 < c ? j3 : j0)];
      float2 t0 = *(const float2*)(T2 + 2 * (size_t)s0);
      float2 t1 = *(const float2*)(T2 + 2 * (size_t)sA);
      float2 t2 = *(const float2*)(T2 + 2 * (size_t)sB);
      float2 t3 = *(const float2*)(T2 + 2 * (size_t)sC);
      float w1 = j1 < c ? 1.f : 0.f;
      float w2 = j2 < c ? 1.f : 0.f;
      float w3 = j3 < c ? 1.f : 0.f;
      a0 += t0.x; a1 += t0.y;
      a0 = fmaf(w1, t1.x, a0); a1 = fmaf(w1, t1.y, a1);
      a0 = fmaf(w2, t2.x, a0); a1 = fmaf(w2, t2.y, a1);
      a0 = fmaf(w3, t3.x, a0); a1 = fmaf(w3, t3.y, a1);
    }
    float di = dinv[node];
    float2 tn = *(const float2*)(T2 + 2 * (size_t)node);
    float v0 = (a0 + tn.x) * di + bias[0];
    float v1 = (a1 + tn.y) * di + bias[1];
    int bb = batch[node];
    atomicAdd(&pl[bb * 2 + 0], v0);
    atomicAdd(&pl[bb * 2 + 1], v1);
    atomicAdd(&pc[bb], 1);
  }
  __syncthreads();
  if (tid < 128 && pl[tid] != 0.f) unsafeAtomicAdd(&pool[tid], pl[tid]);
  if (tid < 64 && pc[tid] != 0) atomicAdd(&pcnt[tid], pc[tid]);
  __syncthreads();
  if (tid == 0) {
    __threadfence();
    int old = atomicAdd(tick, 1);
    lastflag = (old == nblk - 1) ? 1 : 0;
  }
  __syncthreads();
  if (lastflag && tid < 128) {
    float v = unsafeAtomicAdd(&pool[tid], 0.f);       // coherent read
    int c = atomicAdd(&pcnt[tid >> 1], 0);            // coherent read
    out[tid] = v / (float)(c > 0 ? c : 1);
  }
}

extern "C" void kernel_launch(void* const* d_in, const int* in_sizes, int n_in,
                              void* d_out, int out_size, void* d_ws, size_t ws_size,
                              hipStream_t stream) {
  (void)in_sizes; (void)n_in; (void)out_size; (void)ws_size;
  const float* x     = (const float*)d_in[0];
  const float* W_in  = (const float*)d_in[1];
  const float* b_in  = (const float*)d_in[2];
  const float* W_h   = (const float*)d_in[3];
  const float* b_h   = (const float*)d_in[4];
  const float* W_out = (const float*)d_in[5];
  const float* b_out = (const float*)d_in[6];
  const float* gamma = (const float*)d_in[7];
  const float* beta  = (const float*)d_in[8];
  const int*   ei    = (const int*)d_in[9];
  const int*   batch = (const int*)d_in[10];
  const int* src = ei;
  const int* dst = ei + NE;
  float* out = (float*)d_out;

  char* w = (char*)d_ws;
  size_t off = 0;
  auto alloc = [&](size_t bytes) -> void* {
    void* p = (void*)(w + off);
    off += (bytes + 511) & ~(size_t)511;
    return p;
  };
  int*    deg   = (int*)alloc((size_t)NN * 4);
  int*    rowp  = (int*)alloc((size_t)NN * 4);
  int*    col   = (int*)alloc((size_t)NE * 4);
  float*  dinv  = (float*)alloc((size_t)NN * 4);
  float*  rdeg  = (float*)alloc((size_t)NN * 4);
  int*    bbase = (int*)alloc((NBUCK + 1) * 4);
  int*    bcur  = (int*)alloc(NBUCK * 4);
  // zeroed zone: stats (3*128 dbl = 3072) | pool (512) | pcnt (256) | tick (256) |
  //              gbh (782*4 = 3128) -> 7224 bytes
  char*   zzone = (char*)alloc(7680);
  double* stats = (double*)zzone;
  float*  pool  = (float*)(zzone + 3072);
  int*    pcnt  = (int*)(zzone + 3584);
  int*    tick  = (int*)(zzone + 3840);
  int*    gbh   = (int*)(zzone + 4096);
  float*  buf0  = (float*)alloc((size_t)NN * HID * 4);
  float*  buf1  = (float*)alloc((size_t)NN * HID * 4);
  float*  buf2  = (float*)alloc((size_t)NN * HID * 4);
  float*  T2    = (float*)alloc((size_t)NN * 2 * 4);
  // ebuf (9.6MB) aliases buf0: consumed by k_bucket_csr before buf0's first write
  unsigned long long* ebuf = (unsigned long long*)buf0;

  hipMemsetAsync(zzone, 0, 7424, stream);

  // graph prep: bucket-radix CSR build
  k_ehist<<<293, 256, 0, stream>>>(dst, gbh);
  k_escan<<<1, 256, 0, stream>>>(gbh, bbase, bcur);
  k_escatter<<<293, 256, 0, stream>>>(src, dst, bcur, ebuf);
  k_bucket_csr<<<NBUCK, 256, 0, stream>>>(ebuf, bbase, deg, rowp, dinv, rdeg, col);

  const int mmgrid = (NN + 63) / 64;       // 1563
  const int agrid = NN / 4;                // 25000
  const int bngrid = (NN * 16 + 255) / 256;  // 6250

  // layer 1: x(128) -> T(scaled)=buf0 -> G1=buf1 (+relu), stats1
  k_mmA<<<mmgrid, 256, 0, stream>>>(x, W_in, dinv, buf0, NN);
  k_agg64<<<agrid, 256, 0, stream>>>(buf0, rowp, deg, col, dinv, b_in, buf1, 1);
  k_stats<<<512, 256, 0, stream>>>(buf1, stats);

  // layer 2: h1s = BN1(G1)*dinv -> buf2; G2 = relu((agg h1s)@W0 + b) -> buf0; stats2
  k_bnapply<<<bngrid, 256, 0, stream>>>(buf1, stats, gamma, beta, nullptr, dinv, buf2);
  k_aggmm<<<agrid, 256, 0, stream>>>(buf2, rowp, deg, col, dinv, b_h, W_h, buf0);
  k_stats<<<512, 256, 0, stream>>>(buf0, stats + 128);

  // layer 3: h2s = BN2(G2)*dinv + h1s -> buf1; G3 = relu((agg h2s)@W1 + b) -> buf2; stats3
  k_bnapply<<<bngrid, 256, 0, stream>>>(buf0, stats + 128, gamma + 64, beta + 64,
                                        buf2, dinv, buf1);
  k_aggmm<<<agrid, 256, 0, stream>>>(buf1, rowp, deg, col, dinv, b_h + HID,
                                     W_h + HID * HID, buf2);
  k_stats<<<512, 256, 0, stream>>>(buf2, stats + 256);

  // output: h3 = BN3(G3) + h2s*rd, T2 = h3@W_out*dinv, then agg+pool+div fused
  k_bnmmout<<<(NN + 255) / 256, 256, 0, stream>>>(buf2, stats + 256, gamma + 128,
                                                  beta + 128, buf1, W_out, dinv, rdeg,
                                                  T2, NN);
  const int pgrid = (NN + 255) / 256;  // 391
  k_agg2pool<<<pgrid, 256, 0, stream>>>(T2, rowp, deg, col, dinv, b_out, batch, pool,
                                        pcnt, tick, out, pgrid);
}

// Round 10
// 401.917 us; speedup vs baseline: 1.1208x; 1.1208x over previous
//
#include <hip/hip_runtime.h>
#include <hip/hip_fp16.h>

// EnhancedGNN on MI355X.
// R13: R12's aggmm fusion reverted (matvec tail not hidden; +12us). Back to R11
//      structure (best 438.9us) with ONE change: T (the gather operand) stored
//      fp16 in a dedicated buffer Th -- halves the dominant agg64 gather bytes
//      (307->154 MB logical per pass). Accumulation fp32; G/Hside/stats fp32.
//      Also kills the layer-3 G/T alias. 15 launches.

#define NN 100000
#define NE 1200000
#define NBATCH 64
#define IND 128
#define HID 64
#define EPSF 1e-5f
#define NBUCK 782   // ceil(100000/128)
#define NPB 128     // nodes per bucket; bucket(d) = d >> 7

// ---------------- graph prep: bucket histogram ----------------
__global__ void k_ehist(const int* __restrict__ dst, int* __restrict__ gbh) {
  __shared__ int lh[NBUCK];
  int tid = threadIdx.x;
  for (int i = tid; i < NBUCK; i += 256) lh[i] = 0;
  __syncthreads();
  int base = blockIdx.x * 4096;
#pragma unroll
  for (int j = 0; j < 16; j++) {
    int e = base + j * 256 + tid;
    if (e < NE) atomicAdd(&lh[dst[e] >> 7], 1);
  }
  __syncthreads();
  for (int i = tid; i < NBUCK; i += 256) {
    int v = lh[i];
    if (v) atomicAdd(&gbh[i], v);
  }
}

// exclusive scan of 782 bucket counts -> bbase[0..NBUCK], bcur=bbase
__global__ void k_escan(const int* __restrict__ gbh, int* __restrict__ bbase,
                        int* __restrict__ bcur) {
  __shared__ int a[256];
  int tid = threadIdx.x;
  int loc[4];
  int tsum = 0;
  for (int j = 0; j < 4; j++) {
    int idx = tid * 4 + j;
    int v = (idx < NBUCK) ? gbh[idx] : 0;
    loc[j] = tsum;
    tsum += v;
  }
  a[tid] = tsum;
  __syncthreads();
  for (int off = 1; off < 256; off <<= 1) {
    int v = (tid >= off) ? a[tid - off] : 0;
    __syncthreads();
    a[tid] += v;
    __syncthreads();
  }
  int excl = a[tid] - tsum;
  for (int j = 0; j < 4; j++) {
    int idx = tid * 4 + j;
    if (idx < NBUCK) {
      int v = excl + loc[j];
      bbase[idx] = v;
      bcur[idx] = v;
    }
  }
  if (tid == 255) bbase[NBUCK] = a[255];
}

// scatter (src,dst) pairs into bucket-contiguous ebuf; LDS-aggregated cursor grabs
__global__ void k_escatter(const int* __restrict__ src, const int* __restrict__ dst,
                           int* __restrict__ bcur, unsigned long long* __restrict__ ebuf) {
  __shared__ int lh[NBUCK];
  __shared__ int lbase[NBUCK];
  int tid = threadIdx.x;
  for (int i = tid; i < NBUCK; i += 256) lh[i] = 0;
  __syncthreads();
  int base = blockIdx.x * 4096;
  int sv[16], dv[16], rk[16];
#pragma unroll
  for (int j = 0; j < 16; j++) {
    int e = base + j * 256 + tid;
    if (e < NE) {
      sv[j] = src[e];
      dv[j] = dst[e];
      rk[j] = atomicAdd(&lh[dv[j] >> 7], 1);
    } else {
      dv[j] = -1;
    }
  }
  __syncthreads();
  for (int i = tid; i < NBUCK; i += 256) {
    int v = lh[i];
    lbase[i] = v ? atomicAdd(&bcur[i], v) : 0;
  }
  __syncthreads();
#pragma unroll
  for (int j = 0; j < 16; j++) {
    if (dv[j] >= 0) {
      int b = dv[j] >> 7;
      ebuf[lbase[b] + rk[j]] =
          (unsigned long long)(unsigned)sv[j] | ((unsigned long long)(unsigned)dv[j] << 32);
    }
  }
}

// one block per bucket: local hist -> deg/dinv, local scan -> rowp, LDS-cursor fill -> col
__global__ void k_bucket_csr(const unsigned long long* __restrict__ ebuf,
                             const int* __restrict__ bbase, int* __restrict__ deg,
                             int* __restrict__ rowp, float* __restrict__ dinv,
                             int* __restrict__ col) {
  __shared__ int ldeg[NPB];
  __shared__ int lcur[NPB];
  __shared__ int sred[NPB];
  int b = blockIdx.x, tid = threadIdx.x;
  int nbase = b * NPB;
  int e0 = bbase[b], e1 = bbase[b + 1];
  if (tid < NPB) ldeg[tid] = 0;
  __syncthreads();
  for (int e = e0 + tid; e < e1; e += 256) {
    int d = (int)(ebuf[e] >> 32) - nbase;
    atomicAdd(&ldeg[d], 1);
  }
  __syncthreads();
  if (tid < NPB) sred[tid] = ldeg[tid];
  __syncthreads();
  for (int off = 1; off < NPB; off <<= 1) {
    int v = 0;
    if (tid < NPB && tid >= off) v = sred[tid - off];
    __syncthreads();
    if (tid < NPB) sred[tid] += v;
    __syncthreads();
  }
  if (tid < NPB) {
    int excl = sred[tid] - ldeg[tid];
    lcur[tid] = excl;
    int gn = nbase + tid;
    if (gn < NN) {
      int dg = ldeg[tid];
      deg[gn] = dg;
      rowp[gn] = e0 + excl;
      dinv[gn] = rsqrtf((float)dg + 1.0f);
    }
  }
  __syncthreads();
  for (int e = e0 + tid; e < e1; e += 256) {
    unsigned long long p = ebuf[e];
    int s = (int)(unsigned)p;
    int d = (int)(p >> 32) - nbase;
    int r = atomicAdd(&lcur[d], 1);
    col[e0 + r] = s;
  }
}

// ---------------- mm A: X[nrows,128] @ W[128,64] -> Th (fp16) * dinv[row] --------
// 64 rows/block, 4 threads/row (col-quarter per wave, readfirstlane -> s_load W).
__global__ __launch_bounds__(256) void k_mmA(const float* __restrict__ X,
                                             const float* __restrict__ W,
                                             const float* __restrict__ dinv,
                                             __half* __restrict__ T, int nrows) {
  __shared__ float xs[64 * 65];
  int tid = threadIdx.x;
  int rbase = blockIdx.x * 64;
  int q4 = __builtin_amdgcn_readfirstlane(tid >> 6);  // wave-uniform col quarter
  int r = tid & 63;
  int r65 = r * 65;
  float4 acc[4];
#pragma unroll
  for (int j = 0; j < 4; j++) acc[j] = {0.f, 0.f, 0.f, 0.f};

  for (int ch = 0; ch < 2; ch++) {
#pragma unroll
    for (int i = 0; i < 4; i++) {
      int f = i * 256 + tid;
      int rr = f >> 4, kq = f & 15;
      int gr = rbase + rr;
      int grc = gr < nrows ? gr : nrows - 1;
      float4 v = *(const float4*)(X + (size_t)grc * 128 + ch * 64 + 4 * kq);
      float* p = xs + rr * 65 + 4 * kq;
      p[0] = v.x; p[1] = v.y; p[2] = v.z; p[3] = v.w;
    }
    __syncthreads();
    const float* Wb = W + ch * 64 * 64 + q4 * 16;
#pragma unroll 4
    for (int k = 0; k < 64; k++) {
      float xk = xs[r65 + k];
      const float4* wr = (const float4*)(Wb + (size_t)k * 64);
#pragma unroll
      for (int j = 0; j < 4; j++) {
        float4 wv = wr[j];
        acc[j].x = fmaf(xk, wv.x, acc[j].x);
        acc[j].y = fmaf(xk, wv.y, acc[j].y);
        acc[j].z = fmaf(xk, wv.z, acc[j].z);
        acc[j].w = fmaf(xk, wv.w, acc[j].w);
      }
    }
    if (ch == 0) __syncthreads();
  }

  int row = rbase + r;
  if (row < nrows) {
    float dv = dinv[row];
    __half2 o2[8];
#pragma unroll
    for (int j = 0; j < 4; j++) {
      float4 o = acc[j];
      o2[2 * j]     = __floats2half2_rn(o.x * dv, o.y * dv);
      o2[2 * j + 1] = __floats2half2_rn(o.z * dv, o.w * dv);
    }
    float4* tp = (float4*)(T + (size_t)row * 64 + q4 * 16);
    tp[0] = *(float4*)&o2[0];
    tp[1] = *(float4*)&o2[4];
  }
}

// ---------------- mm B: BN(G)(+res) -> Hside(fp32); Th = (h @ W)*dinv fp16 -------
__global__ __launch_bounds__(256) void k_mmB(const float* __restrict__ G,
                                             const double* __restrict__ st,
                                             const float* __restrict__ gamma,
                                             const float* __restrict__ beta,
                                             const float* __restrict__ res,
                                             float* __restrict__ Hside,
                                             const float* __restrict__ W,
                                             const float* __restrict__ dinv,
                                             __half* __restrict__ T, int nrows) {
  __shared__ float xs[64 * 65];
  __shared__ float scl[128];
  int tid = threadIdx.x;
  if (tid < 64) {
    double m = st[tid] / (double)NN;
    double var = st[64 + tid] / (double)NN - m * m;
    float scale = gamma[tid] * rsqrtf((float)var + EPSF);
    scl[tid] = scale;
    scl[64 + tid] = beta[tid] - (float)m * scale;
  }
  __syncthreads();

  int rbase = blockIdx.x * 64;
#pragma unroll
  for (int i = 0; i < 4; i++) {
    int f = i * 256 + tid;
    int rr = f >> 4, kq = f & 15;
    int gr = rbase + rr;
    int grc = gr < nrows ? gr : nrows - 1;
    int kof = 4 * kq;
    float4 v = *(const float4*)(G + (size_t)grc * 64 + kof);
    float4 s = ((const float4*)scl)[kq];
    float4 sh = ((const float4*)(scl + 64))[kq];
    v.x = v.x * s.x + sh.x;
    v.y = v.y * s.y + sh.y;
    v.z = v.z * s.z + sh.z;
    v.w = v.w * s.w + sh.w;
    if (res != nullptr) {
      float4 rr2 = *(const float4*)(res + (size_t)grc * 64 + kof);
      v.x += rr2.x; v.y += rr2.y; v.z += rr2.z; v.w += rr2.w;
    }
    if (gr < nrows) *(float4*)(Hside + (size_t)gr * 64 + kof) = v;
    float* p = xs + rr * 65 + kof;
    p[0] = v.x; p[1] = v.y; p[2] = v.z; p[3] = v.w;
  }
  __syncthreads();

  int q4 = __builtin_amdgcn_readfirstlane(tid >> 6);
  int r = tid & 63;
  int r65 = r * 65;
  float4 acc[4];
#pragma unroll
  for (int j = 0; j < 4; j++) acc[j] = {0.f, 0.f, 0.f, 0.f};
  const float* Wb = W + q4 * 16;
#pragma unroll 4
  for (int k = 0; k < 64; k++) {
    float xk = xs[r65 + k];
    const float4* wr = (const float4*)(Wb + (size_t)k * 64);
#pragma unroll
    for (int j = 0; j < 4; j++) {
      float4 wv = wr[j];
      acc[j].x = fmaf(xk, wv.x, acc[j].x);
      acc[j].y = fmaf(xk, wv.y, acc[j].y);
      acc[j].z = fmaf(xk, wv.z, acc[j].z);
      acc[j].w = fmaf(xk, wv.w, acc[j].w);
    }
  }

  int row = rbase + r;
  if (row < nrows) {
    float dv = dinv[row];
    __half2 o2[8];
#pragma unroll
    for (int j = 0; j < 4; j++) {
      float4 o = acc[j];
      o2[2 * j]     = __floats2half2_rn(o.x * dv, o.y * dv);
      o2[2 * j + 1] = __floats2half2_rn(o.z * dv, o.w * dv);
    }
    float4* tp = (float4*)(T + (size_t)row * 64 + q4 * 16);
    tp[0] = *(float4*)&o2[0];
    tp[1] = *(float4*)&o2[4];
  }
}

// ---------------- aggregation (HID=64): wave/node, fp16 gather, fp32 accum --------
// Th is pre-scaled by dinv[row]: o = di*(sum Th[src] + Th[node]) + bias
__global__ void k_agg64(const __half* __restrict__ T, const int* __restrict__ row_start,
                        const int* __restrict__ cnt, const int* __restrict__ col,
                        const float* __restrict__ dinv, const float* __restrict__ bias,
                        float* __restrict__ G, int relu) {
  int lane = threadIdx.x & 63;
  int wv = threadIdx.x >> 6;
  int node = blockIdx.x * 4 + wv;
  if (node >= NN) return;
  int grp = lane >> 4;
  int q = lane & 15;
  int s = row_start[node];
  int c = cnt[node];
  float4 acc = {0.f, 0.f, 0.f, 0.f};
  for (int i = 0; i < c; i += 16) {
    int j0 = i + grp, j1 = j0 + 4, j2 = j0 + 8, j3 = j0 + 12;
    int s0 = col[s + (j0 < c ? j0 : 0)];
    int s1 = col[s + (j1 < c ? j1 : 0)];
    int s2 = col[s + (j2 < c ? j2 : 0)];
    int s3 = col[s + (j3 < c ? j3 : 0)];
    float2 r0 = *(const float2*)(T + (size_t)s0 * 64 + q * 4);
    float2 r1 = *(const float2*)(T + (size_t)s1 * 64 + q * 4);
    float2 r2 = *(const float2*)(T + (size_t)s2 * 64 + q * 4);
    float2 r3 = *(const float2*)(T + (size_t)s3 * 64 + q * 4);
    float w0 = j0 < c ? 1.f : 0.f;
    float w1 = j1 < c ? 1.f : 0.f;
    float w2 = j2 < c ? 1.f : 0.f;
    float w3 = j3 < c ? 1.f : 0.f;
    {
      __half2* p = (__half2*)&r0;
      float2 lo = __half22float2(p[0]), hi = __half22float2(p[1]);
      acc.x = fmaf(w0, lo.x, acc.x); acc.y = fmaf(w0, lo.y, acc.y);
      acc.z = fmaf(w0, hi.x, acc.z); acc.w = fmaf(w0, hi.y, acc.w);
    }
    {
      __half2* p = (__half2*)&r1;
      float2 lo = __half22float2(p[0]), hi = __half22float2(p[1]);
      acc.x = fmaf(w1, lo.x, acc.x); acc.y = fmaf(w1, lo.y, acc.y);
      acc.z = fmaf(w1, hi.x, acc.z); acc.w = fmaf(w1, hi.y, acc.w);
    }
    {
      __half2* p = (__half2*)&r2;
      float2 lo = __half22float2(p[0]), hi = __half22float2(p[1]);
      acc.x = fmaf(w2, lo.x, acc.x); acc.y = fmaf(w2, lo.y, acc.y);
      acc.z = fmaf(w2, hi.x, acc.z); acc.w = fmaf(w2, hi.y, acc.w);
    }
    {
      __half2* p = (__half2*)&r3;
      float2 lo = __half22float2(p[0]), hi = __half22float2(p[1]);
      acc.x = fmaf(w3, lo.x, acc.x); acc.y = fmaf(w3, lo.y, acc.y);
      acc.z = fmaf(w3, hi.x, acc.z); acc.w = fmaf(w3, hi.y, acc.w);
    }
  }
  acc.x += __shfl_xor(acc.x, 16, 64);
  acc.y += __shfl_xor(acc.y, 16, 64);
  acc.z += __shfl_xor(acc.z, 16, 64);
  acc.w += __shfl_xor(acc.w, 16, 64);
  acc.x += __shfl_xor(acc.x, 32, 64);
  acc.y += __shfl_xor(acc.y, 32, 64);
  acc.z += __shfl_xor(acc.z, 32, 64);
  acc.w += __shfl_xor(acc.w, 32, 64);
  if (grp == 0) {
    float di = dinv[node];
    float2 rs = *(const float2*)(T + (size_t)node * 64 + q * 4);
    __half2* p = (__half2*)&rs;
    float2 lo = __half22float2(p[0]), hi = __half22float2(p[1]);
    float4 bs = ((const float4*)bias)[q];
    float4 o;
    o.x = (acc.x + lo.x) * di + bs.x;
    o.y = (acc.y + lo.y) * di + bs.y;
    o.z = (acc.z + hi.x) * di + bs.z;
    o.w = (acc.w + hi.y) * di + bs.w;
    if (relu) {
      o.x = fmaxf(o.x, 0.f);
      o.y = fmaxf(o.y, 0.f);
      o.z = fmaxf(o.z, 0.f);
      o.w = fmaxf(o.w, 0.f);
    }
    ((float4*)(G + (size_t)node * 64))[q] = o;
  }
}

// ---------------- BN stats (float4 vectorized) ----------------
__global__ __launch_bounds__(256) void k_stats(const float* __restrict__ H,
                                               double* __restrict__ st) {
  int q = threadIdx.x & 15;   // feature quarter (4 floats)
  int rg = threadIdx.x >> 4;  // 16 row-groups per block
  float4 s1 = {0.f, 0.f, 0.f, 0.f};
  float4 s2 = {0.f, 0.f, 0.f, 0.f};
  for (int r = blockIdx.x * 16 + rg; r < NN; r += gridDim.x * 16) {
    float4 v = *(const float4*)(H + (size_t)r * 64 + q * 4);
    s1.x += v.x; s1.y += v.y; s1.z += v.z; s1.w += v.w;
    s2.x = fmaf(v.x, v.x, s2.x); s2.y = fmaf(v.y, v.y, s2.y);
    s2.z = fmaf(v.z, v.z, s2.z); s2.w = fmaf(v.w, v.w, s2.w);
  }
  __shared__ float a[16][16][8];
  a[rg][q][0] = s1.x; a[rg][q][1] = s1.y; a[rg][q][2] = s1.z; a[rg][q][3] = s1.w;
  a[rg][q][4] = s2.x; a[rg][q][5] = s2.y; a[rg][q][6] = s2.z; a[rg][q][7] = s2.w;
  __syncthreads();
  int tid = threadIdx.x;
  if (tid < 128) {
    int f = tid & 63;        // feature
    int which = tid >> 6;    // 0 = sum, 1 = sumsq
    int qq = f >> 2, jj = (f & 3) + which * 4;
    float t = 0.f;
#pragma unroll
    for (int g = 0; g < 16; g++) t += a[g][qq][jj];
    unsafeAtomicAdd(&st[which * 64 + f], (double)t);
  }
}

// ---------------- fused: BN3 (in-block scale) + residual + matmul 64->2, T2 *= dinv --
__global__ void k_bnmmout(const float* __restrict__ G, const double* __restrict__ st,
                          const float* __restrict__ gamma, const float* __restrict__ beta,
                          const float* __restrict__ res, const float* __restrict__ W,
                          const float* __restrict__ dinv, float* __restrict__ T2,
                          int nrows) {
  __shared__ float Wl[128];
  __shared__ float scl[128];
  int tid = threadIdx.x;
  if (tid < 32) ((float4*)Wl)[tid] = ((const float4*)W)[tid];
  else if (tid >= 64 && tid < 128) {
    int f = tid - 64;
    double m = st[f] / (double)NN;
    double var = st[64 + f] / (double)NN - m * m;
    float scale = gamma[f] * rsqrtf((float)var + EPSF);
    scl[f] = scale;
    scl[64 + f] = beta[f] - (float)m * scale;
  }
  __syncthreads();
  int row = blockIdx.x * 256 + tid;
  if (row >= nrows) return;
  const float4* g4 = (const float4*)(G + (size_t)row * 64);
  const float4* r4 = (const float4*)(res + (size_t)row * 64);
  float a0 = 0.f, a1 = 0.f;
#pragma unroll
  for (int q = 0; q < 16; q++) {
    float4 v = g4[q];
    float4 rr = r4[q];
    float4 s = ((const float4*)scl)[q];
    float4 sh = ((const float4*)(scl + 64))[q];
    float h0 = v.x * s.x + sh.x + rr.x;
    float h1 = v.y * s.y + sh.y + rr.y;
    float h2 = v.z * s.z + sh.z + rr.z;
    float h3 = v.w * s.w + sh.w + rr.w;
    const float* wk = Wl + q * 8;
    a0 = fmaf(h0, wk[0], a0); a1 = fmaf(h0, wk[1], a1);
    a0 = fmaf(h1, wk[2], a0); a1 = fmaf(h1, wk[3], a1);
    a0 = fmaf(h2, wk[4], a0); a1 = fmaf(h2, wk[5], a1);
    a0 = fmaf(h3, wk[6], a0); a1 = fmaf(h3, wk[7], a1);
  }
  float dv = dinv[row];
  T2[(size_t)row * 2 + 0] = a0 * dv;
  T2[(size_t)row * 2 + 1] = a1 * dv;
}

// ---- fused final aggregation (dim 2, T2 pre-scaled) + pool + ticket finalize ----
__global__ void k_agg2pool(const float* __restrict__ T2, const int* __restrict__ rowp,
                           const int* __restrict__ cnt, const int* __restrict__ col,
                           const float* __restrict__ dinv, const float* __restrict__ bias,
                           const int* __restrict__ batch, float* __restrict__ pool,
                           int* __restrict__ pcnt, int* __restrict__ tick,
                           float* __restrict__ out, int nblk) {
  __shared__ float pl[128];
  __shared__ int pc[64];
  __shared__ int lastflag;
  int tid = threadIdx.x;
  if (tid < 128) pl[tid] = 0.f;
  if (tid < 64) pc[tid] = 0;
  __syncthreads();
  int node = blockIdx.x * 256 + tid;
  if (node < NN) {
    int s = rowp[node];
    int c = cnt[node];
    float a0 = 0.f, a1 = 0.f;
    for (int i = 0; i < c; i += 4) {
      int j0 = i, j1 = i + 1, j2 = i + 2, j3 = i + 3;
      int s0 = col[s + j0];
      int sA = col[s + (j1 < c ? j1 : j0)];
      int sB = col[s + (j2 < c ? j2 : j0)];
      int sC = col[s + (j3 < c ? j3 : j0)];
      float2 t0 = *(const float2*)(T2 + 2 * (size_t)s0);
      float2 t1 = *(const float2*)(T2 + 2 * (size_t)sA);
      float2 t2 = *(const float2*)(T2 + 2 * (size_t)sB);
      float2 t3 = *(const float2*)(T2 + 2 * (size_t)sC);
      float w1 = j1 < c ? 1.f : 0.f;
      float w2 = j2 < c ? 1.f : 0.f;
      float w3 = j3 < c ? 1.f : 0.f;
      a0 += t0.x; a1 += t0.y;
      a0 = fmaf(w1, t1.x, a0); a1 = fmaf(w1, t1.y, a1);
      a0 = fmaf(w2, t2.x, a0); a1 = fmaf(w2, t2.y, a1);
      a0 = fmaf(w3, t3.x, a0); a1 = fmaf(w3, t3.y, a1);
    }
    float di = dinv[node];
    float2 tn = *(const float2*)(T2 + 2 * (size_t)node);
    float v0 = (a0 + tn.x) * di + bias[0];
    float v1 = (a1 + tn.y) * di + bias[1];
    int bb = batch[node];
    atomicAdd(&pl[bb * 2 + 0], v0);
    atomicAdd(&pl[bb * 2 + 1], v1);
    atomicAdd(&pc[bb], 1);
  }
  __syncthreads();
  if (tid < 128 && pl[tid] != 0.f) unsafeAtomicAdd(&pool[tid], pl[tid]);
  if (tid < 64 && pc[tid] != 0) atomicAdd(&pcnt[tid], pc[tid]);
  __syncthreads();
  if (tid == 0) {
    __threadfence();
    int old = atomicAdd(tick, 1);
    lastflag = (old == nblk - 1) ? 1 : 0;
  }
  __syncthreads();
  if (lastflag && tid < 128) {
    float v = unsafeAtomicAdd(&pool[tid], 0.f);       // coherent read
    int c = atomicAdd(&pcnt[tid >> 1], 0);            // coherent read
    out[tid] = v / (float)(c > 0 ? c : 1);
  }
}

extern "C" void kernel_launch(void* const* d_in, const int* in_sizes, int n_in,
                              void* d_out, int out_size, void* d_ws, size_t ws_size,
                              hipStream_t stream) {
  (void)in_sizes; (void)n_in; (void)out_size; (void)ws_size;
  const float* x     = (const float*)d_in[0];
  const float* W_in  = (const float*)d_in[1];
  const float* b_in  = (const float*)d_in[2];
  const float* W_h   = (const float*)d_in[3];
  const float* b_h   = (const float*)d_in[4];
  const float* W_out = (const float*)d_in[5];
  const float* b_out = (const float*)d_in[6];
  const float* gamma = (const float*)d_in[7];
  const float* beta  = (const float*)d_in[8];
  const int*   ei    = (const int*)d_in[9];
  const int*   batch = (const int*)d_in[10];
  const int* src = ei;
  const int* dst = ei + NE;
  float* out = (float*)d_out;

  char* w = (char*)d_ws;
  size_t off = 0;
  auto alloc = [&](size_t bytes) -> void* {
    void* p = (void*)(w + off);
    off += (bytes + 511) & ~(size_t)511;
    return p;
  };
  int*    deg   = (int*)alloc((size_t)NN * 4);
  int*    rowp  = (int*)alloc((size_t)NN * 4);
  int*    col   = (int*)alloc((size_t)NE * 4);
  float*  dinv  = (float*)alloc((size_t)NN * 4);
  int*    bbase = (int*)alloc((NBUCK + 1) * 4);
  int*    bcur  = (int*)alloc(NBUCK * 4);
  // zeroed zone: stats (3*128 dbl = 3072) | pool (512) | pcnt (256) | tick (256) |
  //              gbh (782*4 = 3128) -> 7224 bytes
  char*   zzone = (char*)alloc(7680);
  double* stats = (double*)zzone;
  float*  pool  = (float*)(zzone + 3072);
  int*    pcnt  = (int*)(zzone + 3584);
  int*    tick  = (int*)(zzone + 3840);
  int*    gbh   = (int*)(zzone + 4096);
  float*  buf0  = (float*)alloc((size_t)NN * HID * 4);
  float*  buf1  = (float*)alloc((size_t)NN * HID * 4);
  float*  buf2  = (float*)alloc((size_t)NN * HID * 4);
  __half* Th    = (__half*)alloc((size_t)NN * HID * 2);
  float*  T2    = (float*)alloc((size_t)NN * 2 * 4);
  // ebuf (9.6MB) aliases buf0: consumed by k_bucket_csr; buf0's first write is G2 (step 5)
  unsigned long long* ebuf = (unsigned long long*)buf0;

  hipMemsetAsync(zzone, 0, 7424, stream);

  // graph prep: bucket-radix CSR build
  k_ehist<<<293, 256, 0, stream>>>(dst, gbh);
  k_escan<<<1, 256, 0, stream>>>(gbh, bbase, bcur);
  k_escatter<<<293, 256, 0, stream>>>(src, dst, bcur, ebuf);
  k_bucket_csr<<<NBUCK, 256, 0, stream>>>(ebuf, bbase, deg, rowp, dinv, col);

  const int mmgrid = (NN + 63) / 64;   // 1563

  // layer 1: x(128) -> Th (fp16, pre-scaled) -> G1=buf1
  k_mmA<<<mmgrid, 256, 0, stream>>>(x, W_in, dinv, Th, NN);
  k_agg64<<<(NN + 3) / 4, 256, 0, stream>>>(Th, rowp, deg, col, dinv, b_in, buf1, 1);
  k_stats<<<512, 256, 0, stream>>>(buf1, stats);

  // layer 2: h1 = BN1(G1) (side-> buf2); Th = h1@W_h0; G2 = buf0
  k_mmB<<<mmgrid, 256, 0, stream>>>(buf1, stats, gamma, beta, nullptr, buf2, W_h,
                                    dinv, Th, NN);
  k_agg64<<<(NN + 3) / 4, 256, 0, stream>>>(Th, rowp, deg, col, dinv, b_h, buf0, 1);
  k_stats<<<512, 256, 0, stream>>>(buf0, stats + 128);

  // layer 3: h2 = BN2(G2)+h1 (side-> buf1); Th = h2@W_h1; G3 = buf2
  k_mmB<<<mmgrid, 256, 0, stream>>>(buf0, stats + 128, gamma + 64, beta + 64, buf2,
                                    buf1, W_h + HID * HID, dinv, Th, NN);
  k_agg64<<<(NN + 3) / 4, 256, 0, stream>>>(Th, rowp, deg, col, dinv, b_h + HID, buf2, 1);
  k_stats<<<512, 256, 0, stream>>>(buf2, stats + 256);

  // output: h3 = BN3(G3)+h2(buf1) fused with mm 64->2 (T2 pre-scaled), then agg+pool+div
  k_bnmmout<<<(NN + 255) / 256, 256, 0, stream>>>(buf2, stats + 256, gamma + 128,
                                                  beta + 128, buf1, W_out, dinv, T2, NN);
  const int pgrid = (NN + 255) / 256;  // 391
  k_agg2pool<<<pgrid, 256, 0, stream>>>(T2, rowp, deg, col, dinv, b_out, batch, pool,
                                        pcnt, tick, out, pgrid);
}

// Round 12
// 392.414 us; speedup vs baseline: 1.1479x; 1.0242x over previous
//
#include <hip/hip_runtime.h>
#include <hip/hip_fp16.h>

// EnhancedGNN on MI355X.
// R14 (resubmit; prior run died to container infra failure, no kernel verdict):
//      (1) mm kernels widened to 512-thread / 8-col-per-wave (q8 readfirstlane
//      keeps W s_load-uniform): total waves 6250 -> 12500 (12.2/SIMD) -- TLP is
//      the proven lever for this latency-bound family (R6 1.5w=56us -> R7 6.1w=40us).
//      Epilogue: 8 fp16 cols = one 16B store. (2) rowp+deg packed int2 -> one
//      dependent load at agg chain start. R13's fp16-T gather kept. 15 launches.

#define NN 100000
#define NE 1200000
#define NBATCH 64
#define IND 128
#define HID 64
#define EPSF 1e-5f
#define NBUCK 782   // ceil(100000/128)
#define NPB 128     // nodes per bucket; bucket(d) = d >> 7

// ---------------- graph prep: bucket histogram ----------------
__global__ void k_ehist(const int* __restrict__ dst, int* __restrict__ gbh) {
  __shared__ int lh[NBUCK];
  int tid = threadIdx.x;
  for (int i = tid; i < NBUCK; i += 256) lh[i] = 0;
  __syncthreads();
  int base = blockIdx.x * 4096;
#pragma unroll
  for (int j = 0; j < 16; j++) {
    int e = base + j * 256 + tid;
    if (e < NE) atomicAdd(&lh[dst[e] >> 7], 1);
  }
  __syncthreads();
  for (int i = tid; i < NBUCK; i += 256) {
    int v = lh[i];
    if (v) atomicAdd(&gbh[i], v);
  }
}

// exclusive scan of 782 bucket counts -> bbase[0..NBUCK], bcur=bbase
__global__ void k_escan(const int* __restrict__ gbh, int* __restrict__ bbase,
                        int* __restrict__ bcur) {
  __shared__ int a[256];
  int tid = threadIdx.x;
  int loc[4];
  int tsum = 0;
  for (int j = 0; j < 4; j++) {
    int idx = tid * 4 + j;
    int v = (idx < NBUCK) ? gbh[idx] : 0;
    loc[j] = tsum;
    tsum += v;
  }
  a[tid] = tsum;
  __syncthreads();
  for (int off = 1; off < 256; off <<= 1) {
    int v = (tid >= off) ? a[tid - off] : 0;
    __syncthreads();
    a[tid] += v;
    __syncthreads();
  }
  int excl = a[tid] - tsum;
  for (int j = 0; j < 4; j++) {
    int idx = tid * 4 + j;
    if (idx < NBUCK) {
      int v = excl + loc[j];
      bbase[idx] = v;
      bcur[idx] = v;
    }
  }
  if (tid == 255) bbase[NBUCK] = a[255];
}

// scatter (src,dst) pairs into bucket-contiguous ebuf; LDS-aggregated cursor grabs
__global__ void k_escatter(const int* __restrict__ src, const int* __restrict__ dst,
                           int* __restrict__ bcur, unsigned long long* __restrict__ ebuf) {
  __shared__ int lh[NBUCK];
  __shared__ int lbase[NBUCK];
  int tid = threadIdx.x;
  for (int i = tid; i < NBUCK; i += 256) lh[i] = 0;
  __syncthreads();
  int base = blockIdx.x * 4096;
  int sv[16], dv[16], rk[16];
#pragma unroll
  for (int j = 0; j < 16; j++) {
    int e = base + j * 256 + tid;
    if (e < NE) {
      sv[j] = src[e];
      dv[j] = dst[e];
      rk[j] = atomicAdd(&lh[dv[j] >> 7], 1);
    } else {
      dv[j] = -1;
    }
  }
  __syncthreads();
  for (int i = tid; i < NBUCK; i += 256) {
    int v = lh[i];
    lbase[i] = v ? atomicAdd(&bcur[i], v) : 0;
  }
  __syncthreads();
#pragma unroll
  for (int j = 0; j < 16; j++) {
    if (dv[j] >= 0) {
      int b = dv[j] >> 7;
      ebuf[lbase[b] + rk[j]] =
          (unsigned long long)(unsigned)sv[j] | ((unsigned long long)(unsigned)dv[j] << 32);
    }
  }
}

// one block per bucket: local hist -> rc(int2)/dinv, local scan, LDS-cursor fill -> col
__global__ void k_bucket_csr(const unsigned long long* __restrict__ ebuf,
                             const int* __restrict__ bbase, int2* __restrict__ rc,
                             float* __restrict__ dinv, int* __restrict__ col) {
  __shared__ int ldeg[NPB];
  __shared__ int lcur[NPB];
  __shared__ int sred[NPB];
  int b = blockIdx.x, tid = threadIdx.x;
  int nbase = b * NPB;
  int e0 = bbase[b], e1 = bbase[b + 1];
  if (tid < NPB) ldeg[tid] = 0;
  __syncthreads();
  for (int e = e0 + tid; e < e1; e += 256) {
    int d = (int)(ebuf[e] >> 32) - nbase;
    atomicAdd(&ldeg[d], 1);
  }
  __syncthreads();
  if (tid < NPB) sred[tid] = ldeg[tid];
  __syncthreads();
  for (int off = 1; off < NPB; off <<= 1) {
    int v = 0;
    if (tid < NPB && tid >= off) v = sred[tid - off];
    __syncthreads();
    if (tid < NPB) sred[tid] += v;
    __syncthreads();
  }
  if (tid < NPB) {
    int excl = sred[tid] - ldeg[tid];
    lcur[tid] = excl;
    int gn = nbase + tid;
    if (gn < NN) {
      int dg = ldeg[tid];
      rc[gn] = make_int2(e0 + excl, dg);
      dinv[gn] = rsqrtf((float)dg + 1.0f);
    }
  }
  __syncthreads();
  for (int e = e0 + tid; e < e1; e += 256) {
    unsigned long long p = ebuf[e];
    int s = (int)(unsigned)p;
    int d = (int)(p >> 32) - nbase;
    int r = atomicAdd(&lcur[d], 1);
    col[e0 + r] = s;
  }
}

// ------ mm A: X[nrows,128] @ W[128,64] -> Th (fp16) * dinv[row] ------------------
// 512 threads / 8 waves; 64 rows/block; col-EIGHTH per wave (readfirstlane ->
// s_load W). 12500 waves total (2x R7). Epilogue: 8 fp16 cols = one 16B store.
__global__ __launch_bounds__(512) void k_mmA(const float* __restrict__ X,
                                             const float* __restrict__ W,
                                             const float* __restrict__ dinv,
                                             __half* __restrict__ T, int nrows) {
  __shared__ float xs[64 * 65];
  int tid = threadIdx.x;
  int rbase = blockIdx.x * 64;
  int q8 = __builtin_amdgcn_readfirstlane(tid >> 6);  // wave-uniform col eighth
  int r = tid & 63;
  int r65 = r * 65;
  float4 acc[2];
  acc[0] = {0.f, 0.f, 0.f, 0.f};
  acc[1] = {0.f, 0.f, 0.f, 0.f};

  for (int ch = 0; ch < 2; ch++) {
#pragma unroll
    for (int i = 0; i < 2; i++) {
      int f = i * 512 + tid;
      int rr = f >> 4, kq = f & 15;
      int gr = rbase + rr;
      int grc = gr < nrows ? gr : nrows - 1;
      float4 v = *(const float4*)(X + (size_t)grc * 128 + ch * 64 + 4 * kq);
      float* p = xs + rr * 65 + 4 * kq;
      p[0] = v.x; p[1] = v.y; p[2] = v.z; p[3] = v.w;
    }
    __syncthreads();
    const float* Wb = W + ch * 64 * 64 + q8 * 8;
#pragma unroll 4
    for (int k = 0; k < 64; k++) {
      float xk = xs[r65 + k];
      const float4* wr = (const float4*)(Wb + (size_t)k * 64);
      float4 w0 = wr[0], w1 = wr[1];
      acc[0].x = fmaf(xk, w0.x, acc[0].x);
      acc[0].y = fmaf(xk, w0.y, acc[0].y);
      acc[0].z = fmaf(xk, w0.z, acc[0].z);
      acc[0].w = fmaf(xk, w0.w, acc[0].w);
      acc[1].x = fmaf(xk, w1.x, acc[1].x);
      acc[1].y = fmaf(xk, w1.y, acc[1].y);
      acc[1].z = fmaf(xk, w1.z, acc[1].z);
      acc[1].w = fmaf(xk, w1.w, acc[1].w);
    }
    if (ch == 0) __syncthreads();
  }

  int row = rbase + r;
  if (row < nrows) {
    float dv = dinv[row];
    __half2 o2[4];
    o2[0] = __floats2half2_rn(acc[0].x * dv, acc[0].y * dv);
    o2[1] = __floats2half2_rn(acc[0].z * dv, acc[0].w * dv);
    o2[2] = __floats2half2_rn(acc[1].x * dv, acc[1].y * dv);
    o2[3] = __floats2half2_rn(acc[1].z * dv, acc[1].w * dv);
    *(float4*)(T + (size_t)row * 64 + q8 * 8) = *(float4*)&o2[0];
  }
}

// ------ mm B: BN(G)(+res) -> Hside(fp32); Th = (h @ W)*dinv fp16 -----------------
// Same 512-thread / 8-wave / col-eighth structure, K=64 (single stage).
__global__ __launch_bounds__(512) void k_mmB(const float* __restrict__ G,
                                             const double* __restrict__ st,
                                             const float* __restrict__ gamma,
                                             const float* __restrict__ beta,
                                             const float* __restrict__ res,
                                             float* __restrict__ Hside,
                                             const float* __restrict__ W,
                                             const float* __restrict__ dinv,
                                             __half* __restrict__ T, int nrows) {
  __shared__ float xs[64 * 65];
  __shared__ float scl[128];
  int tid = threadIdx.x;
  if (tid < 64) {
    double m = st[tid] / (double)NN;
    double var = st[64 + tid] / (double)NN - m * m;
    float scale = gamma[tid] * rsqrtf((float)var + EPSF);
    scl[tid] = scale;
    scl[64 + tid] = beta[tid] - (float)m * scale;
  }
  __syncthreads();

  int rbase = blockIdx.x * 64;
#pragma unroll
  for (int i = 0; i < 2; i++) {
    int f = i * 512 + tid;
    int rr = f >> 4, kq = f & 15;
    int gr = rbase + rr;
    int grc = gr < nrows ? gr : nrows - 1;
    int kof = 4 * kq;
    float4 v = *(const float4*)(G + (size_t)grc * 64 + kof);
    float4 s = ((const float4*)scl)[kq];
    float4 sh = ((const float4*)(scl + 64))[kq];
    v.x = v.x * s.x + sh.x;
    v.y = v.y * s.y + sh.y;
    v.z = v.z * s.z + sh.z;
    v.w = v.w * s.w + sh.w;
    if (res != nullptr) {
      float4 rr2 = *(const float4*)(res + (size_t)grc * 64 + kof);
      v.x += rr2.x; v.y += rr2.y; v.z += rr2.z; v.w += rr2.w;
    }
    if (gr < nrows) *(float4*)(Hside + (size_t)gr * 64 + kof) = v;
    float* p = xs + rr * 65 + kof;
    p[0] = v.x; p[1] = v.y; p[2] = v.z; p[3] = v.w;
  }
  __syncthreads();

  int q8 = __builtin_amdgcn_readfirstlane(tid >> 6);
  int r = tid & 63;
  int r65 = r * 65;
  float4 acc[2];
  acc[0] = {0.f, 0.f, 0.f, 0.f};
  acc[1] = {0.f, 0.f, 0.f, 0.f};
  const float* Wb = W + q8 * 8;
#pragma unroll 4
  for (int k = 0; k < 64; k++) {
    float xk = xs[r65 + k];
    const float4* wr = (const float4*)(Wb + (size_t)k * 64);
    float4 w0 = wr[0], w1 = wr[1];
    acc[0].x = fmaf(xk, w0.x, acc[0].x);
    acc[0].y = fmaf(xk, w0.y, acc[0].y);
    acc[0].z = fmaf(xk, w0.z, acc[0].z);
    acc[0].w = fmaf(xk, w0.w, acc[0].w);
    acc[1].x = fmaf(xk, w1.x, acc[1].x);
    acc[1].y = fmaf(xk, w1.y, acc[1].y);
    acc[1].z = fmaf(xk, w1.z, acc[1].z);
    acc[1].w = fmaf(xk, w1.w, acc[1].w);
  }

  int row = rbase + r;
  if (row < nrows) {
    float dv = dinv[row];
    __half2 o2[4];
    o2[0] = __floats2half2_rn(acc[0].x * dv, acc[0].y * dv);
    o2[1] = __floats2half2_rn(acc[0].z * dv, acc[0].w * dv);
    o2[2] = __floats2half2_rn(acc[1].x * dv, acc[1].y * dv);
    o2[3] = __floats2half2_rn(acc[1].z * dv, acc[1].w * dv);
    *(float4*)(T + (size_t)row * 64 + q8 * 8) = *(float4*)&o2[0];
  }
}

// ---------------- aggregation (HID=64): wave/node, fp16 gather, fp32 accum --------
// Th is pre-scaled by dinv[row]: o = di*(sum Th[src] + Th[node]) + bias
__global__ void k_agg64(const __half* __restrict__ T, const int2* __restrict__ rc,
                        const int* __restrict__ col, const float* __restrict__ dinv,
                        const float* __restrict__ bias, float* __restrict__ G,
                        int relu) {
  int lane = threadIdx.x & 63;
  int wv = threadIdx.x >> 6;
  int node = blockIdx.x * 4 + wv;
  if (node >= NN) return;
  int grp = lane >> 4;
  int q = lane & 15;
  int2 sc = rc[node];
  int s = sc.x;
  int c = sc.y;
  float4 acc = {0.f, 0.f, 0.f, 0.f};
  for (int i = 0; i < c; i += 16) {
    int j0 = i + grp, j1 = j0 + 4, j2 = j0 + 8, j3 = j0 + 12;
    int s0 = col[s + (j0 < c ? j0 : 0)];
    int s1 = col[s + (j1 < c ? j1 : 0)];
    int s2 = col[s + (j2 < c ? j2 : 0)];
    int s3 = col[s + (j3 < c ? j3 : 0)];
    float2 r0 = *(const float2*)(T + (size_t)s0 * 64 + q * 4);
    float2 r1 = *(const float2*)(T + (size_t)s1 * 64 + q * 4);
    float2 r2 = *(const float2*)(T + (size_t)s2 * 64 + q * 4);
    float2 r3 = *(const float2*)(T + (size_t)s3 * 64 + q * 4);
    float w0 = j0 < c ? 1.f : 0.f;
    float w1 = j1 < c ? 1.f : 0.f;
    float w2 = j2 < c ? 1.f : 0.f;
    float w3 = j3 < c ? 1.f : 0.f;
    {
      __half2* p = (__half2*)&r0;
      float2 lo = __half22float2(p[0]), hi = __half22float2(p[1]);
      acc.x = fmaf(w0, lo.x, acc.x); acc.y = fmaf(w0, lo.y, acc.y);
      acc.z = fmaf(w0, hi.x, acc.z); acc.w = fmaf(w0, hi.y, acc.w);
    }
    {
      __half2* p = (__half2*)&r1;
      float2 lo = __half22float2(p[0]), hi = __half22float2(p[1]);
      acc.x = fmaf(w1, lo.x, acc.x); acc.y = fmaf(w1, lo.y, acc.y);
      acc.z = fmaf(w1, hi.x, acc.z); acc.w = fmaf(w1, hi.y, acc.w);
    }
    {
      __half2* p = (__half2*)&r2;
      float2 lo = __half22float2(p[0]), hi = __half22float2(p[1]);
      acc.x = fmaf(w2, lo.x, acc.x); acc.y = fmaf(w2, lo.y, acc.y);
      acc.z = fmaf(w2, hi.x, acc.z); acc.w = fmaf(w2, hi.y, acc.w);
    }
    {
      __half2* p = (__half2*)&r3;
      float2 lo = __half22float2(p[0]), hi = __half22float2(p[1]);
      acc.x = fmaf(w3, lo.x, acc.x); acc.y = fmaf(w3, lo.y, acc.y);
      acc.z = fmaf(w3, hi.x, acc.z); acc.w = fmaf(w3, hi.y, acc.w);
    }
  }
  acc.x += __shfl_xor(acc.x, 16, 64);
  acc.y += __shfl_xor(acc.y, 16, 64);
  acc.z += __shfl_xor(acc.z, 16, 64);
  acc.w += __shfl_xor(acc.w, 16, 64);
  acc.x += __shfl_xor(acc.x, 32, 64);
  acc.y += __shfl_xor(acc.y, 32, 64);
  acc.z += __shfl_xor(acc.z, 32, 64);
  acc.w += __shfl_xor(acc.w, 32, 64);
  if (grp == 0) {
    float di = dinv[node];
    float2 rs = *(const float2*)(T + (size_t)node * 64 + q * 4);
    __half2* p = (__half2*)&rs;
    float2 lo = __half22float2(p[0]), hi = __half22float2(p[1]);
    float4 bs = ((const float4*)bias)[q];
    float4 o;
    o.x = (acc.x + lo.x) * di + bs.x;
    o.y = (acc.y + lo.y) * di + bs.y;
    o.z = (acc.z + hi.x) * di + bs.z;
    o.w = (acc.w + hi.y) * di + bs.w;
    if (relu) {
      o.x = fmaxf(o.x, 0.f);
      o.y = fmaxf(o.y, 0.f);
      o.z = fmaxf(o.z, 0.f);
      o.w = fmaxf(o.w, 0.f);
    }
    ((float4*)(G + (size_t)node * 64))[q] = o;
  }
}

// ---------------- BN stats (float4 vectorized) ----------------
__global__ __launch_bounds__(256) void k_stats(const float* __restrict__ H,
                                               double* __restrict__ st) {
  int q = threadIdx.x & 15;   // feature quarter (4 floats)
  int rg = threadIdx.x >> 4;  // 16 row-groups per block
  float4 s1 = {0.f, 0.f, 0.f, 0.f};
  float4 s2 = {0.f, 0.f, 0.f, 0.f};
  for (int r = blockIdx.x * 16 + rg; r < NN; r += gridDim.x * 16) {
    float4 v = *(const float4*)(H + (size_t)r * 64 + q * 4);
    s1.x += v.x; s1.y += v.y; s1.z += v.z; s1.w += v.w;
    s2.x = fmaf(v.x, v.x, s2.x); s2.y = fmaf(v.y, v.y, s2.y);
    s2.z = fmaf(v.z, v.z, s2.z); s2.w = fmaf(v.w, v.w, s2.w);
  }
  __shared__ float a[16][16][8];
  a[rg][q][0] = s1.x; a[rg][q][1] = s1.y; a[rg][q][2] = s1.z; a[rg][q][3] = s1.w;
  a[rg][q][4] = s2.x; a[rg][q][5] = s2.y; a[rg][q][6] = s2.z; a[rg][q][7] = s2.w;
  __syncthreads();
  int tid = threadIdx.x;
  if (tid < 128) {
    int f = tid & 63;        // feature
    int which = tid >> 6;    // 0 = sum, 1 = sumsq
    int qq = f >> 2, jj = (f & 3) + which * 4;
    float t = 0.f;
#pragma unroll
    for (int g = 0; g < 16; g++) t += a[g][qq][jj];
    unsafeAtomicAdd(&st[which * 64 + f], (double)t);
  }
}

// ---------------- fused: BN3 (in-block scale) + residual + matmul 64->2, T2 *= dinv --
__global__ void k_bnmmout(const float* __restrict__ G, const double* __restrict__ st,
                          const float* __restrict__ gamma, const float* __restrict__ beta,
                          const float* __restrict__ res, const float* __restrict__ W,
                          const float* __restrict__ dinv, float* __restrict__ T2,
                          int nrows) {
  __shared__ float Wl[128];
  __shared__ float scl[128];
  int tid = threadIdx.x;
  if (tid < 32) ((float4*)Wl)[tid] = ((const float4*)W)[tid];
  else if (tid >= 64 && tid < 128) {
    int f = tid - 64;
    double m = st[f] / (double)NN;
    double var = st[64 + f] / (double)NN - m * m;
    float scale = gamma[f] * rsqrtf((float)var + EPSF);
    scl[f] = scale;
    scl[64 + f] = beta[f] - (float)m * scale;
  }
  __syncthreads();
  int row = blockIdx.x * 256 + tid;
  if (row >= nrows) return;
  const float4* g4 = (const float4*)(G + (size_t)row * 64);
  const float4* r4 = (const float4*)(res + (size_t)row * 64);
  float a0 = 0.f, a1 = 0.f;
#pragma unroll
  for (int q = 0; q < 16; q++) {
    float4 v = g4[q];
    float4 rr = r4[q];
    float4 s = ((const float4*)scl)[q];
    float4 sh = ((const float4*)(scl + 64))[q];
    float h0 = v.x * s.x + sh.x + rr.x;
    float h1 = v.y * s.y + sh.y + rr.y;
    float h2 = v.z * s.z + sh.z + rr.z;
    float h3 = v.w * s.w + sh.w + rr.w;
    const float* wk = Wl + q * 8;
    a0 = fmaf(h0, wk[0], a0); a1 = fmaf(h0, wk[1], a1);
    a0 = fmaf(h1, wk[2], a0); a1 = fmaf(h1, wk[3], a1);
    a0 = fmaf(h2, wk[4], a0); a1 = fmaf(h2, wk[5], a1);
    a0 = fmaf(h3, wk[6], a0); a1 = fmaf(h3, wk[7], a1);
  }
  float dv = dinv[row];
  T2[(size_t)row * 2 + 0] = a0 * dv;
  T2[(size_t)row * 2 + 1] = a1 * dv;
}

// ---- fused final aggregation (dim 2, T2 pre-scaled) + pool + ticket finalize ----
__global__ void k_agg2pool(const float* __restrict__ T2, const int2* __restrict__ rc,
                           const int* __restrict__ col, const float* __restrict__ dinv,
                           const float* __restrict__ bias, const int* __restrict__ batch,
                           float* __restrict__ pool, int* __restrict__ pcnt,
                           int* __restrict__ tick, float* __restrict__ out, int nblk) {
  __shared__ float pl[128];
  __shared__ int pc[64];
  __shared__ int lastflag;
  int tid = threadIdx.x;
  if (tid < 128) pl[tid] = 0.f;
  if (tid < 64) pc[tid] = 0;
  __syncthreads();
  int node = blockIdx.x * 256 + tid;
  if (node < NN) {
    int2 sc = rc[node];
    int s = sc.x;
    int c = sc.y;
    float a0 = 0.f, a1 = 0.f;
    for (int i = 0; i < c; i += 4) {
      int j0 = i, j1 = i + 1, j2 = i + 2, j3 = i + 3;
      int s0 = col[s + j0];
      int sA = col[s + (j1 < c ? j1 : j0)];
      int sB = col[s + (j2 < c ? j2 : j0)];
      int sC = col[s + (j3 < c ? j3 : j0)];
      float2 t0 = *(const float2*)(T2 + 2 * (size_t)s0);
      float2 t1 = *(const float2*)(T2 + 2 * (size_t)sA);
      float2 t2 = *(const float2*)(T2 + 2 * (size_t)sB);
      float2 t3 = *(const float2*)(T2 + 2 * (size_t)sC);
      float w1 = j1 < c ? 1.f : 0.f;
      float w2 = j2 < c ? 1.f : 0.f;
      float w3 = j3 < c ? 1.f : 0.f;
      a0 += t0.x; a1 += t0.y;
      a0 = fmaf(w1, t1.x, a0); a1 = fmaf(w1, t1.y, a1);
      a0 = fmaf(w2, t2.x, a0); a1 = fmaf(w2, t2.y, a1);
      a0 = fmaf(w3, t3.x, a0); a1 = fmaf(w3, t3.y, a1);
    }
    float di = dinv[node];
    float2 tn = *(const float2*)(T2 + 2 * (size_t)node);
    float v0 = (a0 + tn.x) * di + bias[0];
    float v1 = (a1 + tn.y) * di + bias[1];
    int bb = batch[node];
    atomicAdd(&pl[bb * 2 + 0], v0);
    atomicAdd(&pl[bb * 2 + 1], v1);
    atomicAdd(&pc[bb], 1);
  }
  __syncthreads();
  if (tid < 128 && pl[tid] != 0.f) unsafeAtomicAdd(&pool[tid], pl[tid]);
  if (tid < 64 && pc[tid] != 0) atomicAdd(&pcnt[tid], pc[tid]);
  __syncthreads();
  if (tid == 0) {
    __threadfence();
    int old = atomicAdd(tick, 1);
    lastflag = (old == nblk - 1) ? 1 : 0;
  }
  __syncthreads();
  if (lastflag && tid < 128) {
    float v = unsafeAtomicAdd(&pool[tid], 0.f);       // coherent read
    int c = atomicAdd(&pcnt[tid >> 1], 0);            // coherent read
    out[tid] = v / (float)(c > 0 ? c : 1);
  }
}

extern "C" void kernel_launch(void* const* d_in, const int* in_sizes, int n_in,
                              void* d_out, int out_size, void* d_ws, size_t ws_size,
                              hipStream_t stream) {
  (void)in_sizes; (void)n_in; (void)out_size; (void)ws_size;
  const float* x     = (const float*)d_in[0];
  const float* W_in  = (const float*)d_in[1];
  const float* b_in  = (const float*)d_in[2];
  const float* W_h   = (const float*)d_in[3];
  const float* b_h   = (const float*)d_in[4];
  const float* W_out = (const float*)d_in[5];
  const float* b_out = (const float*)d_in[6];
  const float* gamma = (const float*)d_in[7];
  const float* beta  = (const float*)d_in[8];
  const int*   ei    = (const int*)d_in[9];
  const int*   batch = (const int*)d_in[10];
  const int* src = ei;
  const int* dst = ei + NE;
  float* out = (float*)d_out;

  char* w = (char*)d_ws;
  size_t off = 0;
  auto alloc = [&](size_t bytes) -> void* {
    void* p = (void*)(w + off);
    off += (bytes + 511) & ~(size_t)511;
    return p;
  };
  int2*   rc    = (int2*)alloc((size_t)NN * 8);
  int*    col   = (int*)alloc((size_t)NE * 4);
  float*  dinv  = (float*)alloc((size_t)NN * 4);
  int*    bbase = (int*)alloc((NBUCK + 1) * 4);
  int*    bcur  = (int*)alloc(NBUCK * 4);
  // zeroed zone: stats (3*128 dbl = 3072) | pool (512) | pcnt (256) | tick (256) |
  //              gbh (782*4 = 3128) -> 7224 bytes
  char*   zzone = (char*)alloc(7680);
  double* stats = (double*)zzone;
  float*  pool  = (float*)(zzone + 3072);
  int*    pcnt  = (int*)(zzone + 3584);
  int*    tick  = (int*)(zzone + 3840);
  int*    gbh   = (int*)(zzone + 4096);
  float*  buf0  = (float*)alloc((size_t)NN * HID * 4);
  float*  buf1  = (float*)alloc((size_t)NN * HID * 4);
  float*  buf2  = (float*)alloc((size_t)NN * HID * 4);
  __half* Th    = (__half*)alloc((size_t)NN * HID * 2);
  float*  T2    = (float*)alloc((size_t)NN * 2 * 4);
  // ebuf (9.6MB) aliases buf0: consumed by k_bucket_csr; buf0's first write is G2 (step 5)
  unsigned long long* ebuf = (unsigned long long*)buf0;

  hipMemsetAsync(zzone, 0, 7424, stream);

  // graph prep: bucket-radix CSR build
  k_ehist<<<293, 256, 0, stream>>>(dst, gbh);
  k_escan<<<1, 256, 0, stream>>>(gbh, bbase, bcur);
  k_escatter<<<293, 256, 0, stream>>>(src, dst, bcur, ebuf);
  k_bucket_csr<<<NBUCK, 256, 0, stream>>>(ebuf, bbase, rc, dinv, col);

  const int mmgrid = (NN + 63) / 64;   // 1563

  // layer 1: x(128) -> Th (fp16, pre-scaled) -> G1=buf1
  k_mmA<<<mmgrid, 512, 0, stream>>>(x, W_in, dinv, Th, NN);
  k_agg64<<<(NN + 3) / 4, 256, 0, stream>>>(Th, rc, col, dinv, b_in, buf1, 1);
  k_stats<<<512, 256, 0, stream>>>(buf1, stats);

  // layer 2: h1 = BN1(G1) (side-> buf2); Th = h1@W_h0; G2 = buf0
  k_mmB<<<mmgrid, 512, 0, stream>>>(buf1, stats, gamma, beta, nullptr, buf2, W_h,
                                    dinv, Th, NN);
  k_agg64<<<(NN + 3) / 4, 256, 0, stream>>>(Th, rc, col, dinv, b_h, buf0, 1);
  k_stats<<<512, 256, 0, stream>>>(buf0, stats + 128);

  // layer 3: h2 = BN2(G2)+h1 (side-> buf1); Th = h2@W_h1; G3 = buf2
  k_mmB<<<mmgrid, 512, 0, stream>>>(buf0, stats + 128, gamma + 64, beta + 64, buf2,
                                    buf1, W_h + HID * HID, dinv, Th, NN);
  k_agg64<<<(NN + 3) / 4, 256, 0, stream>>>(Th, rc, col, dinv, b_h + HID, buf2, 1);
  k_stats<<<512, 256, 0, stream>>>(buf2, stats + 256);

  // output: h3 = BN3(G3)+h2(buf1) fused with mm 64->2 (T2 pre-scaled), then agg+pool+div
  k_bnmmout<<<(NN + 255) / 256, 256, 0, stream>>>(buf2, stats + 256, gamma + 128,
                                                  beta + 128, buf1, W_out, dinv, T2, NN);
  const int pgrid = (NN + 255) / 256;  // 391
  k_agg2pool<<<pgrid, 256, 0, stream>>>(T2, rc, col, dinv, b_out, batch, pool,
                                        pcnt, tick, out, pgrid);
}

// Round 13
// 382.395 us; speedup vs baseline: 1.1780x; 1.0262x over previous
//
#include <hip/hip_runtime.h>
#include <hip/hip_fp16.h>

// EnhancedGNN on MI355X.
// R15: CSR build shortened: buckets get fixed 2048-edge slots (13-sigma headroom
//      over mean 1536), so the global histogram (k_ehist) + exclusive scan
//      (k_escan) that made buckets contiguous are deleted -- escatter grabs
//      per-bucket bases from 782 global atomic cursors, bucket_csr writes
//      rowp = b*2048 + local_excl. R14's fp16-T gather + 512-thread mm kept.
//      13 launches.

#define NN 100000
#define NE 1200000
#define NBATCH 64
#define IND 128
#define HID 64
#define EPSF 1e-5f
#define NBUCK 782   // ceil(100000/128)
#define NPB 128     // nodes per bucket; bucket(d) = d >> 7
#define BCAP 2048   // slot capacity per bucket (mean 1536, sigma 39)

// scatter (src,dst) pairs into per-bucket SLOTS of ebuf; LDS hist + global cursor
__global__ void k_escatter(const int* __restrict__ src, const int* __restrict__ dst,
                           int* __restrict__ bcur, unsigned long long* __restrict__ ebuf) {
  __shared__ int lh[NBUCK];
  __shared__ int lbase[NBUCK];
  int tid = threadIdx.x;
  for (int i = tid; i < NBUCK; i += 256) lh[i] = 0;
  __syncthreads();
  int base = blockIdx.x * 4096;
  int sv[16], dv[16], rk[16];
#pragma unroll
  for (int j = 0; j < 16; j++) {
    int e = base + j * 256 + tid;
    if (e < NE) {
      sv[j] = src[e];
      dv[j] = dst[e];
      rk[j] = atomicAdd(&lh[dv[j] >> 7], 1);
    } else {
      dv[j] = -1;
    }
  }
  __syncthreads();
  for (int i = tid; i < NBUCK; i += 256) {
    int v = lh[i];
    lbase[i] = v ? atomicAdd(&bcur[i], v) : 0;
  }
  __syncthreads();
#pragma unroll
  for (int j = 0; j < 16; j++) {
    if (dv[j] >= 0) {
      int b = dv[j] >> 7;
      ebuf[(size_t)b * BCAP + lbase[b] + rk[j]] =
          (unsigned long long)(unsigned)sv[j] | ((unsigned long long)(unsigned)dv[j] << 32);
    }
  }
}

// one block per bucket: local hist -> rc(int2)/dinv, local scan, LDS-cursor fill -> col
// (slotted: bucket b owns ebuf/col range [b*BCAP, b*BCAP+cnt))
__global__ void k_bucket_csr(const unsigned long long* __restrict__ ebuf,
                             const int* __restrict__ bcur, int2* __restrict__ rc,
                             float* __restrict__ dinv, int* __restrict__ col) {
  __shared__ int ldeg[NPB];
  __shared__ int lcur[NPB];
  __shared__ int sred[NPB];
  int b = blockIdx.x, tid = threadIdx.x;
  int nbase = b * NPB;
  int e0 = b * BCAP;
  int cnt = bcur[b];
  if (tid < NPB) ldeg[tid] = 0;
  __syncthreads();
  for (int e = tid; e < cnt; e += 256) {
    int d = (int)(ebuf[e0 + e] >> 32) - nbase;
    atomicAdd(&ldeg[d], 1);
  }
  __syncthreads();
  if (tid < NPB) sred[tid] = ldeg[tid];
  __syncthreads();
  for (int off = 1; off < NPB; off <<= 1) {
    int v = 0;
    if (tid < NPB && tid >= off) v = sred[tid - off];
    __syncthreads();
    if (tid < NPB) sred[tid] += v;
    __syncthreads();
  }
  if (tid < NPB) {
    int excl = sred[tid] - ldeg[tid];
    lcur[tid] = excl;
    int gn = nbase + tid;
    if (gn < NN) {
      int dg = ldeg[tid];
      rc[gn] = make_int2(e0 + excl, dg);
      dinv[gn] = rsqrtf((float)dg + 1.0f);
    }
  }
  __syncthreads();
  for (int e = tid; e < cnt; e += 256) {
    unsigned long long p = ebuf[e0 + e];
    int s = (int)(unsigned)p;
    int d = (int)(p >> 32) - nbase;
    int r = atomicAdd(&lcur[d], 1);
    col[e0 + r] = s;
  }
}

// ------ mm A: X[nrows,128] @ W[128,64] -> Th (fp16) * dinv[row] ------------------
// 512 threads / 8 waves; 64 rows/block; col-EIGHTH per wave (readfirstlane ->
// s_load W). 12500 waves total. Epilogue: 8 fp16 cols = one 16B store.
__global__ __launch_bounds__(512) void k_mmA(const float* __restrict__ X,
                                             const float* __restrict__ W,
                                             const float* __restrict__ dinv,
                                             __half* __restrict__ T, int nrows) {
  __shared__ float xs[64 * 65];
  int tid = threadIdx.x;
  int rbase = blockIdx.x * 64;
  int q8 = __builtin_amdgcn_readfirstlane(tid >> 6);  // wave-uniform col eighth
  int r = tid & 63;
  int r65 = r * 65;
  float4 acc[2];
  acc[0] = {0.f, 0.f, 0.f, 0.f};
  acc[1] = {0.f, 0.f, 0.f, 0.f};

  for (int ch = 0; ch < 2; ch++) {
#pragma unroll
    for (int i = 0; i < 2; i++) {
      int f = i * 512 + tid;
      int rr = f >> 4, kq = f & 15;
      int gr = rbase + rr;
      int grc = gr < nrows ? gr : nrows - 1;
      float4 v = *(const float4*)(X + (size_t)grc * 128 + ch * 64 + 4 * kq);
      float* p = xs + rr * 65 + 4 * kq;
      p[0] = v.x; p[1] = v.y; p[2] = v.z; p[3] = v.w;
    }
    __syncthreads();
    const float* Wb = W + ch * 64 * 64 + q8 * 8;
#pragma unroll 4
    for (int k = 0; k < 64; k++) {
      float xk = xs[r65 + k];
      const float4* wr = (const float4*)(Wb + (size_t)k * 64);
      float4 w0 = wr[0], w1 = wr[1];
      acc[0].x = fmaf(xk, w0.x, acc[0].x);
      acc[0].y = fmaf(xk, w0.y, acc[0].y);
      acc[0].z = fmaf(xk, w0.z, acc[0].z);
      acc[0].w = fmaf(xk, w0.w, acc[0].w);
      acc[1].x = fmaf(xk, w1.x, acc[1].x);
      acc[1].y = fmaf(xk, w1.y, acc[1].y);
      acc[1].z = fmaf(xk, w1.z, acc[1].z);
      acc[1].w = fmaf(xk, w1.w, acc[1].w);
    }
    if (ch == 0) __syncthreads();
  }

  int row = rbase + r;
  if (row < nrows) {
    float dv = dinv[row];
    __half2 o2[4];
    o2[0] = __floats2half2_rn(acc[0].x * dv, acc[0].y * dv);
    o2[1] = __floats2half2_rn(acc[0].z * dv, acc[0].w * dv);
    o2[2] = __floats2half2_rn(acc[1].x * dv, acc[1].y * dv);
    o2[3] = __floats2half2_rn(acc[1].z * dv, acc[1].w * dv);
    *(float4*)(T + (size_t)row * 64 + q8 * 8) = *(float4*)&o2[0];
  }
}

// ------ mm B: BN(G)(+res) -> Hside(fp32); Th = (h @ W)*dinv fp16 -----------------
__global__ __launch_bounds__(512) void k_mmB(const float* __restrict__ G,
                                             const double* __restrict__ st,
                                             const float* __restrict__ gamma,
                                             const float* __restrict__ beta,
                                             const float* __restrict__ res,
                                             float* __restrict__ Hside,
                                             const float* __restrict__ W,
                                             const float* __restrict__ dinv,
                                             __half* __restrict__ T, int nrows) {
  __shared__ float xs[64 * 65];
  __shared__ float scl[128];
  int tid = threadIdx.x;
  if (tid < 64) {
    double m = st[tid] / (double)NN;
    double var = st[64 + tid] / (double)NN - m * m;
    float scale = gamma[tid] * rsqrtf((float)var + EPSF);
    scl[tid] = scale;
    scl[64 + tid] = beta[tid] - (float)m * scale;
  }
  __syncthreads();

  int rbase = blockIdx.x * 64;
#pragma unroll
  for (int i = 0; i < 2; i++) {
    int f = i * 512 + tid;
    int rr = f >> 4, kq = f & 15;
    int gr = rbase + rr;
    int grc = gr < nrows ? gr : nrows - 1;
    int kof = 4 * kq;
    float4 v = *(const float4*)(G + (size_t)grc * 64 + kof);
    float4 s = ((const float4*)scl)[kq];
    float4 sh = ((const float4*)(scl + 64))[kq];
    v.x = v.x * s.x + sh.x;
    v.y = v.y * s.y + sh.y;
    v.z = v.z * s.z + sh.z;
    v.w = v.w * s.w + sh.w;
    if (res != nullptr) {
      float4 rr2 = *(const float4*)(res + (size_t)grc * 64 + kof);
      v.x += rr2.x; v.y += rr2.y; v.z += rr2.z; v.w += rr2.w;
    }
    if (gr < nrows) *(float4*)(Hside + (size_t)gr * 64 + kof) = v;
    float* p = xs + rr * 65 + kof;
    p[0] = v.x; p[1] = v.y; p[2] = v.z; p[3] = v.w;
  }
  __syncthreads();

  int q8 = __builtin_amdgcn_readfirstlane(tid >> 6);
  int r = tid & 63;
  int r65 = r * 65;
  float4 acc[2];
  acc[0] = {0.f, 0.f, 0.f, 0.f};
  acc[1] = {0.f, 0.f, 0.f, 0.f};
  const float* Wb = W + q8 * 8;
#pragma unroll 4
  for (int k = 0; k < 64; k++) {
    float xk = xs[r65 + k];
    const float4* wr = (const float4*)(Wb + (size_t)k * 64);
    float4 w0 = wr[0], w1 = wr[1];
    acc[0].x = fmaf(xk, w0.x, acc[0].x);
    acc[0].y = fmaf(xk, w0.y, acc[0].y);
    acc[0].z = fmaf(xk, w0.z, acc[0].z);
    acc[0].w = fmaf(xk, w0.w, acc[0].w);
    acc[1].x = fmaf(xk, w1.x, acc[1].x);
    acc[1].y = fmaf(xk, w1.y, acc[1].y);
    acc[1].z = fmaf(xk, w1.z, acc[1].z);
    acc[1].w = fmaf(xk, w1.w, acc[1].w);
  }

  int row = rbase + r;
  if (row < nrows) {
    float dv = dinv[row];
    __half2 o2[4];
    o2[0] = __floats2half2_rn(acc[0].x * dv, acc[0].y * dv);
    o2[1] = __floats2half2_rn(acc[0].z * dv, acc[0].w * dv);
    o2[2] = __floats2half2_rn(acc[1].x * dv, acc[1].y * dv);
    o2[3] = __floats2half2_rn(acc[1].z * dv, acc[1].w * dv);
    *(float4*)(T + (size_t)row * 64 + q8 * 8) = *(float4*)&o2[0];
  }
}

// ---------------- aggregation (HID=64): wave/node, fp16 gather, fp32 accum --------
// Th is pre-scaled by dinv[row]: o = di*(sum Th[src] + Th[node]) + bias
__global__ void k_agg64(const __half* __restrict__ T, const int2* __restrict__ rc,
                        const int* __restrict__ col, const float* __restrict__ dinv,
                        const float* __restrict__ bias, float* __restrict__ G,
                        int relu) {
  int lane = threadIdx.x & 63;
  int wv = threadIdx.x >> 6;
  int node = blockIdx.x * 4 + wv;
  if (node >= NN) return;
  int grp = lane >> 4;
  int q = lane & 15;
  int2 sc = rc[node];
  int s = sc.x;
  int c = sc.y;
  float4 acc = {0.f, 0.f, 0.f, 0.f};
  for (int i = 0; i < c; i += 16) {
    int j0 = i + grp, j1 = j0 + 4, j2 = j0 + 8, j3 = j0 + 12;
    int s0 = col[s + (j0 < c ? j0 : 0)];
    int s1 = col[s + (j1 < c ? j1 : 0)];
    int s2 = col[s + (j2 < c ? j2 : 0)];
    int s3 = col[s + (j3 < c ? j3 : 0)];
    float2 r0 = *(const float2*)(T + (size_t)s0 * 64 + q * 4);
    float2 r1 = *(const float2*)(T + (size_t)s1 * 64 + q * 4);
    float2 r2 = *(const float2*)(T + (size_t)s2 * 64 + q * 4);
    float2 r3 = *(const float2*)(T + (size_t)s3 * 64 + q * 4);
    float w0 = j0 < c ? 1.f : 0.f;
    float w1 = j1 < c ? 1.f : 0.f;
    float w2 = j2 < c ? 1.f : 0.f;
    float w3 = j3 < c ? 1.f : 0.f;
    {
      __half2* p = (__half2*)&r0;
      float2 lo = __half22float2(p[0]), hi = __half22float2(p[1]);
      acc.x = fmaf(w0, lo.x, acc.x); acc.y = fmaf(w0, lo.y, acc.y);
      acc.z = fmaf(w0, hi.x, acc.z); acc.w = fmaf(w0, hi.y, acc.w);
    }
    {
      __half2* p = (__half2*)&r1;
      float2 lo = __half22float2(p[0]), hi = __half22float2(p[1]);
      acc.x = fmaf(w1, lo.x, acc.x); acc.y = fmaf(w1, lo.y, acc.y);
      acc.z = fmaf(w1, hi.x, acc.z); acc.w = fmaf(w1, hi.y, acc.w);
    }
    {
      __half2* p = (__half2*)&r2;
      float2 lo = __half22float2(p[0]), hi = __half22float2(p[1]);
      acc.x = fmaf(w2, lo.x, acc.x); acc.y = fmaf(w2, lo.y, acc.y);
      acc.z = fmaf(w2, hi.x, acc.z); acc.w = fmaf(w2, hi.y, acc.w);
    }
    {
      __half2* p = (__half2*)&r3;
      float2 lo = __half22float2(p[0]), hi = __half22float2(p[1]);
      acc.x = fmaf(w3, lo.x, acc.x); acc.y = fmaf(w3, lo.y, acc.y);
      acc.z = fmaf(w3, hi.x, acc.z); acc.w = fmaf(w3, hi.y, acc.w);
    }
  }
  acc.x += __shfl_xor(acc.x, 16, 64);
  acc.y += __shfl_xor(acc.y, 16, 64);
  acc.z += __shfl_xor(acc.z, 16, 64);
  acc.w += __shfl_xor(acc.w, 16, 64);
  acc.x += __shfl_xor(acc.x, 32, 64);
  acc.y += __shfl_xor(acc.y, 32, 64);
  acc.z += __shfl_xor(acc.z, 32, 64);
  acc.w += __shfl_xor(acc.w, 32, 64);
  if (grp == 0) {
    float di = dinv[node];
    float2 rs = *(const float2*)(T + (size_t)node * 64 + q * 4);
    __half2* p = (__half2*)&rs;
    float2 lo = __half22float2(p[0]), hi = __half22float2(p[1]);
    float4 bs = ((const float4*)bias)[q];
    float4 o;
    o.x = (acc.x + lo.x) * di + bs.x;
    o.y = (acc.y + lo.y) * di + bs.y;
    o.z = (acc.z + hi.x) * di + bs.z;
    o.w = (acc.w + hi.y) * di + bs.w;
    if (relu) {
      o.x = fmaxf(o.x, 0.f);
      o.y = fmaxf(o.y, 0.f);
      o.z = fmaxf(o.z, 0.f);
      o.w = fmaxf(o.w, 0.f);
    }
    ((float4*)(G + (size_t)node * 64))[q] = o;
  }
}

// ---------------- BN stats (float4 vectorized) ----------------
__global__ __launch_bounds__(256) void k_stats(const float* __restrict__ H,
                                               double* __restrict__ st) {
  int q = threadIdx.x & 15;   // feature quarter (4 floats)
  int rg = threadIdx.x >> 4;  // 16 row-groups per block
  float4 s1 = {0.f, 0.f, 0.f, 0.f};
  float4 s2 = {0.f, 0.f, 0.f, 0.f};
  for (int r = blockIdx.x * 16 + rg; r < NN; r += gridDim.x * 16) {
    float4 v = *(const float4*)(H + (size_t)r * 64 + q * 4);
    s1.x += v.x; s1.y += v.y; s1.z += v.z; s1.w += v.w;
    s2.x = fmaf(v.x, v.x, s2.x); s2.y = fmaf(v.y, v.y, s2.y);
    s2.z = fmaf(v.z, v.z, s2.z); s2.w = fmaf(v.w, v.w, s2.w);
  }
  __shared__ float a[16][16][8];
  a[rg][q][0] = s1.x; a[rg][q][1] = s1.y; a[rg][q][2] = s1.z; a[rg][q][3] = s1.w;
  a[rg][q][4] = s2.x; a[rg][q][5] = s2.y; a[rg][q][6] = s2.z; a[rg][q][7] = s2.w;
  __syncthreads();
  int tid = threadIdx.x;
  if (tid < 128) {
    int f = tid & 63;        // feature
    int which = tid >> 6;    // 0 = sum, 1 = sumsq
    int qq = f >> 2, jj = (f & 3) + which * 4;
    float t = 0.f;
#pragma unroll
    for (int g = 0; g < 16; g++) t += a[g][qq][jj];
    unsafeAtomicAdd(&st[which * 64 + f], (double)t);
  }
}

// ---------------- fused: BN3 (in-block scale) + residual + matmul 64->2, T2 *= dinv --
__global__ void k_bnmmout(const float* __restrict__ G, const double* __restrict__ st,
                          const float* __restrict__ gamma, const float* __restrict__ beta,
                          const float* __restrict__ res, const float* __restrict__ W,
                          const float* __restrict__ dinv, float* __restrict__ T2,
                          int nrows) {
  __shared__ float Wl[128];
  __shared__ float scl[128];
  int tid = threadIdx.x;
  if (tid < 32) ((float4*)Wl)[tid] = ((const float4*)W)[tid];
  else if (tid >= 64 && tid < 128) {
    int f = tid - 64;
    double m = st[f] / (double)NN;
    double var = st[64 + f] / (double)NN - m * m;
    float scale = gamma[f] * rsqrtf((float)var + EPSF);
    scl[f] = scale;
    scl[64 + f] = beta[f] - (float)m * scale;
  }
  __syncthreads();
  int row = blockIdx.x * 256 + tid;
  if (row >= nrows) return;
  const float4* g4 = (const float4*)(G + (size_t)row * 64);
  const float4* r4 = (const float4*)(res + (size_t)row * 64);
  float a0 = 0.f, a1 = 0.f;
#pragma unroll
  for (int q = 0; q < 16; q++) {
    float4 v = g4[q];
    float4 rr = r4[q];
    float4 s = ((const float4*)scl)[q];
    float4 sh = ((const float4*)(scl + 64))[q];
    float h0 = v.x * s.x + sh.x + rr.x;
    float h1 = v.y * s.y + sh.y + rr.y;
    float h2 = v.z * s.z + sh.z + rr.z;
    float h3 = v.w * s.w + sh.w + rr.w;
    const float* wk = Wl + q * 8;
    a0 = fmaf(h0, wk[0], a0); a1 = fmaf(h0, wk[1], a1);
    a0 = fmaf(h1, wk[2], a0); a1 = fmaf(h1, wk[3], a1);
    a0 = fmaf(h2, wk[4], a0); a1 = fmaf(h2, wk[5], a1);
    a0 = fmaf(h3, wk[6], a0); a1 = fmaf(h3, wk[7], a1);
  }
  float dv = dinv[row];
  T2[(size_t)row * 2 + 0] = a0 * dv;
  T2[(size_t)row * 2 + 1] = a1 * dv;
}

// ---- fused final aggregation (dim 2, T2 pre-scaled) + pool + ticket finalize ----
__global__ void k_agg2pool(const float* __restrict__ T2, const int2* __restrict__ rc,
                           const int* __restrict__ col, const float* __restrict__ dinv,
                           const float* __restrict__ bias, const int* __restrict__ batch,
                           float* __restrict__ pool, int* __restrict__ pcnt,
                           int* __restrict__ tick, float* __restrict__ out, int nblk) {
  __shared__ float pl[128];
  __shared__ int pc[64];
  __shared__ int lastflag;
  int tid = threadIdx.x;
  if (tid < 128) pl[tid] = 0.f;
  if (tid < 64) pc[tid] = 0;
  __syncthreads();
  int node = blockIdx.x * 256 + tid;
  if (node < NN) {
    int2 sc = rc[node];
    int s = sc.x;
    int c = sc.y;
    float a0 = 0.f, a1 = 0.f;
    for (int i = 0; i < c; i += 4) {
      int j0 = i, j1 = i + 1, j2 = i + 2, j3 = i + 3;
      int s0 = col[s + j0];
      int sA = col[s + (j1 < c ? j1 : j0)];
      int sB = col[s + (j2 < c ? j2 : j0)];
      int sC = col[s + (j3 < c ? j3 : j0)];
      float2 t0 = *(const float2*)(T2 + 2 * (size_t)s0);
      float2 t1 = *(const float2*)(T2 + 2 * (size_t)sA);
      float2 t2 = *(const float2*)(T2 + 2 * (size_t)sB);
      float2 t3 = *(const float2*)(T2 + 2 * (size_t)sC);
      float w1 = j1 < c ? 1.f : 0.f;
      float w2 = j2 < c ? 1.f : 0.f;
      float w3 = j3 < c ? 1.f : 0.f;
      a0 += t0.x; a1 += t0.y;
      a0 = fmaf(w1, t1.x, a0); a1 = fmaf(w1, t1.y, a1);
      a0 = fmaf(w2, t2.x, a0); a1 = fmaf(w2, t2.y, a1);
      a0 = fmaf(w3, t3.x, a0); a1 = fmaf(w3, t3.y, a1);
    }
    float di = dinv[node];
    float2 tn = *(const float2*)(T2 + 2 * (size_t)node);
    float v0 = (a0 + tn.x) * di + bias[0];
    float v1 = (a1 + tn.y) * di + bias[1];
    int bb = batch[node];
    atomicAdd(&pl[bb * 2 + 0], v0);
    atomicAdd(&pl[bb * 2 + 1], v1);
    atomicAdd(&pc[bb], 1);
  }
  __syncthreads();
  if (tid < 128 && pl[tid] != 0.f) unsafeAtomicAdd(&pool[tid], pl[tid]);
  if (tid < 64 && pc[tid] != 0) atomicAdd(&pcnt[tid], pc[tid]);
  __syncthreads();
  if (tid == 0) {
    __threadfence();
    int old = atomicAdd(tick, 1);
    lastflag = (old == nblk - 1) ? 1 : 0;
  }
  __syncthreads();
  if (lastflag && tid < 128) {
    float v = unsafeAtomicAdd(&pool[tid], 0.f);       // coherent read
    int c = atomicAdd(&pcnt[tid >> 1], 0);            // coherent read
    out[tid] = v / (float)(c > 0 ? c : 1);
  }
}

extern "C" void kernel_launch(void* const* d_in, const int* in_sizes, int n_in,
                              void* d_out, int out_size, void* d_ws, size_t ws_size,
                              hipStream_t stream) {
  (void)in_sizes; (void)n_in; (void)out_size; (void)ws_size;
  const float* x     = (const float*)d_in[0];
  const float* W_in  = (const float*)d_in[1];
  const float* b_in  = (const float*)d_in[2];
  const float* W_h   = (const float*)d_in[3];
  const float* b_h   = (const float*)d_in[4];
  const float* W_out = (const float*)d_in[5];
  const float* b_out = (const float*)d_in[6];
  const float* gamma = (const float*)d_in[7];
  const float* beta  = (const float*)d_in[8];
  const int*   ei    = (const int*)d_in[9];
  const int*   batch = (const int*)d_in[10];
  const int* src = ei;
  const int* dst = ei + NE;
  float* out = (float*)d_out;

  char* w = (char*)d_ws;
  size_t off = 0;
  auto alloc = [&](size_t bytes) -> void* {
    void* p = (void*)(w + off);
    off += (bytes + 511) & ~(size_t)511;
    return p;
  };
  int2*   rc    = (int2*)alloc((size_t)NN * 8);
  int*    col   = (int*)alloc((size_t)NBUCK * BCAP * 4);   // slotted, 6.4 MB
  float*  dinv  = (float*)alloc((size_t)NN * 4);
  // zeroed zone: stats (3*128 dbl = 3072) | pool (512) | pcnt (256) | tick (256) |
  //              bcur (782*4 = 3128) -> 7224 bytes
  char*   zzone = (char*)alloc(7680);
  double* stats = (double*)zzone;
  float*  pool  = (float*)(zzone + 3072);
  int*    pcnt  = (int*)(zzone + 3584);
  int*    tick  = (int*)(zzone + 3840);
  int*    bcur  = (int*)(zzone + 4096);
  float*  buf0  = (float*)alloc((size_t)NN * HID * 4);
  float*  buf1  = (float*)alloc((size_t)NN * HID * 4);
  float*  buf2  = (float*)alloc((size_t)NN * HID * 4);
  __half* Th    = (__half*)alloc((size_t)NN * HID * 2);
  float*  T2    = (float*)alloc((size_t)NN * 2 * 4);
  // ebuf (slotted, 782*2048*8 = 12.8MB) aliases buf0: consumed by k_bucket_csr
  // before buf0's first write (G2, step 5)
  unsigned long long* ebuf = (unsigned long long*)buf0;

  hipMemsetAsync(zzone, 0, 7424, stream);

  // graph prep: slotted bucket-radix CSR build (no histogram/scan passes)
  k_escatter<<<293, 256, 0, stream>>>(src, dst, bcur, ebuf);
  k_bucket_csr<<<NBUCK, 256, 0, stream>>>(ebuf, bcur, rc, dinv, col);

  const int mmgrid = (NN + 63) / 64;   // 1563

  // layer 1: x(128) -> Th (fp16, pre-scaled) -> G1=buf1
  k_mmA<<<mmgrid, 512, 0, stream>>>(x, W_in, dinv, Th, NN);
  k_agg64<<<(NN + 3) / 4, 256, 0, stream>>>(Th, rc, col, dinv, b_in, buf1, 1);
  k_stats<<<512, 256, 0, stream>>>(buf1, stats);

  // layer 2: h1 = BN1(G1) (side-> buf2); Th = h1@W_h0; G2 = buf0
  k_mmB<<<mmgrid, 512, 0, stream>>>(buf1, stats, gamma, beta, nullptr, buf2, W_h,
                                    dinv, Th, NN);
  k_agg64<<<(NN + 3) / 4, 256, 0, stream>>>(Th, rc, col, dinv, b_h, buf0, 1);
  k_stats<<<512, 256, 0, stream>>>(buf0, stats + 128);

  // layer 3: h2 = BN2(G2)+h1 (side-> buf1); Th = h2@W_h1; G3 = buf2
  k_mmB<<<mmgrid, 512, 0, stream>>>(buf0, stats + 128, gamma + 64, beta + 64, buf2,
                                    buf1, W_h + HID * HID, dinv, Th, NN);
  k_agg64<<<(NN + 3) / 4, 256, 0, stream>>>(Th, rc, col, dinv, b_h + HID, buf2, 1);
  k_stats<<<512, 256, 0, stream>>>(buf2, stats + 256);

  // output: h3 = BN3(G3)+h2(buf1) fused with mm 64->2 (T2 pre-scaled), then agg+pool+div
  k_bnmmout<<<(NN + 255) / 256, 256, 0, stream>>>(buf2, stats + 256, gamma + 128,
                                                  beta + 128, buf1, W_out, dinv, T2, NN);
  const int pgrid = (NN + 255) / 256;  // 391
  k_agg2pool<<<pgrid, 256, 0, stream>>>(T2, rc, col, dinv, b_out, batch, pool,
                                        pcnt, tick, out, pgrid);
}

// Round 14
// 376.152 us; speedup vs baseline: 1.1975x; 1.0166x over previous
//
#include <hip/hip_runtime.h>
#include <hip/hip_fp16.h>

// EnhancedGNN on MI355X.
// R16: G (post-agg activations) stored fp16 -- cuts ~115MB of streaming traffic
//      across agg64-write/stats-read/mmB-read/bnmmout-read. BN stats computed
//      from the rounded values (self-consistent); residuals h1/h2 stay fp32
//      (hA/hB); all accumulation fp32/f64. ebuf aliases hA. R15 slotted CSR +
//      fp16-T gather + 512-thread mm kept. 13 launches.

#define NN 100000
#define NE 1200000
#define NBATCH 64
#define IND 128
#define HID 64
#define EPSF 1e-5f
#define NBUCK 782   // ceil(100000/128)
#define NPB 128     // nodes per bucket; bucket(d) = d >> 7
#define BCAP 2048   // slot capacity per bucket (mean 1536, sigma 39)

// scatter (src,dst) pairs into per-bucket SLOTS of ebuf; LDS hist + global cursor
__global__ void k_escatter(const int* __restrict__ src, const int* __restrict__ dst,
                           int* __restrict__ bcur, unsigned long long* __restrict__ ebuf) {
  __shared__ int lh[NBUCK];
  __shared__ int lbase[NBUCK];
  int tid = threadIdx.x;
  for (int i = tid; i < NBUCK; i += 256) lh[i] = 0;
  __syncthreads();
  int base = blockIdx.x * 4096;
  int sv[16], dv[16], rk[16];
#pragma unroll
  for (int j = 0; j < 16; j++) {
    int e = base + j * 256 + tid;
    if (e < NE) {
      sv[j] = src[e];
      dv[j] = dst[e];
      rk[j] = atomicAdd(&lh[dv[j] >> 7], 1);
    } else {
      dv[j] = -1;
    }
  }
  __syncthreads();
  for (int i = tid; i < NBUCK; i += 256) {
    int v = lh[i];
    lbase[i] = v ? atomicAdd(&bcur[i], v) : 0;
  }
  __syncthreads();
#pragma unroll
  for (int j = 0; j < 16; j++) {
    if (dv[j] >= 0) {
      int b = dv[j] >> 7;
      ebuf[(size_t)b * BCAP + lbase[b] + rk[j]] =
          (unsigned long long)(unsigned)sv[j] | ((unsigned long long)(unsigned)dv[j] << 32);
    }
  }
}

// one block per bucket: local hist -> rc(int2)/dinv, local scan, LDS-cursor fill -> col
__global__ void k_bucket_csr(const unsigned long long* __restrict__ ebuf,
                             const int* __restrict__ bcur, int2* __restrict__ rc,
                             float* __restrict__ dinv, int* __restrict__ col) {
  __shared__ int ldeg[NPB];
  __shared__ int lcur[NPB];
  __shared__ int sred[NPB];
  int b = blockIdx.x, tid = threadIdx.x;
  int nbase = b * NPB;
  int e0 = b * BCAP;
  int cnt = bcur[b];
  if (tid < NPB) ldeg[tid] = 0;
  __syncthreads();
  for (int e = tid; e < cnt; e += 256) {
    int d = (int)(ebuf[e0 + e] >> 32) - nbase;
    atomicAdd(&ldeg[d], 1);
  }
  __syncthreads();
  if (tid < NPB) sred[tid] = ldeg[tid];
  __syncthreads();
  for (int off = 1; off < NPB; off <<= 1) {
    int v = 0;
    if (tid < NPB && tid >= off) v = sred[tid - off];
    __syncthreads();
    if (tid < NPB) sred[tid] += v;
    __syncthreads();
  }
  if (tid < NPB) {
    int excl = sred[tid] - ldeg[tid];
    lcur[tid] = excl;
    int gn = nbase + tid;
    if (gn < NN) {
      int dg = ldeg[tid];
      rc[gn] = make_int2(e0 + excl, dg);
      dinv[gn] = rsqrtf((float)dg + 1.0f);
    }
  }
  __syncthreads();
  for (int e = tid; e < cnt; e += 256) {
    unsigned long long p = ebuf[e0 + e];
    int s = (int)(unsigned)p;
    int d = (int)(p >> 32) - nbase;
    int r = atomicAdd(&lcur[d], 1);
    col[e0 + r] = s;
  }
}

// ------ mm A: X[nrows,128] @ W[128,64] -> Th (fp16) * dinv[row] ------------------
// 512 threads / 8 waves; 64 rows/block; col-EIGHTH per wave (readfirstlane ->
// s_load W). Epilogue: 8 fp16 cols = one 16B store.
__global__ __launch_bounds__(512) void k_mmA(const float* __restrict__ X,
                                             const float* __restrict__ W,
                                             const float* __restrict__ dinv,
                                             __half* __restrict__ T, int nrows) {
  __shared__ float xs[64 * 65];
  int tid = threadIdx.x;
  int rbase = blockIdx.x * 64;
  int q8 = __builtin_amdgcn_readfirstlane(tid >> 6);  // wave-uniform col eighth
  int r = tid & 63;
  int r65 = r * 65;
  float4 acc[2];
  acc[0] = {0.f, 0.f, 0.f, 0.f};
  acc[1] = {0.f, 0.f, 0.f, 0.f};

  for (int ch = 0; ch < 2; ch++) {
#pragma unroll
    for (int i = 0; i < 2; i++) {
      int f = i * 512 + tid;
      int rr = f >> 4, kq = f & 15;
      int gr = rbase + rr;
      int grc = gr < nrows ? gr : nrows - 1;
      float4 v = *(const float4*)(X + (size_t)grc * 128 + ch * 64 + 4 * kq);
      float* p = xs + rr * 65 + 4 * kq;
      p[0] = v.x; p[1] = v.y; p[2] = v.z; p[3] = v.w;
    }
    __syncthreads();
    const float* Wb = W + ch * 64 * 64 + q8 * 8;
#pragma unroll 4
    for (int k = 0; k < 64; k++) {
      float xk = xs[r65 + k];
      const float4* wr = (const float4*)(Wb + (size_t)k * 64);
      float4 w0 = wr[0], w1 = wr[1];
      acc[0].x = fmaf(xk, w0.x, acc[0].x);
      acc[0].y = fmaf(xk, w0.y, acc[0].y);
      acc[0].z = fmaf(xk, w0.z, acc[0].z);
      acc[0].w = fmaf(xk, w0.w, acc[0].w);
      acc[1].x = fmaf(xk, w1.x, acc[1].x);
      acc[1].y = fmaf(xk, w1.y, acc[1].y);
      acc[1].z = fmaf(xk, w1.z, acc[1].z);
      acc[1].w = fmaf(xk, w1.w, acc[1].w);
    }
    if (ch == 0) __syncthreads();
  }

  int row = rbase + r;
  if (row < nrows) {
    float dv = dinv[row];
    __half2 o2[4];
    o2[0] = __floats2half2_rn(acc[0].x * dv, acc[0].y * dv);
    o2[1] = __floats2half2_rn(acc[0].z * dv, acc[0].w * dv);
    o2[2] = __floats2half2_rn(acc[1].x * dv, acc[1].y * dv);
    o2[3] = __floats2half2_rn(acc[1].z * dv, acc[1].w * dv);
    *(float4*)(T + (size_t)row * 64 + q8 * 8) = *(float4*)&o2[0];
  }
}

// ------ mm B: G fp16 in; BN(G)(+res fp32) -> Hside fp32; Th = (h @ W)*dinv fp16 --
// Staging: 512 chunks of 8 halves (one per thread), BN+res applied in fp32.
__global__ __launch_bounds__(512) void k_mmB(const __half* __restrict__ G,
                                             const double* __restrict__ st,
                                             const float* __restrict__ gamma,
                                             const float* __restrict__ beta,
                                             const float* __restrict__ res,
                                             float* __restrict__ Hside,
                                             const float* __restrict__ W,
                                             const float* __restrict__ dinv,
                                             __half* __restrict__ T, int nrows) {
  __shared__ float xs[64 * 65];
  __shared__ float scl[128];
  int tid = threadIdx.x;
  if (tid < 64) {
    double m = st[tid] / (double)NN;
    double var = st[64 + tid] / (double)NN - m * m;
    float scale = gamma[tid] * rsqrtf((float)var + EPSF);
    scl[tid] = scale;
    scl[64 + tid] = beta[tid] - (float)m * scale;
  }
  __syncthreads();

  int rbase = blockIdx.x * 64;
  {
    int rr = tid >> 3;   // 0..63 row
    int kc = tid & 7;    // chunk of 8 features
    int gr = rbase + rr;
    int grc = gr < nrows ? gr : nrows - 1;
    int fb = kc * 8;
    float4 raw = *(const float4*)(G + (size_t)grc * 64 + fb);  // 8 halves
    const __half2* hp = (const __half2*)&raw;
    float v[8];
    float2 t0 = __half22float2(hp[0]); v[0] = t0.x; v[1] = t0.y;
    float2 t1 = __half22float2(hp[1]); v[2] = t1.x; v[3] = t1.y;
    float2 t2 = __half22float2(hp[2]); v[4] = t2.x; v[5] = t2.y;
    float2 t3 = __half22float2(hp[3]); v[6] = t3.x; v[7] = t3.y;
#pragma unroll
    for (int j = 0; j < 8; j++) v[j] = v[j] * scl[fb + j] + scl[64 + fb + j];
    if (res != nullptr) {
      float4 r0 = *(const float4*)(res + (size_t)grc * 64 + fb);
      float4 r1 = *(const float4*)(res + (size_t)grc * 64 + fb + 4);
      v[0] += r0.x; v[1] += r0.y; v[2] += r0.z; v[3] += r0.w;
      v[4] += r1.x; v[5] += r1.y; v[6] += r1.z; v[7] += r1.w;
    }
    if (gr < nrows) {
      *(float4*)(Hside + (size_t)gr * 64 + fb) = make_float4(v[0], v[1], v[2], v[3]);
      *(float4*)(Hside + (size_t)gr * 64 + fb + 4) = make_float4(v[4], v[5], v[6], v[7]);
    }
    float* p = xs + rr * 65 + fb;
#pragma unroll
    for (int j = 0; j < 8; j++) p[j] = v[j];
  }
  __syncthreads();

  int q8 = __builtin_amdgcn_readfirstlane(tid >> 6);
  int r = tid & 63;
  int r65 = r * 65;
  float4 acc[2];
  acc[0] = {0.f, 0.f, 0.f, 0.f};
  acc[1] = {0.f, 0.f, 0.f, 0.f};
  const float* Wb = W + q8 * 8;
#pragma unroll 4
  for (int k = 0; k < 64; k++) {
    float xk = xs[r65 + k];
    const float4* wr = (const float4*)(Wb + (size_t)k * 64);
    float4 w0 = wr[0], w1 = wr[1];
    acc[0].x = fmaf(xk, w0.x, acc[0].x);
    acc[0].y = fmaf(xk, w0.y, acc[0].y);
    acc[0].z = fmaf(xk, w0.z, acc[0].z);
    acc[0].w = fmaf(xk, w0.w, acc[0].w);
    acc[1].x = fmaf(xk, w1.x, acc[1].x);
    acc[1].y = fmaf(xk, w1.y, acc[1].y);
    acc[1].z = fmaf(xk, w1.z, acc[1].z);
    acc[1].w = fmaf(xk, w1.w, acc[1].w);
  }

  int row = rbase + r;
  if (row < nrows) {
    float dv = dinv[row];
    __half2 o2[4];
    o2[0] = __floats2half2_rn(acc[0].x * dv, acc[0].y * dv);
    o2[1] = __floats2half2_rn(acc[0].z * dv, acc[0].w * dv);
    o2[2] = __floats2half2_rn(acc[1].x * dv, acc[1].y * dv);
    o2[3] = __floats2half2_rn(acc[1].z * dv, acc[1].w * dv);
    *(float4*)(T + (size_t)row * 64 + q8 * 8) = *(float4*)&o2[0];
  }
}

// ---------------- aggregation (HID=64): wave/node, fp16 gather, fp32 accum --------
// Th pre-scaled by dinv[row]: o = di*(sum Th[src] + Th[node]) + bias. G out fp16.
__global__ void k_agg64(const __half* __restrict__ T, const int2* __restrict__ rc,
                        const int* __restrict__ col, const float* __restrict__ dinv,
                        const float* __restrict__ bias, __half* __restrict__ G,
                        int relu) {
  int lane = threadIdx.x & 63;
  int wv = threadIdx.x >> 6;
  int node = blockIdx.x * 4 + wv;
  if (node >= NN) return;
  int grp = lane >> 4;
  int q = lane & 15;
  int2 sc = rc[node];
  int s = sc.x;
  int c = sc.y;
  float4 acc = {0.f, 0.f, 0.f, 0.f};
  for (int i = 0; i < c; i += 16) {
    int j0 = i + grp, j1 = j0 + 4, j2 = j0 + 8, j3 = j0 + 12;
    int s0 = col[s + (j0 < c ? j0 : 0)];
    int s1 = col[s + (j1 < c ? j1 : 0)];
    int s2 = col[s + (j2 < c ? j2 : 0)];
    int s3 = col[s + (j3 < c ? j3 : 0)];
    float2 r0 = *(const float2*)(T + (size_t)s0 * 64 + q * 4);
    float2 r1 = *(const float2*)(T + (size_t)s1 * 64 + q * 4);
    float2 r2 = *(const float2*)(T + (size_t)s2 * 64 + q * 4);
    float2 r3 = *(const float2*)(T + (size_t)s3 * 64 + q * 4);
    float w0 = j0 < c ? 1.f : 0.f;
    float w1 = j1 < c ? 1.f : 0.f;
    float w2 = j2 < c ? 1.f : 0.f;
    float w3 = j3 < c ? 1.f : 0.f;
    {
      __half2* p = (__half2*)&r0;
      float2 lo = __half22float2(p[0]), hi = __half22float2(p[1]);
      acc.x = fmaf(w0, lo.x, acc.x); acc.y = fmaf(w0, lo.y, acc.y);
      acc.z = fmaf(w0, hi.x, acc.z); acc.w = fmaf(w0, hi.y, acc.w);
    }
    {
      __half2* p = (__half2*)&r1;
      float2 lo = __half22float2(p[0]), hi = __half22float2(p[1]);
      acc.x = fmaf(w1, lo.x, acc.x); acc.y = fmaf(w1, lo.y, acc.y);
      acc.z = fmaf(w1, hi.x, acc.z); acc.w = fmaf(w1, hi.y, acc.w);
    }
    {
      __half2* p = (__half2*)&r2;
      float2 lo = __half22float2(p[0]), hi = __half22float2(p[1]);
      acc.x = fmaf(w2, lo.x, acc.x); acc.y = fmaf(w2, lo.y, acc.y);
      acc.z = fmaf(w2, hi.x, acc.z); acc.w = fmaf(w2, hi.y, acc.w);
    }
    {
      __half2* p = (__half2*)&r3;
      float2 lo = __half22float2(p[0]), hi = __half22float2(p[1]);
      acc.x = fmaf(w3, lo.x, acc.x); acc.y = fmaf(w3, lo.y, acc.y);
      acc.z = fmaf(w3, hi.x, acc.z); acc.w = fmaf(w3, hi.y, acc.w);
    }
  }
  acc.x += __shfl_xor(acc.x, 16, 64);
  acc.y += __shfl_xor(acc.y, 16, 64);
  acc.z += __shfl_xor(acc.z, 16, 64);
  acc.w += __shfl_xor(acc.w, 16, 64);
  acc.x += __shfl_xor(acc.x, 32, 64);
  acc.y += __shfl_xor(acc.y, 32, 64);
  acc.z += __shfl_xor(acc.z, 32, 64);
  acc.w += __shfl_xor(acc.w, 32, 64);
  if (grp == 0) {
    float di = dinv[node];
    float2 rs = *(const float2*)(T + (size_t)node * 64 + q * 4);
    __half2* p = (__half2*)&rs;
    float2 lo = __half22float2(p[0]), hi = __half22float2(p[1]);
    float4 bs = ((const float4*)bias)[q];
    float4 o;
    o.x = (acc.x + lo.x) * di + bs.x;
    o.y = (acc.y + lo.y) * di + bs.y;
    o.z = (acc.z + hi.x) * di + bs.z;
    o.w = (acc.w + hi.y) * di + bs.w;
    if (relu) {
      o.x = fmaxf(o.x, 0.f);
      o.y = fmaxf(o.y, 0.f);
      o.z = fmaxf(o.z, 0.f);
      o.w = fmaxf(o.w, 0.f);
    }
    float2 pk;
    ((__half2*)&pk)[0] = __floats2half2_rn(o.x, o.y);
    ((__half2*)&pk)[1] = __floats2half2_rn(o.z, o.w);
    *(float2*)(G + (size_t)node * 64 + q * 4) = pk;
  }
}

// ---------------- BN stats (fp16 input, fp32 accum, f64 atomics) ----------------
__global__ __launch_bounds__(256) void k_stats(const __half* __restrict__ H,
                                               double* __restrict__ st) {
  int q = threadIdx.x & 15;   // feature quarter (4 halves)
  int rg = threadIdx.x >> 4;  // 16 row-groups per block
  float4 s1 = {0.f, 0.f, 0.f, 0.f};
  float4 s2 = {0.f, 0.f, 0.f, 0.f};
  for (int r = blockIdx.x * 16 + rg; r < NN; r += gridDim.x * 16) {
    float2 raw = *(const float2*)(H + (size_t)r * 64 + q * 4);
    const __half2* hp = (const __half2*)&raw;
    float2 lo = __half22float2(hp[0]), hi = __half22float2(hp[1]);
    s1.x += lo.x; s1.y += lo.y; s1.z += hi.x; s1.w += hi.y;
    s2.x = fmaf(lo.x, lo.x, s2.x); s2.y = fmaf(lo.y, lo.y, s2.y);
    s2.z = fmaf(hi.x, hi.x, s2.z); s2.w = fmaf(hi.y, hi.y, s2.w);
  }
  __shared__ float a[16][16][8];
  a[rg][q][0] = s1.x; a[rg][q][1] = s1.y; a[rg][q][2] = s1.z; a[rg][q][3] = s1.w;
  a[rg][q][4] = s2.x; a[rg][q][5] = s2.y; a[rg][q][6] = s2.z; a[rg][q][7] = s2.w;
  __syncthreads();
  int tid = threadIdx.x;
  if (tid < 128) {
    int f = tid & 63;        // feature
    int which = tid >> 6;    // 0 = sum, 1 = sumsq
    int qq = f >> 2, jj = (f & 3) + which * 4;
    float t = 0.f;
#pragma unroll
    for (int g = 0; g < 16; g++) t += a[g][qq][jj];
    unsafeAtomicAdd(&st[which * 64 + f], (double)t);
  }
}

// ------- fused: BN3 (G fp16) + residual (fp32) + matmul 64->2, T2 *= dinv --------
__global__ void k_bnmmout(const __half* __restrict__ G, const double* __restrict__ st,
                          const float* __restrict__ gamma, const float* __restrict__ beta,
                          const float* __restrict__ res, const float* __restrict__ W,
                          const float* __restrict__ dinv, float* __restrict__ T2,
                          int nrows) {
  __shared__ float Wl[128];
  __shared__ float scl[128];
  int tid = threadIdx.x;
  if (tid < 32) ((float4*)Wl)[tid] = ((const float4*)W)[tid];
  else if (tid >= 64 && tid < 128) {
    int f = tid - 64;
    double m = st[f] / (double)NN;
    double var = st[64 + f] / (double)NN - m * m;
    float scale = gamma[f] * rsqrtf((float)var + EPSF);
    scl[f] = scale;
    scl[64 + f] = beta[f] - (float)m * scale;
  }
  __syncthreads();
  int row = blockIdx.x * 256 + tid;
  if (row >= nrows) return;
  const __half* g = G + (size_t)row * 64;
  const float4* r4 = (const float4*)(res + (size_t)row * 64);
  float a0 = 0.f, a1 = 0.f;
#pragma unroll
  for (int q = 0; q < 16; q++) {
    float2 raw = *(const float2*)(g + q * 4);
    const __half2* hp = (const __half2*)&raw;
    float2 lo = __half22float2(hp[0]), hi = __half22float2(hp[1]);
    float4 rr = r4[q];
    float4 s = ((const float4*)scl)[q];
    float4 sh = ((const float4*)(scl + 64))[q];
    float h0 = lo.x * s.x + sh.x + rr.x;
    float h1 = lo.y * s.y + sh.y + rr.y;
    float h2 = hi.x * s.z + sh.z + rr.z;
    float h3 = hi.y * s.w + sh.w + rr.w;
    const float* wk = Wl + q * 8;
    a0 = fmaf(h0, wk[0], a0); a1 = fmaf(h0, wk[1], a1);
    a0 = fmaf(h1, wk[2], a0); a1 = fmaf(h1, wk[3], a1);
    a0 = fmaf(h2, wk[4], a0); a1 = fmaf(h2, wk[5], a1);
    a0 = fmaf(h3, wk[6], a0); a1 = fmaf(h3, wk[7], a1);
  }
  float dv = dinv[row];
  T2[(size_t)row * 2 + 0] = a0 * dv;
  T2[(size_t)row * 2 + 1] = a1 * dv;
}

// ---- fused final aggregation (dim 2, T2 pre-scaled) + pool + ticket finalize ----
__global__ void k_agg2pool(const float* __restrict__ T2, const int2* __restrict__ rc,
                           const int* __restrict__ col, const float* __restrict__ dinv,
                           const float* __restrict__ bias, const int* __restrict__ batch,
                           float* __restrict__ pool, int* __restrict__ pcnt,
                           int* __restrict__ tick, float* __restrict__ out, int nblk) {
  __shared__ float pl[128];
  __shared__ int pc[64];
  __shared__ int lastflag;
  int tid = threadIdx.x;
  if (tid < 128) pl[tid] = 0.f;
  if (tid < 64) pc[tid] = 0;
  __syncthreads();
  int node = blockIdx.x * 256 + tid;
  if (node < NN) {
    int2 sc = rc[node];
    int s = sc.x;
    int c = sc.y;
    float a0 = 0.f, a1 = 0.f;
    for (int i = 0; i < c; i += 4) {
      int j0 = i, j1 = i + 1, j2 = i + 2, j3 = i + 3;
      int s0 = col[s + j0];
      int sA = col[s + (j1 < c ? j1 : j0)];
      int sB = col[s + (j2 < c ? j2 : j0)];
      int sC = col[s + (j3 < c ? j3 : j0)];
      float2 t0 = *(const float2*)(T2 + 2 * (size_t)s0);
      float2 t1 = *(const float2*)(T2 + 2 * (size_t)sA);
      float2 t2 = *(const float2*)(T2 + 2 * (size_t)sB);
      float2 t3 = *(const float2*)(T2 + 2 * (size_t)sC);
      float w1 = j1 < c ? 1.f : 0.f;
      float w2 = j2 < c ? 1.f : 0.f;
      float w3 = j3 < c ? 1.f : 0.f;
      a0 += t0.x; a1 += t0.y;
      a0 = fmaf(w1, t1.x, a0); a1 = fmaf(w1, t1.y, a1);
      a0 = fmaf(w2, t2.x, a0); a1 = fmaf(w2, t2.y, a1);
      a0 = fmaf(w3, t3.x, a0); a1 = fmaf(w3, t3.y, a1);
    }
    float di = dinv[node];
    float2 tn = *(const float2*)(T2 + 2 * (size_t)node);
    float v0 = (a0 + tn.x) * di + bias[0];
    float v1 = (a1 + tn.y) * di + bias[1];
    int bb = batch[node];
    atomicAdd(&pl[bb * 2 + 0], v0);
    atomicAdd(&pl[bb * 2 + 1], v1);
    atomicAdd(&pc[bb], 1);
  }
  __syncthreads();
  if (tid < 128 && pl[tid] != 0.f) unsafeAtomicAdd(&pool[tid], pl[tid]);
  if (tid < 64 && pc[tid] != 0) atomicAdd(&pcnt[tid], pc[tid]);
  __syncthreads();
  if (tid == 0) {
    __threadfence();
    int old = atomicAdd(tick, 1);
    lastflag = (old == nblk - 1) ? 1 : 0;
  }
  __syncthreads();
  if (lastflag && tid < 128) {
    float v = unsafeAtomicAdd(&pool[tid], 0.f);       // coherent read
    int c = atomicAdd(&pcnt[tid >> 1], 0);            // coherent read
    out[tid] = v / (float)(c > 0 ? c : 1);
  }
}

extern "C" void kernel_launch(void* const* d_in, const int* in_sizes, int n_in,
                              void* d_out, int out_size, void* d_ws, size_t ws_size,
                              hipStream_t stream) {
  (void)in_sizes; (void)n_in; (void)out_size; (void)ws_size;
  const float* x     = (const float*)d_in[0];
  const float* W_in  = (const float*)d_in[1];
  const float* b_in  = (const float*)d_in[2];
  const float* W_h   = (const float*)d_in[3];
  const float* b_h   = (const float*)d_in[4];
  const float* W_out = (const float*)d_in[5];
  const float* b_out = (const float*)d_in[6];
  const float* gamma = (const float*)d_in[7];
  const float* beta  = (const float*)d_in[8];
  const int*   ei    = (const int*)d_in[9];
  const int*   batch = (const int*)d_in[10];
  const int* src = ei;
  const int* dst = ei + NE;
  float* out = (float*)d_out;

  char* w = (char*)d_ws;
  size_t off = 0;
  auto alloc = [&](size_t bytes) -> void* {
    void* p = (void*)(w + off);
    off += (bytes + 511) & ~(size_t)511;
    return p;
  };
  int2*   rc    = (int2*)alloc((size_t)NN * 8);
  int*    col   = (int*)alloc((size_t)NBUCK * BCAP * 4);   // slotted, 6.4 MB
  float*  dinv  = (float*)alloc((size_t)NN * 4);
  // zeroed zone: stats (3*128 dbl = 3072) | pool (512) | pcnt (256) | tick (256) |
  //              bcur (782*4 = 3128) -> 7224 bytes
  char*   zzone = (char*)alloc(7680);
  double* stats = (double*)zzone;
  float*  pool  = (float*)(zzone + 3072);
  int*    pcnt  = (int*)(zzone + 3584);
  int*    tick  = (int*)(zzone + 3840);
  int*    bcur  = (int*)(zzone + 4096);
  __half* Ga    = (__half*)alloc((size_t)NN * HID * 2);   // G1 / G3
  __half* Gb    = (__half*)alloc((size_t)NN * HID * 2);   // G2
  float*  hA    = (float*)alloc((size_t)NN * HID * 4);    // h1 (fp32)
  float*  hB    = (float*)alloc((size_t)NN * HID * 4);    // h2 (fp32)
  __half* Th    = (__half*)alloc((size_t)NN * HID * 2);
  float*  T2    = (float*)alloc((size_t)NN * 2 * 4);
  // ebuf (slotted, 782*2048*8 = 12.82MB) aliases hA (25.6MB): consumed by
  // k_bucket_csr; hA's first write is layer-2 mmB's Hside (step 6)
  unsigned long long* ebuf = (unsigned long long*)hA;

  hipMemsetAsync(zzone, 0, 7424, stream);

  // graph prep: slotted bucket-radix CSR build (no histogram/scan passes)
  k_escatter<<<293, 256, 0, stream>>>(src, dst, bcur, ebuf);
  k_bucket_csr<<<NBUCK, 256, 0, stream>>>(ebuf, bcur, rc, dinv, col);

  const int mmgrid = (NN + 63) / 64;   // 1563

  // layer 1: x(128) -> Th (fp16, pre-scaled) -> G1=Ga (fp16)
  k_mmA<<<mmgrid, 512, 0, stream>>>(x, W_in, dinv, Th, NN);
  k_agg64<<<(NN + 3) / 4, 256, 0, stream>>>(Th, rc, col, dinv, b_in, Ga, 1);
  k_stats<<<512, 256, 0, stream>>>(Ga, stats);

  // layer 2: h1 = BN1(G1) (fp32 side-> hA); Th = h1@W_h0; G2 = Gb
  k_mmB<<<mmgrid, 512, 0, stream>>>(Ga, stats, gamma, beta, nullptr, hA, W_h,
                                    dinv, Th, NN);
  k_agg64<<<(NN + 3) / 4, 256, 0, stream>>>(Th, rc, col, dinv, b_h, Gb, 1);
  k_stats<<<512, 256, 0, stream>>>(Gb, stats + 128);

  // layer 3: h2 = BN2(G2)+h1 (fp32 side-> hB); Th = h2@W_h1; G3 = Ga (G1 dead)
  k_mmB<<<mmgrid, 512, 0, stream>>>(Gb, stats + 128, gamma + 64, beta + 64, hA,
                                    hB, W_h + HID * HID, dinv, Th, NN);
  k_agg64<<<(NN + 3) / 4, 256, 0, stream>>>(Th, rc, col, dinv, b_h + HID, Ga, 1);
  k_stats<<<512, 256, 0, stream>>>(Ga, stats + 256);

  // output: h3 = BN3(G3)+h2(hB) fused with mm 64->2 (T2 pre-scaled), then agg+pool+div
  k_bnmmout<<<(NN + 255) / 256, 256, 0, stream>>>(Ga, stats + 256, gamma + 128,
                                                  beta + 128, hB, W_out, dinv, T2, NN);
  const int pgrid = (NN + 255) / 256;  // 391
  k_agg2pool<<<pgrid, 256, 0, stream>>>(T2, rc, col, dinv, b_out, batch, pool,
                                        pcnt, tick, out, pgrid);
}

// Round 15
// 372.565 us; speedup vs baseline: 1.2091x; 1.0096x over previous
//
#include <hip/hip_runtime.h>
#include <hip/hip_fp16.h>

// EnhancedGNN on MI355X.
// R17: consolidation: (1) dinv array deleted -- all consumers compute
//      rsqrtf(deg+1) from rc.y (1 VALU op vs dependent 4B load; agg64/agg2pool
//      get it free from the rc they already load). (2) agg64 self-row T gather
//      hoisted above the edge loop (overlaps ~500cy L2/L3 latency that was
//      serialized in the tail). (3) escatter edge loads int4-vectorized.
//      R16 fp16 G/T + slotted CSR + 512-thread mm kept. 13 launches.

#define NN 100000
#define NE 1200000
#define NBATCH 64
#define IND 128
#define HID 64
#define EPSF 1e-5f
#define NBUCK 782   // ceil(100000/128)
#define NPB 128     // nodes per bucket; bucket(d) = d >> 7
#define BCAP 2048   // slot capacity per bucket (mean 1536, sigma 39)

// scatter (src,dst) pairs into per-bucket SLOTS of ebuf; LDS hist + global cursor
__global__ void k_escatter(const int* __restrict__ src, const int* __restrict__ dst,
                           int* __restrict__ bcur, unsigned long long* __restrict__ ebuf) {
  __shared__ int lh[NBUCK];
  __shared__ int lbase[NBUCK];
  int tid = threadIdx.x;
  for (int i = tid; i < NBUCK; i += 256) lh[i] = 0;
  __syncthreads();
  int base4 = blockIdx.x * 1024;  // int4 units; block covers 4096 edges
  int sv[16], dv[16], rk[16];
#pragma unroll
  for (int j = 0; j < 4; j++) {
    int i4 = base4 + j * 256 + tid;
    if (i4 * 4 < NE) {
      int4 s4 = ((const int4*)src)[i4];
      int4 d4 = ((const int4*)dst)[i4];
      sv[4 * j + 0] = s4.x; dv[4 * j + 0] = d4.x;
      sv[4 * j + 1] = s4.y; dv[4 * j + 1] = d4.y;
      sv[4 * j + 2] = s4.z; dv[4 * j + 2] = d4.z;
      sv[4 * j + 3] = s4.w; dv[4 * j + 3] = d4.w;
      rk[4 * j + 0] = atomicAdd(&lh[d4.x >> 7], 1);
      rk[4 * j + 1] = atomicAdd(&lh[d4.y >> 7], 1);
      rk[4 * j + 2] = atomicAdd(&lh[d4.z >> 7], 1);
      rk[4 * j + 3] = atomicAdd(&lh[d4.w >> 7], 1);
    } else {
      dv[4 * j + 0] = -1; dv[4 * j + 1] = -1;
      dv[4 * j + 2] = -1; dv[4 * j + 3] = -1;
    }
  }
  __syncthreads();
  for (int i = tid; i < NBUCK; i += 256) {
    int v = lh[i];
    lbase[i] = v ? atomicAdd(&bcur[i], v) : 0;
  }
  __syncthreads();
#pragma unroll
  for (int j = 0; j < 16; j++) {
    if (dv[j] >= 0) {
      int b = dv[j] >> 7;
      ebuf[(size_t)b * BCAP + lbase[b] + rk[j]] =
          (unsigned long long)(unsigned)sv[j] | ((unsigned long long)(unsigned)dv[j] << 32);
    }
  }
}

// one block per bucket: local hist -> rc(int2), local scan, LDS-cursor fill -> col
__global__ void k_bucket_csr(const unsigned long long* __restrict__ ebuf,
                             const int* __restrict__ bcur, int2* __restrict__ rc,
                             int* __restrict__ col) {
  __shared__ int ldeg[NPB];
  __shared__ int lcur[NPB];
  __shared__ int sred[NPB];
  int b = blockIdx.x, tid = threadIdx.x;
  int nbase = b * NPB;
  int e0 = b * BCAP;
  int cnt = bcur[b];
  if (tid < NPB) ldeg[tid] = 0;
  __syncthreads();
  for (int e = tid; e < cnt; e += 256) {
    int d = (int)(ebuf[e0 + e] >> 32) - nbase;
    atomicAdd(&ldeg[d], 1);
  }
  __syncthreads();
  if (tid < NPB) sred[tid] = ldeg[tid];
  __syncthreads();
  for (int off = 1; off < NPB; off <<= 1) {
    int v = 0;
    if (tid < NPB && tid >= off) v = sred[tid - off];
    __syncthreads();
    if (tid < NPB) sred[tid] += v;
    __syncthreads();
  }
  if (tid < NPB) {
    int excl = sred[tid] - ldeg[tid];
    lcur[tid] = excl;
    int gn = nbase + tid;
    if (gn < NN) rc[gn] = make_int2(e0 + excl, ldeg[tid]);
  }
  __syncthreads();
  for (int e = tid; e < cnt; e += 256) {
    unsigned long long p = ebuf[e0 + e];
    int s = (int)(unsigned)p;
    int d = (int)(p >> 32) - nbase;
    int r = atomicAdd(&lcur[d], 1);
    col[e0 + r] = s;
  }
}

// ------ mm A: X[nrows,128] @ W[128,64] -> Th (fp16) * dinv[row] ------------------
// 512 threads / 8 waves; 64 rows/block; col-EIGHTH per wave (readfirstlane ->
// s_load W). Epilogue: 8 fp16 cols = one 16B store; dinv from rc.y.
__global__ __launch_bounds__(512) void k_mmA(const float* __restrict__ X,
                                             const float* __restrict__ W,
                                             const int2* __restrict__ rc,
                                             __half* __restrict__ T, int nrows) {
  __shared__ float xs[64 * 65];
  int tid = threadIdx.x;
  int rbase = blockIdx.x * 64;
  int q8 = __builtin_amdgcn_readfirstlane(tid >> 6);  // wave-uniform col eighth
  int r = tid & 63;
  int r65 = r * 65;
  float4 acc[2];
  acc[0] = {0.f, 0.f, 0.f, 0.f};
  acc[1] = {0.f, 0.f, 0.f, 0.f};

  for (int ch = 0; ch < 2; ch++) {
#pragma unroll
    for (int i = 0; i < 2; i++) {
      int f = i * 512 + tid;
      int rr = f >> 4, kq = f & 15;
      int gr = rbase + rr;
      int grc = gr < nrows ? gr : nrows - 1;
      float4 v = *(const float4*)(X + (size_t)grc * 128 + ch * 64 + 4 * kq);
      float* p = xs + rr * 65 + 4 * kq;
      p[0] = v.x; p[1] = v.y; p[2] = v.z; p[3] = v.w;
    }
    __syncthreads();
    const float* Wb = W + ch * 64 * 64 + q8 * 8;
#pragma unroll 4
    for (int k = 0; k < 64; k++) {
      float xk = xs[r65 + k];
      const float4* wr = (const float4*)(Wb + (size_t)k * 64);
      float4 w0 = wr[0], w1 = wr[1];
      acc[0].x = fmaf(xk, w0.x, acc[0].x);
      acc[0].y = fmaf(xk, w0.y, acc[0].y);
      acc[0].z = fmaf(xk, w0.z, acc[0].z);
      acc[0].w = fmaf(xk, w0.w, acc[0].w);
      acc[1].x = fmaf(xk, w1.x, acc[1].x);
      acc[1].y = fmaf(xk, w1.y, acc[1].y);
      acc[1].z = fmaf(xk, w1.z, acc[1].z);
      acc[1].w = fmaf(xk, w1.w, acc[1].w);
    }
    if (ch == 0) __syncthreads();
  }

  int row = rbase + r;
  if (row < nrows) {
    float dv = rsqrtf((float)rc[row].y + 1.0f);
    __half2 o2[4];
    o2[0] = __floats2half2_rn(acc[0].x * dv, acc[0].y * dv);
    o2[1] = __floats2half2_rn(acc[0].z * dv, acc[0].w * dv);
    o2[2] = __floats2half2_rn(acc[1].x * dv, acc[1].y * dv);
    o2[3] = __floats2half2_rn(acc[1].z * dv, acc[1].w * dv);
    *(float4*)(T + (size_t)row * 64 + q8 * 8) = *(float4*)&o2[0];
  }
}

// ------ mm B: G fp16 in; BN(G)(+res fp32) -> Hside fp32; Th = (h @ W)*dinv fp16 --
__global__ __launch_bounds__(512) void k_mmB(const __half* __restrict__ G,
                                             const double* __restrict__ st,
                                             const float* __restrict__ gamma,
                                             const float* __restrict__ beta,
                                             const float* __restrict__ res,
                                             float* __restrict__ Hside,
                                             const float* __restrict__ W,
                                             const int2* __restrict__ rc,
                                             __half* __restrict__ T, int nrows) {
  __shared__ float xs[64 * 65];
  __shared__ float scl[128];
  int tid = threadIdx.x;
  if (tid < 64) {
    double m = st[tid] / (double)NN;
    double var = st[64 + tid] / (double)NN - m * m;
    float scale = gamma[tid] * rsqrtf((float)var + EPSF);
    scl[tid] = scale;
    scl[64 + tid] = beta[tid] - (float)m * scale;
  }
  __syncthreads();

  int rbase = blockIdx.x * 64;
  {
    int rr = tid >> 3;   // 0..63 row
    int kc = tid & 7;    // chunk of 8 features
    int gr = rbase + rr;
    int grc = gr < nrows ? gr : nrows - 1;
    int fb = kc * 8;
    float4 raw = *(const float4*)(G + (size_t)grc * 64 + fb);  // 8 halves
    const __half2* hp = (const __half2*)&raw;
    float v[8];
    float2 t0 = __half22float2(hp[0]); v[0] = t0.x; v[1] = t0.y;
    float2 t1 = __half22float2(hp[1]); v[2] = t1.x; v[3] = t1.y;
    float2 t2 = __half22float2(hp[2]); v[4] = t2.x; v[5] = t2.y;
    float2 t3 = __half22float2(hp[3]); v[6] = t3.x; v[7] = t3.y;
#pragma unroll
    for (int j = 0; j < 8; j++) v[j] = v[j] * scl[fb + j] + scl[64 + fb + j];
    if (res != nullptr) {
      float4 r0 = *(const float4*)(res + (size_t)grc * 64 + fb);
      float4 r1 = *(const float4*)(res + (size_t)grc * 64 + fb + 4);
      v[0] += r0.x; v[1] += r0.y; v[2] += r0.z; v[3] += r0.w;
      v[4] += r1.x; v[5] += r1.y; v[6] += r1.z; v[7] += r1.w;
    }
    if (gr < nrows) {
      *(float4*)(Hside + (size_t)gr * 64 + fb) = make_float4(v[0], v[1], v[2], v[3]);
      *(float4*)(Hside + (size_t)gr * 64 + fb + 4) = make_float4(v[4], v[5], v[6], v[7]);
    }
    float* p = xs + rr * 65 + fb;
#pragma unroll
    for (int j = 0; j < 8; j++) p[j] = v[j];
  }
  __syncthreads();

  int q8 = __builtin_amdgcn_readfirstlane(tid >> 6);
  int r = tid & 63;
  int r65 = r * 65;
  float4 acc[2];
  acc[0] = {0.f, 0.f, 0.f, 0.f};
  acc[1] = {0.f, 0.f, 0.f, 0.f};
  const float* Wb = W + q8 * 8;
#pragma unroll 4
  for (int k = 0; k < 64; k++) {
    float xk = xs[r65 + k];
    const float4* wr = (const float4*)(Wb + (size_t)k * 64);
    float4 w0 = wr[0], w1 = wr[1];
    acc[0].x = fmaf(xk, w0.x, acc[0].x);
    acc[0].y = fmaf(xk, w0.y, acc[0].y);
    acc[0].z = fmaf(xk, w0.z, acc[0].z);
    acc[0].w = fmaf(xk, w0.w, acc[0].w);
    acc[1].x = fmaf(xk, w1.x, acc[1].x);
    acc[1].y = fmaf(xk, w1.y, acc[1].y);
    acc[1].z = fmaf(xk, w1.z, acc[1].z);
    acc[1].w = fmaf(xk, w1.w, acc[1].w);
  }

  int row = rbase + r;
  if (row < nrows) {
    float dv = rsqrtf((float)rc[row].y + 1.0f);
    __half2 o2[4];
    o2[0] = __floats2half2_rn(acc[0].x * dv, acc[0].y * dv);
    o2[1] = __floats2half2_rn(acc[0].z * dv, acc[0].w * dv);
    o2[2] = __floats2half2_rn(acc[1].x * dv, acc[1].y * dv);
    o2[3] = __floats2half2_rn(acc[1].z * dv, acc[1].w * dv);
    *(float4*)(T + (size_t)row * 64 + q8 * 8) = *(float4*)&o2[0];
  }
}

// ---------------- aggregation (HID=64): wave/node, fp16 gather, fp32 accum --------
// Th pre-scaled by dinv[row]: o = di*(sum Th[src] + Th[node]) + bias. G out fp16.
// dinv recomputed from deg (rc.y); self-row gather hoisted above the edge loop.
__global__ void k_agg64(const __half* __restrict__ T, const int2* __restrict__ rc,
                        const int* __restrict__ col, const float* __restrict__ bias,
                        __half* __restrict__ G, int relu) {
  int lane = threadIdx.x & 63;
  int wv = threadIdx.x >> 6;
  int node = blockIdx.x * 4 + wv;
  if (node >= NN) return;
  int grp = lane >> 4;
  int q = lane & 15;
  int2 sc = rc[node];
  int s = sc.x;
  int c = sc.y;
  float di = rsqrtf((float)c + 1.0f);
  float2 rs = *(const float2*)(T + (size_t)node * 64 + q * 4);  // self row, early
  float4 acc = {0.f, 0.f, 0.f, 0.f};
  for (int i = 0; i < c; i += 16) {
    int j0 = i + grp, j1 = j0 + 4, j2 = j0 + 8, j3 = j0 + 12;
    int s0 = col[s + (j0 < c ? j0 : 0)];
    int s1 = col[s + (j1 < c ? j1 : 0)];
    int s2 = col[s + (j2 < c ? j2 : 0)];
    int s3 = col[s + (j3 < c ? j3 : 0)];
    float2 r0 = *(const float2*)(T + (size_t)s0 * 64 + q * 4);
    float2 r1 = *(const float2*)(T + (size_t)s1 * 64 + q * 4);
    float2 r2 = *(const float2*)(T + (size_t)s2 * 64 + q * 4);
    float2 r3 = *(const float2*)(T + (size_t)s3 * 64 + q * 4);
    float w0 = j0 < c ? 1.f : 0.f;
    float w1 = j1 < c ? 1.f : 0.f;
    float w2 = j2 < c ? 1.f : 0.f;
    float w3 = j3 < c ? 1.f : 0.f;
    {
      __half2* p = (__half2*)&r0;
      float2 lo = __half22float2(p[0]), hi = __half22float2(p[1]);
      acc.x = fmaf(w0, lo.x, acc.x); acc.y = fmaf(w0, lo.y, acc.y);
      acc.z = fmaf(w0, hi.x, acc.z); acc.w = fmaf(w0, hi.y, acc.w);
    }
    {
      __half2* p = (__half2*)&r1;
      float2 lo = __half22float2(p[0]), hi = __half22float2(p[1]);
      acc.x = fmaf(w1, lo.x, acc.x); acc.y = fmaf(w1, lo.y, acc.y);
      acc.z = fmaf(w1, hi.x, acc.z); acc.w = fmaf(w1, hi.y, acc.w);
    }
    {
      __half2* p = (__half2*)&r2;
      float2 lo = __half22float2(p[0]), hi = __half22float2(p[1]);
      acc.x = fmaf(w2, lo.x, acc.x); acc.y = fmaf(w2, lo.y, acc.y);
      acc.z = fmaf(w2, hi.x, acc.z); acc.w = fmaf(w2, hi.y, acc.w);
    }
    {
      __half2* p = (__half2*)&r3;
      float2 lo = __half22float2(p[0]), hi = __half22float2(p[1]);
      acc.x = fmaf(w3, lo.x, acc.x); acc.y = fmaf(w3, lo.y, acc.y);
      acc.z = fmaf(w3, hi.x, acc.z); acc.w = fmaf(w3, hi.y, acc.w);
    }
  }
  acc.x += __shfl_xor(acc.x, 16, 64);
  acc.y += __shfl_xor(acc.y, 16, 64);
  acc.z += __shfl_xor(acc.z, 16, 64);
  acc.w += __shfl_xor(acc.w, 16, 64);
  acc.x += __shfl_xor(acc.x, 32, 64);
  acc.y += __shfl_xor(acc.y, 32, 64);
  acc.z += __shfl_xor(acc.z, 32, 64);
  acc.w += __shfl_xor(acc.w, 32, 64);
  if (grp == 0) {
    __half2* p = (__half2*)&rs;
    float2 lo = __half22float2(p[0]), hi = __half22float2(p[1]);
    float4 bs = ((const float4*)bias)[q];
    float4 o;
    o.x = (acc.x + lo.x) * di + bs.x;
    o.y = (acc.y + lo.y) * di + bs.y;
    o.z = (acc.z + hi.x) * di + bs.z;
    o.w = (acc.w + hi.y) * di + bs.w;
    if (relu) {
      o.x = fmaxf(o.x, 0.f);
      o.y = fmaxf(o.y, 0.f);
      o.z = fmaxf(o.z, 0.f);
      o.w = fmaxf(o.w, 0.f);
    }
    float2 pk;
    ((__half2*)&pk)[0] = __floats2half2_rn(o.x, o.y);
    ((__half2*)&pk)[1] = __floats2half2_rn(o.z, o.w);
    *(float2*)(G + (size_t)node * 64 + q * 4) = pk;
  }
}

// ---------------- BN stats (fp16 input, fp32 accum, f64 atomics) ----------------
__global__ __launch_bounds__(256) void k_stats(const __half* __restrict__ H,
                                               double* __restrict__ st) {
  int q = threadIdx.x & 15;   // feature quarter (4 halves)
  int rg = threadIdx.x >> 4;  // 16 row-groups per block
  float4 s1 = {0.f, 0.f, 0.f, 0.f};
  float4 s2 = {0.f, 0.f, 0.f, 0.f};
  for (int r = blockIdx.x * 16 + rg; r < NN; r += gridDim.x * 16) {
    float2 raw = *(const float2*)(H + (size_t)r * 64 + q * 4);
    const __half2* hp = (const __half2*)&raw;
    float2 lo = __half22float2(hp[0]), hi = __half22float2(hp[1]);
    s1.x += lo.x; s1.y += lo.y; s1.z += hi.x; s1.w += hi.y;
    s2.x = fmaf(lo.x, lo.x, s2.x); s2.y = fmaf(lo.y, lo.y, s2.y);
    s2.z = fmaf(hi.x, hi.x, s2.z); s2.w = fmaf(hi.y, hi.y, s2.w);
  }
  __shared__ float a[16][16][8];
  a[rg][q][0] = s1.x; a[rg][q][1] = s1.y; a[rg][q][2] = s1.z; a[rg][q][3] = s1.w;
  a[rg][q][4] = s2.x; a[rg][q][5] = s2.y; a[rg][q][6] = s2.z; a[rg][q][7] = s2.w;
  __syncthreads();
  int tid = threadIdx.x;
  if (tid < 128) {
    int f = tid & 63;        // feature
    int which = tid >> 6;    // 0 = sum, 1 = sumsq
    int qq = f >> 2, jj = (f & 3) + which * 4;
    float t = 0.f;
#pragma unroll
    for (int g = 0; g < 16; g++) t += a[g][qq][jj];
    unsafeAtomicAdd(&st[which * 64 + f], (double)t);
  }
}

// ------- fused: BN3 (G fp16) + residual (fp32) + matmul 64->2, T2 *= dinv --------
__global__ void k_bnmmout(const __half* __restrict__ G, const double* __restrict__ st,
                          const float* __restrict__ gamma, const float* __restrict__ beta,
                          const float* __restrict__ res, const float* __restrict__ W,
                          const int2* __restrict__ rc, float* __restrict__ T2,
                          int nrows) {
  __shared__ float Wl[128];
  __shared__ float scl[128];
  int tid = threadIdx.x;
  if (tid < 32) ((float4*)Wl)[tid] = ((const float4*)W)[tid];
  else if (tid >= 64 && tid < 128) {
    int f = tid - 64;
    double m = st[f] / (double)NN;
    double var = st[64 + f] / (double)NN - m * m;
    float scale = gamma[f] * rsqrtf((float)var + EPSF);
    scl[f] = scale;
    scl[64 + f] = beta[f] - (float)m * scale;
  }
  __syncthreads();
  int row = blockIdx.x * 256 + tid;
  if (row >= nrows) return;
  const __half* g = G + (size_t)row * 64;
  const float4* r4 = (const float4*)(res + (size_t)row * 64);
  float a0 = 0.f, a1 = 0.f;
#pragma unroll
  for (int q = 0; q < 16; q++) {
    float2 raw = *(const float2*)(g + q * 4);
    const __half2* hp = (const __half2*)&raw;
    float2 lo = __half22float2(hp[0]), hi = __half22float2(hp[1]);
    float4 rr = r4[q];
    float4 s = ((const float4*)scl)[q];
    float4 sh = ((const float4*)(scl + 64))[q];
    float h0 = lo.x * s.x + sh.x + rr.x;
    float h1 = lo.y * s.y + sh.y + rr.y;
    float h2 = hi.x * s.z + sh.z + rr.z;
    float h3 = hi.y * s.w + sh.w + rr.w;
    const float* wk = Wl + q * 8;
    a0 = fmaf(h0, wk[0], a0); a1 = fmaf(h0, wk[1], a1);
    a0 = fmaf(h1, wk[2], a0); a1 = fmaf(h1, wk[3], a1);
    a0 = fmaf(h2, wk[4], a0); a1 = fmaf(h2, wk[5], a1);
    a0 = fmaf(h3, wk[6], a0); a1 = fmaf(h3, wk[7], a1);
  }
  float dv = rsqrtf((float)rc[row].y + 1.0f);
  T2[(size_t)row * 2 + 0] = a0 * dv;
  T2[(size_t)row * 2 + 1] = a1 * dv;
}

// ---- fused final aggregation (dim 2, T2 pre-scaled) + pool + ticket finalize ----
__global__ void k_agg2pool(const float* __restrict__ T2, const int2* __restrict__ rc,
                           const int* __restrict__ col, const float* __restrict__ bias,
                           const int* __restrict__ batch, float* __restrict__ pool,
                           int* __restrict__ pcnt, int* __restrict__ tick,
                           float* __restrict__ out, int nblk) {
  __shared__ float pl[128];
  __shared__ int pc[64];
  __shared__ int lastflag;
  int tid = threadIdx.x;
  if (tid < 128) pl[tid] = 0.f;
  if (tid < 64) pc[tid] = 0;
  __syncthreads();
  int node = blockIdx.x * 256 + tid;
  if (node < NN) {
    int2 sc = rc[node];
    int s = sc.x;
    int c = sc.y;
    float a0 = 0.f, a1 = 0.f;
    for (int i = 0; i < c; i += 4) {
      int j0 = i, j1 = i + 1, j2 = i + 2, j3 = i + 3;
      int s0 = col[s + j0];
      int sA = col[s + (j1 < c ? j1 : j0)];
      int sB = col[s + (j2 < c ? j2 : j0)];
      int sC = col[s + (j3 < c ? j3 : j0)];
      float2 t0 = *(const float2*)(T2 + 2 * (size_t)s0);
      float2 t1 = *(const float2*)(T2 + 2 * (size_t)sA);
      float2 t2 = *(const float2*)(T2 + 2 * (size_t)sB);
      float2 t3 = *(const float2*)(T2 + 2 * (size_t)sC);
      float w1 = j1 < c ? 1.f : 0.f;
      float w2 = j2 < c ? 1.f : 0.f;
      float w3 = j3 < c ? 1.f : 0.f;
      a0 += t0.x; a1 += t0.y;
      a0 = fmaf(w1, t1.x, a0); a1 = fmaf(w1, t1.y, a1);
      a0 = fmaf(w2, t2.x, a0); a1 = fmaf(w2, t2.y, a1);
      a0 = fmaf(w3, t3.x, a0); a1 = fmaf(w3, t3.y, a1);
    }
    float di = rsqrtf((float)c + 1.0f);
    float2 tn = *(const float2*)(T2 + 2 * (size_t)node);
    float v0 = (a0 + tn.x) * di + bias[0];
    float v1 = (a1 + tn.y) * di + bias[1];
    int bb = batch[node];
    atomicAdd(&pl[bb * 2 + 0], v0);
    atomicAdd(&pl[bb * 2 + 1], v1);
    atomicAdd(&pc[bb], 1);
  }
  __syncthreads();
  if (tid < 128 && pl[tid] != 0.f) unsafeAtomicAdd(&pool[tid], pl[tid]);
  if (tid < 64 && pc[tid] != 0) atomicAdd(&pcnt[tid], pc[tid]);
  __syncthreads();
  if (tid == 0) {
    __threadfence();
    int old = atomicAdd(tick, 1);
    lastflag = (old == nblk - 1) ? 1 : 0;
  }
  __syncthreads();
  if (lastflag && tid < 128) {
    float v = unsafeAtomicAdd(&pool[tid], 0.f);       // coherent read
    int c = atomicAdd(&pcnt[tid >> 1], 0);            // coherent read
    out[tid] = v / (float)(c > 0 ? c : 1);
  }
}

extern "C" void kernel_launch(void* const* d_in, const int* in_sizes, int n_in,
                              void* d_out, int out_size, void* d_ws, size_t ws_size,
                              hipStream_t stream) {
  (void)in_sizes; (void)n_in; (void)out_size; (void)ws_size;
  const float* x     = (const float*)d_in[0];
  const float* W_in  = (const float*)d_in[1];
  const float* b_in  = (const float*)d_in[2];
  const float* W_h   = (const float*)d_in[3];
  const float* b_h   = (const float*)d_in[4];
  const float* W_out = (const float*)d_in[5];
  const float* b_out = (const float*)d_in[6];
  const float* gamma = (const float*)d_in[7];
  const float* beta  = (const float*)d_in[8];
  const int*   ei    = (const int*)d_in[9];
  const int*   batch = (const int*)d_in[10];
  const int* src = ei;
  const int* dst = ei + NE;
  float* out = (float*)d_out;

  char* w = (char*)d_ws;
  size_t off = 0;
  auto alloc = [&](size_t bytes) -> void* {
    void* p = (void*)(w + off);
    off += (bytes + 511) & ~(size_t)511;
    return p;
  };
  int2*   rc    = (int2*)alloc((size_t)NN * 8);
  int*    col   = (int*)alloc((size_t)NBUCK * BCAP * 4);   // slotted, 6.4 MB
  // zeroed zone: stats (3*128 dbl = 3072) | pool (512) | pcnt (256) | tick (256) |
  //              bcur (782*4 = 3128) -> 7224 bytes
  char*   zzone = (char*)alloc(7680);
  double* stats = (double*)zzone;
  float*  pool  = (float*)(zzone + 3072);
  int*    pcnt  = (int*)(zzone + 3584);
  int*    tick  = (int*)(zzone + 3840);
  int*    bcur  = (int*)(zzone + 4096);
  __half* Ga    = (__half*)alloc((size_t)NN * HID * 2);   // G1 / G3
  __half* Gb    = (__half*)alloc((size_t)NN * HID * 2);   // G2
  float*  hA    = (float*)alloc((size_t)NN * HID * 4);    // h1 (fp32)
  float*  hB    = (float*)alloc((size_t)NN * HID * 4);    // h2 (fp32)
  __half* Th    = (__half*)alloc((size_t)NN * HID * 2);
  float*  T2    = (float*)alloc((size_t)NN * 2 * 4);
  // ebuf (slotted, 782*2048*8 = 12.82MB) aliases hA (25.6MB): consumed by
  // k_bucket_csr; hA's first write is layer-2 mmB's Hside (step 6)
  unsigned long long* ebuf = (unsigned long long*)hA;

  hipMemsetAsync(zzone, 0, 7424, stream);

  // graph prep: slotted bucket-radix CSR build (no histogram/scan passes)
  k_escatter<<<293, 256, 0, stream>>>(src, dst, bcur, ebuf);
  k_bucket_csr<<<NBUCK, 256, 0, stream>>>(ebuf, bcur, rc, col);

  const int mmgrid = (NN + 63) / 64;   // 1563

  // layer 1: x(128) -> Th (fp16, pre-scaled) -> G1=Ga (fp16)
  k_mmA<<<mmgrid, 512, 0, stream>>>(x, W_in, rc, Th, NN);
  k_agg64<<<(NN + 3) / 4, 256, 0, stream>>>(Th, rc, col, b_in, Ga, 1);
  k_stats<<<512, 256, 0, stream>>>(Ga, stats);

  // layer 2: h1 = BN1(G1) (fp32 side-> hA); Th = h1@W_h0; G2 = Gb
  k_mmB<<<mmgrid, 512, 0, stream>>>(Ga, stats, gamma, beta, nullptr, hA, W_h,
                                    rc, Th, NN);
  k_agg64<<<(NN + 3) / 4, 256, 0, stream>>>(Th, rc, col, b_h, Gb, 1);
  k_stats<<<512, 256, 0, stream>>>(Gb, stats + 128);

  // layer 3: h2 = BN2(G2)+h1 (fp32 side-> hB); Th = h2@W_h1; G3 = Ga (G1 dead)
  k_mmB<<<mmgrid, 512, 0, stream>>>(Gb, stats + 128, gamma + 64, beta + 64, hA,
                                    hB, W_h + HID * HID, rc, Th, NN);
  k_agg64<<<(NN + 3) / 4, 256, 0, stream>>>(Th, rc, col, b_h + HID, Ga, 1);
  k_stats<<<512, 256, 0, stream>>>(Ga, stats + 256);

  // output: h3 = BN3(G3)+h2(hB) fused with mm 64->2 (T2 pre-scaled), then agg+pool+div
  k_bnmmout<<<(NN + 255) / 256, 256, 0, stream>>>(Ga, stats + 256, gamma + 128,
                                                  beta + 128, hB, W_out, rc, T2, NN);
  const int pgrid = (NN + 255) / 256;  // 391
  k_agg2pool<<<pgrid, 256, 0, stream>>>(T2, rc, col, b_out, batch, pool,
                                        pcnt, tick, out, pgrid);
}

// Round 16
// 369.109 us; speedup vs baseline: 1.2204x; 1.0094x over previous
//
#include <hip/hip_runtime.h>
#include <hip/hip_fp16.h>

// EnhancedGNN on MI355X.
// R18: (1) agg64 re-partitioned 16x4 -> 8 feature-lanes x 8 edge-groups with
//      float4 (16B) gathers: half the gather instructions per edge, 32 edges in
//      flight (97% of nodes single-pass). (2) residuals h1/h2 stored fp16
//      (last fp32 streams; -19MB across mmB x2 + bnmmout). ebuf aliases hA with
//      12KB spill into hB (both written long after CSR). R17 base kept. 13 launches.

#define NN 100000
#define NE 1200000
#define NBATCH 64
#define IND 128
#define HID 64
#define EPSF 1e-5f
#define NBUCK 782   // ceil(100000/128)
#define NPB 128     // nodes per bucket; bucket(d) = d >> 7
#define BCAP 2048   // slot capacity per bucket (mean 1536, sigma 39)

// scatter (src,dst) pairs into per-bucket SLOTS of ebuf; LDS hist + global cursor
__global__ void k_escatter(const int* __restrict__ src, const int* __restrict__ dst,
                           int* __restrict__ bcur, unsigned long long* __restrict__ ebuf) {
  __shared__ int lh[NBUCK];
  __shared__ int lbase[NBUCK];
  int tid = threadIdx.x;
  for (int i = tid; i < NBUCK; i += 256) lh[i] = 0;
  __syncthreads();
  int base4 = blockIdx.x * 1024;  // int4 units; block covers 4096 edges
  int sv[16], dv[16], rk[16];
#pragma unroll
  for (int j = 0; j < 4; j++) {
    int i4 = base4 + j * 256 + tid;
    if (i4 * 4 < NE) {
      int4 s4 = ((const int4*)src)[i4];
      int4 d4 = ((const int4*)dst)[i4];
      sv[4 * j + 0] = s4.x; dv[4 * j + 0] = d4.x;
      sv[4 * j + 1] = s4.y; dv[4 * j + 1] = d4.y;
      sv[4 * j + 2] = s4.z; dv[4 * j + 2] = d4.z;
      sv[4 * j + 3] = s4.w; dv[4 * j + 3] = d4.w;
      rk[4 * j + 0] = atomicAdd(&lh[d4.x >> 7], 1);
      rk[4 * j + 1] = atomicAdd(&lh[d4.y >> 7], 1);
      rk[4 * j + 2] = atomicAdd(&lh[d4.z >> 7], 1);
      rk[4 * j + 3] = atomicAdd(&lh[d4.w >> 7], 1);
    } else {
      dv[4 * j + 0] = -1; dv[4 * j + 1] = -1;
      dv[4 * j + 2] = -1; dv[4 * j + 3] = -1;
    }
  }
  __syncthreads();
  for (int i = tid; i < NBUCK; i += 256) {
    int v = lh[i];
    lbase[i] = v ? atomicAdd(&bcur[i], v) : 0;
  }
  __syncthreads();
#pragma unroll
  for (int j = 0; j < 16; j++) {
    if (dv[j] >= 0) {
      int b = dv[j] >> 7;
      ebuf[(size_t)b * BCAP + lbase[b] + rk[j]] =
          (unsigned long long)(unsigned)sv[j] | ((unsigned long long)(unsigned)dv[j] << 32);
    }
  }
}

// one block per bucket: local hist -> rc(int2), local scan, LDS-cursor fill -> col
__global__ void k_bucket_csr(const unsigned long long* __restrict__ ebuf,
                             const int* __restrict__ bcur, int2* __restrict__ rc,
                             int* __restrict__ col) {
  __shared__ int ldeg[NPB];
  __shared__ int lcur[NPB];
  __shared__ int sred[NPB];
  int b = blockIdx.x, tid = threadIdx.x;
  int nbase = b * NPB;
  int e0 = b * BCAP;
  int cnt = bcur[b];
  if (tid < NPB) ldeg[tid] = 0;
  __syncthreads();
  for (int e = tid; e < cnt; e += 256) {
    int d = (int)(ebuf[e0 + e] >> 32) - nbase;
    atomicAdd(&ldeg[d], 1);
  }
  __syncthreads();
  if (tid < NPB) sred[tid] = ldeg[tid];
  __syncthreads();
  for (int off = 1; off < NPB; off <<= 1) {
    int v = 0;
    if (tid < NPB && tid >= off) v = sred[tid - off];
    __syncthreads();
    if (tid < NPB) sred[tid] += v;
    __syncthreads();
  }
  if (tid < NPB) {
    int excl = sred[tid] - ldeg[tid];
    lcur[tid] = excl;
    int gn = nbase + tid;
    if (gn < NN) rc[gn] = make_int2(e0 + excl, ldeg[tid]);
  }
  __syncthreads();
  for (int e = tid; e < cnt; e += 256) {
    unsigned long long p = ebuf[e0 + e];
    int s = (int)(unsigned)p;
    int d = (int)(p >> 32) - nbase;
    int r = atomicAdd(&lcur[d], 1);
    col[e0 + r] = s;
  }
}

// ------ mm A: X[nrows,128] @ W[128,64] -> Th (fp16) * dinv[row] ------------------
__global__ __launch_bounds__(512) void k_mmA(const float* __restrict__ X,
                                             const float* __restrict__ W,
                                             const int2* __restrict__ rc,
                                             __half* __restrict__ T, int nrows) {
  __shared__ float xs[64 * 65];
  int tid = threadIdx.x;
  int rbase = blockIdx.x * 64;
  int q8 = __builtin_amdgcn_readfirstlane(tid >> 6);  // wave-uniform col eighth
  int r = tid & 63;
  int r65 = r * 65;
  float4 acc[2];
  acc[0] = {0.f, 0.f, 0.f, 0.f};
  acc[1] = {0.f, 0.f, 0.f, 0.f};

  for (int ch = 0; ch < 2; ch++) {
#pragma unroll
    for (int i = 0; i < 2; i++) {
      int f = i * 512 + tid;
      int rr = f >> 4, kq = f & 15;
      int gr = rbase + rr;
      int grc = gr < nrows ? gr : nrows - 1;
      float4 v = *(const float4*)(X + (size_t)grc * 128 + ch * 64 + 4 * kq);
      float* p = xs + rr * 65 + 4 * kq;
      p[0] = v.x; p[1] = v.y; p[2] = v.z; p[3] = v.w;
    }
    __syncthreads();
    const float* Wb = W + ch * 64 * 64 + q8 * 8;
#pragma unroll 4
    for (int k = 0; k < 64; k++) {
      float xk = xs[r65 + k];
      const float4* wr = (const float4*)(Wb + (size_t)k * 64);
      float4 w0 = wr[0], w1 = wr[1];
      acc[0].x = fmaf(xk, w0.x, acc[0].x);
      acc[0].y = fmaf(xk, w0.y, acc[0].y);
      acc[0].z = fmaf(xk, w0.z, acc[0].z);
      acc[0].w = fmaf(xk, w0.w, acc[0].w);
      acc[1].x = fmaf(xk, w1.x, acc[1].x);
      acc[1].y = fmaf(xk, w1.y, acc[1].y);
      acc[1].z = fmaf(xk, w1.z, acc[1].z);
      acc[1].w = fmaf(xk, w1.w, acc[1].w);
    }
    if (ch == 0) __syncthreads();
  }

  int row = rbase + r;
  if (row < nrows) {
    float dv = rsqrtf((float)rc[row].y + 1.0f);
    __half2 o2[4];
    o2[0] = __floats2half2_rn(acc[0].x * dv, acc[0].y * dv);
    o2[1] = __floats2half2_rn(acc[0].z * dv, acc[0].w * dv);
    o2[2] = __floats2half2_rn(acc[1].x * dv, acc[1].y * dv);
    o2[3] = __floats2half2_rn(acc[1].z * dv, acc[1].w * dv);
    *(float4*)(T + (size_t)row * 64 + q8 * 8) = *(float4*)&o2[0];
  }
}

// ------ mm B: G fp16; BN(G)(+res fp16) -> Hside fp16; Th = (h @ W)*dinv fp16 -----
__global__ __launch_bounds__(512) void k_mmB(const __half* __restrict__ G,
                                             const double* __restrict__ st,
                                             const float* __restrict__ gamma,
                                             const float* __restrict__ beta,
                                             const __half* __restrict__ res,
                                             __half* __restrict__ Hside,
                                             const float* __restrict__ W,
                                             const int2* __restrict__ rc,
                                             __half* __restrict__ T, int nrows) {
  __shared__ float xs[64 * 65];
  __shared__ float scl[128];
  int tid = threadIdx.x;
  if (tid < 64) {
    double m = st[tid] / (double)NN;
    double var = st[64 + tid] / (double)NN - m * m;
    float scale = gamma[tid] * rsqrtf((float)var + EPSF);
    scl[tid] = scale;
    scl[64 + tid] = beta[tid] - (float)m * scale;
  }
  __syncthreads();

  int rbase = blockIdx.x * 64;
  {
    int rr = tid >> 3;   // 0..63 row
    int kc = tid & 7;    // chunk of 8 features
    int gr = rbase + rr;
    int grc = gr < nrows ? gr : nrows - 1;
    int fb = kc * 8;
    float4 raw = *(const float4*)(G + (size_t)grc * 64 + fb);  // 8 halves
    const __half2* hp = (const __half2*)&raw;
    float v[8];
    float2 t0 = __half22float2(hp[0]); v[0] = t0.x; v[1] = t0.y;
    float2 t1 = __half22float2(hp[1]); v[2] = t1.x; v[3] = t1.y;
    float2 t2 = __half22float2(hp[2]); v[4] = t2.x; v[5] = t2.y;
    float2 t3 = __half22float2(hp[3]); v[6] = t3.x; v[7] = t3.y;
#pragma unroll
    for (int j = 0; j < 8; j++) v[j] = v[j] * scl[fb + j] + scl[64 + fb + j];
    if (res != nullptr) {
      float4 rraw = *(const float4*)(res + (size_t)grc * 64 + fb);  // 8 halves
      const __half2* rp = (const __half2*)&rraw;
      float2 a0 = __half22float2(rp[0]); v[0] += a0.x; v[1] += a0.y;
      float2 a1 = __half22float2(rp[1]); v[2] += a1.x; v[3] += a1.y;
      float2 a2 = __half22float2(rp[2]); v[4] += a2.x; v[5] += a2.y;
      float2 a3 = __half22float2(rp[3]); v[6] += a3.x; v[7] += a3.y;
    }
    if (gr < nrows) {
      __half2 hpk[4];
      hpk[0] = __floats2half2_rn(v[0], v[1]);
      hpk[1] = __floats2half2_rn(v[2], v[3]);
      hpk[2] = __floats2half2_rn(v[4], v[5]);
      hpk[3] = __floats2half2_rn(v[6], v[7]);
      *(float4*)(Hside + (size_t)gr * 64 + fb) = *(float4*)hpk;
    }
    float* p = xs + rr * 65 + fb;
#pragma unroll
    for (int j = 0; j < 8; j++) p[j] = v[j];
  }
  __syncthreads();

  int q8 = __builtin_amdgcn_readfirstlane(tid >> 6);
  int r = tid & 63;
  int r65 = r * 65;
  float4 acc[2];
  acc[0] = {0.f, 0.f, 0.f, 0.f};
  acc[1] = {0.f, 0.f, 0.f, 0.f};
  const float* Wb = W + q8 * 8;
#pragma unroll 4
  for (int k = 0; k < 64; k++) {
    float xk = xs[r65 + k];
    const float4* wr = (const float4*)(Wb + (size_t)k * 64);
    float4 w0 = wr[0], w1 = wr[1];
    acc[0].x = fmaf(xk, w0.x, acc[0].x);
    acc[0].y = fmaf(xk, w0.y, acc[0].y);
    acc[0].z = fmaf(xk, w0.z, acc[0].z);
    acc[0].w = fmaf(xk, w0.w, acc[0].w);
    acc[1].x = fmaf(xk, w1.x, acc[1].x);
    acc[1].y = fmaf(xk, w1.y, acc[1].y);
    acc[1].z = fmaf(xk, w1.z, acc[1].z);
    acc[1].w = fmaf(xk, w1.w, acc[1].w);
  }

  int row = rbase + r;
  if (row < nrows) {
    float dv = rsqrtf((float)rc[row].y + 1.0f);
    __half2 o2[4];
    o2[0] = __floats2half2_rn(acc[0].x * dv, acc[0].y * dv);
    o2[1] = __floats2half2_rn(acc[0].z * dv, acc[0].w * dv);
    o2[2] = __floats2half2_rn(acc[1].x * dv, acc[1].y * dv);
    o2[3] = __floats2half2_rn(acc[1].z * dv, acc[1].w * dv);
    *(float4*)(T + (size_t)row * 64 + q8 * 8) = *(float4*)&o2[0];
  }
}

// ------- aggregation: wave/node, 8 feature-lanes x 8 edge-groups, float4 gathers --
// Th pre-scaled by dinv[row]: o = di*(sum Th[src] + Th[node]) + bias. G out fp16.
// 32 edges in flight per iteration; 3-round shuffle reduce.
__global__ void k_agg64(const __half* __restrict__ T, const int2* __restrict__ rc,
                        const int* __restrict__ col, const float* __restrict__ bias,
                        __half* __restrict__ G, int relu) {
  int lane = threadIdx.x & 63;
  int wv = threadIdx.x >> 6;
  int node = blockIdx.x * 4 + wv;
  if (node >= NN) return;
  int grp = lane >> 3;   // 8 edge groups
  int q = lane & 7;      // feature eighth (8 halves = 16B)
  int2 sc = rc[node];
  int s = sc.x;
  int c = sc.y;
  float di = rsqrtf((float)c + 1.0f);
  float4 rs = *(const float4*)(T + (size_t)node * 64 + q * 8);  // self row, early
  float acc[8] = {0.f, 0.f, 0.f, 0.f, 0.f, 0.f, 0.f, 0.f};
  for (int i = 0; i < c; i += 32) {
    int j0 = i + grp, j1 = j0 + 8, j2 = j0 + 16, j3 = j0 + 24;
    int s0 = col[s + (j0 < c ? j0 : 0)];
    int s1 = col[s + (j1 < c ? j1 : 0)];
    int s2 = col[s + (j2 < c ? j2 : 0)];
    int s3 = col[s + (j3 < c ? j3 : 0)];
    float4 r0 = *(const float4*)(T + (size_t)s0 * 64 + q * 8);
    float4 r1 = *(const float4*)(T + (size_t)s1 * 64 + q * 8);
    float4 r2 = *(const float4*)(T + (size_t)s2 * 64 + q * 8);
    float4 r3 = *(const float4*)(T + (size_t)s3 * 64 + q * 8);
    float w0 = j0 < c ? 1.f : 0.f;
    float w1 = j1 < c ? 1.f : 0.f;
    float w2 = j2 < c ? 1.f : 0.f;
    float w3 = j3 < c ? 1.f : 0.f;
    {
      const __half2* p = (const __half2*)&r0;
      float2 f0 = __half22float2(p[0]), f1 = __half22float2(p[1]);
      float2 f2 = __half22float2(p[2]), f3 = __half22float2(p[3]);
      acc[0] = fmaf(w0, f0.x, acc[0]); acc[1] = fmaf(w0, f0.y, acc[1]);
      acc[2] = fmaf(w0, f1.x, acc[2]); acc[3] = fmaf(w0, f1.y, acc[3]);
      acc[4] = fmaf(w0, f2.x, acc[4]); acc[5] = fmaf(w0, f2.y, acc[5]);
      acc[6] = fmaf(w0, f3.x, acc[6]); acc[7] = fmaf(w0, f3.y, acc[7]);
    }
    {
      const __half2* p = (const __half2*)&r1;
      float2 f0 = __half22float2(p[0]), f1 = __half22float2(p[1]);
      float2 f2 = __half22float2(p[2]), f3 = __half22float2(p[3]);
      acc[0] = fmaf(w1, f0.x, acc[0]); acc[1] = fmaf(w1, f0.y, acc[1]);
      acc[2] = fmaf(w1, f1.x, acc[2]); acc[3] = fmaf(w1, f1.y, acc[3]);
      acc[4] = fmaf(w1, f2.x, acc[4]); acc[5] = fmaf(w1, f2.y, acc[5]);
      acc[6] = fmaf(w1, f3.x, acc[6]); acc[7] = fmaf(w1, f3.y, acc[7]);
    }
    {
      const __half2* p = (const __half2*)&r2;
      float2 f0 = __half22float2(p[0]), f1 = __half22float2(p[1]);
      float2 f2 = __half22float2(p[2]), f3 = __half22float2(p[3]);
      acc[0] = fmaf(w2, f0.x, acc[0]); acc[1] = fmaf(w2, f0.y, acc[1]);
      acc[2] = fmaf(w2, f1.x, acc[2]); acc[3] = fmaf(w2, f1.y, acc[3]);
      acc[4] = fmaf(w2, f2.x, acc[4]); acc[5] = fmaf(w2, f2.y, acc[5]);
      acc[6] = fmaf(w2, f3.x, acc[6]); acc[7] = fmaf(w2, f3.y, acc[7]);
    }
    {
      const __half2* p = (const __half2*)&r3;
      float2 f0 = __half22float2(p[0]), f1 = __half22float2(p[1]);
      float2 f2 = __half22float2(p[2]), f3 = __half22float2(p[3]);
      acc[0] = fmaf(w3, f0.x, acc[0]); acc[1] = fmaf(w3, f0.y, acc[1]);
      acc[2] = fmaf(w3, f1.x, acc[2]); acc[3] = fmaf(w3, f1.y, acc[3]);
      acc[4] = fmaf(w3, f2.x, acc[4]); acc[5] = fmaf(w3, f2.y, acc[5]);
      acc[6] = fmaf(w3, f3.x, acc[6]); acc[7] = fmaf(w3, f3.y, acc[7]);
    }
  }
#pragma unroll
  for (int off = 8; off < 64; off <<= 1) {
#pragma unroll
    for (int j = 0; j < 8; j++) acc[j] += __shfl_xor(acc[j], off, 64);
  }
  if (grp == 0) {
    const __half2* p = (const __half2*)&rs;
    float2 f0 = __half22float2(p[0]), f1 = __half22float2(p[1]);
    float2 f2 = __half22float2(p[2]), f3 = __half22float2(p[3]);
    float sv[8] = {f0.x, f0.y, f1.x, f1.y, f2.x, f2.y, f3.x, f3.y};
    float4 b0 = ((const float4*)bias)[q * 2];
    float4 b1 = ((const float4*)bias)[q * 2 + 1];
    float bb[8] = {b0.x, b0.y, b0.z, b0.w, b1.x, b1.y, b1.z, b1.w};
    float o[8];
#pragma unroll
    for (int j = 0; j < 8; j++) {
      o[j] = (acc[j] + sv[j]) * di + bb[j];
      if (relu) o[j] = fmaxf(o[j], 0.f);
    }
    __half2 pk[4];
    pk[0] = __floats2half2_rn(o[0], o[1]);
    pk[1] = __floats2half2_rn(o[2], o[3]);
    pk[2] = __floats2half2_rn(o[4], o[5]);
    pk[3] = __floats2half2_rn(o[6], o[7]);
    *(float4*)(G + (size_t)node * 64 + q * 8) = *(float4*)pk;
  }
}

// ---------------- BN stats (fp16 input, fp32 accum, f64 atomics) ----------------
__global__ __launch_bounds__(256) void k_stats(const __half* __restrict__ H,
                                               double* __restrict__ st) {
  int q = threadIdx.x & 15;   // feature quarter (4 halves)
  int rg = threadIdx.x >> 4;  // 16 row-groups per block
  float4 s1 = {0.f, 0.f, 0.f, 0.f};
  float4 s2 = {0.f, 0.f, 0.f, 0.f};
  for (int r = blockIdx.x * 16 + rg; r < NN; r += gridDim.x * 16) {
    float2 raw = *(const float2*)(H + (size_t)r * 64 + q * 4);
    const __half2* hp = (const __half2*)&raw;
    float2 lo = __half22float2(hp[0]), hi = __half22float2(hp[1]);
    s1.x += lo.x; s1.y += lo.y; s1.z += hi.x; s1.w += hi.y;
    s2.x = fmaf(lo.x, lo.x, s2.x); s2.y = fmaf(lo.y, lo.y, s2.y);
    s2.z = fmaf(hi.x, hi.x, s2.z); s2.w = fmaf(hi.y, hi.y, s2.w);
  }
  __shared__ float a[16][16][8];
  a[rg][q][0] = s1.x; a[rg][q][1] = s1.y; a[rg][q][2] = s1.z; a[rg][q][3] = s1.w;
  a[rg][q][4] = s2.x; a[rg][q][5] = s2.y; a[rg][q][6] = s2.z; a[rg][q][7] = s2.w;
  __syncthreads();
  int tid = threadIdx.x;
  if (tid < 128) {
    int f = tid & 63;        // feature
    int which = tid >> 6;    // 0 = sum, 1 = sumsq
    int qq = f >> 2, jj = (f & 3) + which * 4;
    float t = 0.f;
#pragma unroll
    for (int g = 0; g < 16; g++) t += a[g][qq][jj];
    unsafeAtomicAdd(&st[which * 64 + f], (double)t);
  }
}

// ------- fused: BN3 (G fp16) + residual (fp16) + matmul 64->2, T2 *= dinv --------
__global__ void k_bnmmout(const __half* __restrict__ G, const double* __restrict__ st,
                          const float* __restrict__ gamma, const float* __restrict__ beta,
                          const __half* __restrict__ res, const float* __restrict__ W,
                          const int2* __restrict__ rc, float* __restrict__ T2,
                          int nrows) {
  __shared__ float Wl[128];
  __shared__ float scl[128];
  int tid = threadIdx.x;
  if (tid < 32) ((float4*)Wl)[tid] = ((const float4*)W)[tid];
  else if (tid >= 64 && tid < 128) {
    int f = tid - 64;
    double m = st[f] / (double)NN;
    double var = st[64 + f] / (double)NN - m * m;
    float scale = gamma[f] * rsqrtf((float)var + EPSF);
    scl[f] = scale;
    scl[64 + f] = beta[f] - (float)m * scale;
  }
  __syncthreads();
  int row = blockIdx.x * 256 + tid;
  if (row >= nrows) return;
  const __half* g = G + (size_t)row * 64;
  const __half* rr = res + (size_t)row * 64;
  float a0 = 0.f, a1 = 0.f;
#pragma unroll
  for (int qq = 0; qq < 8; qq++) {
    int fb = qq * 8;
    float4 graw = *(const float4*)(g + fb);   // 8 halves
    float4 rraw = *(const float4*)(rr + fb);  // 8 halves
    const __half2* gp = (const __half2*)&graw;
    const __half2* rp = (const __half2*)&rraw;
    float gv[8], rv[8];
    float2 t0 = __half22float2(gp[0]); gv[0] = t0.x; gv[1] = t0.y;
    float2 t1 = __half22float2(gp[1]); gv[2] = t1.x; gv[3] = t1.y;
    float2 t2 = __half22float2(gp[2]); gv[4] = t2.x; gv[5] = t2.y;
    float2 t3 = __half22float2(gp[3]); gv[6] = t3.x; gv[7] = t3.y;
    float2 u0 = __half22float2(rp[0]); rv[0] = u0.x; rv[1] = u0.y;
    float2 u1 = __half22float2(rp[1]); rv[2] = u1.x; rv[3] = u1.y;
    float2 u2 = __half22float2(rp[2]); rv[4] = u2.x; rv[5] = u2.y;
    float2 u3 = __half22float2(rp[3]); rv[6] = u3.x; rv[7] = u3.y;
#pragma unroll
    for (int j = 0; j < 8; j++) {
      float h = gv[j] * scl[fb + j] + scl[64 + fb + j] + rv[j];
      a0 = fmaf(h, Wl[(fb + j) * 2 + 0], a0);
      a1 = fmaf(h, Wl[(fb + j) * 2 + 1], a1);
    }
  }
  float dv = rsqrtf((float)rc[row].y + 1.0f);
  T2[(size_t)row * 2 + 0] = a0 * dv;
  T2[(size_t)row * 2 + 1] = a1 * dv;
}

// ---- fused final aggregation (dim 2, T2 pre-scaled) + pool + ticket finalize ----
__global__ void k_agg2pool(const float* __restrict__ T2, const int2* __restrict__ rc,
                           const int* __restrict__ col, const float* __restrict__ bias,
                           const int* __restrict__ batch, float* __restrict__ pool,
                           int* __restrict__ pcnt, int* __restrict__ tick,
                           float* __restrict__ out, int nblk) {
  __shared__ float pl[128];
  __shared__ int pc[64];
  __shared__ int lastflag;
  int tid = threadIdx.x;
  if (tid < 128) pl[tid] = 0.f;
  if (tid < 64) pc[tid] = 0;
  __syncthreads();
  int node = blockIdx.x * 256 + tid;
  if (node < NN) {
    int2 sc = rc[node];
    int s = sc.x;
    int c = sc.y;
    float a0 = 0.f, a1 = 0.f;
    for (int i = 0; i < c; i += 4) {
      int j0 = i, j1 = i + 1, j2 = i + 2, j3 = i + 3;
      int s0 = col[s + j0];
      int sA = col[s + (j1 < c ? j1 : j0)];
      int sB = col[s + (j2 < c ? j2 : j0)];
      int sC = col[s + (j3 < c ? j3 : j0)];
      float2 t0 = *(const float2*)(T2 + 2 * (size_t)s0);
      float2 t1 = *(const float2*)(T2 + 2 * (size_t)sA);
      float2 t2 = *(const float2*)(T2 + 2 * (size_t)sB);
      float2 t3 = *(const float2*)(T2 + 2 * (size_t)sC);
      float w1 = j1 < c ? 1.f : 0.f;
      float w2 = j2 < c ? 1.f : 0.f;
      float w3 = j3 < c ? 1.f : 0.f;
      a0 += t0.x; a1 += t0.y;
      a0 = fmaf(w1, t1.x, a0); a1 = fmaf(w1, t1.y, a1);
      a0 = fmaf(w2, t2.x, a0); a1 = fmaf(w2, t2.y, a1);
      a0 = fmaf(w3, t3.x, a0); a1 = fmaf(w3, t3.y, a1);
    }
    float di = rsqrtf((float)c + 1.0f);
    float2 tn = *(const float2*)(T2 + 2 * (size_t)node);
    float v0 = (a0 + tn.x) * di + bias[0];
    float v1 = (a1 + tn.y) * di + bias[1];
    int bb = batch[node];
    atomicAdd(&pl[bb * 2 + 0], v0);
    atomicAdd(&pl[bb * 2 + 1], v1);
    atomicAdd(&pc[bb], 1);
  }
  __syncthreads();
  if (tid < 128 && pl[tid] != 0.f) unsafeAtomicAdd(&pool[tid], pl[tid]);
  if (tid < 64 && pc[tid] != 0) atomicAdd(&pcnt[tid], pc[tid]);
  __syncthreads();
  if (tid == 0) {
    __threadfence();
    int old = atomicAdd(tick, 1);
    lastflag = (old == nblk - 1) ? 1 : 0;
  }
  __syncthreads();
  if (lastflag && tid < 128) {
    float v = unsafeAtomicAdd(&pool[tid], 0.f);       // coherent read
    int c = atomicAdd(&pcnt[tid >> 1], 0);            // coherent read
    out[tid] = v / (float)(c > 0 ? c : 1);
  }
}

extern "C" void kernel_launch(void* const* d_in, const int* in_sizes, int n_in,
                              void* d_out, int out_size, void* d_ws, size_t ws_size,
                              hipStream_t stream) {
  (void)in_sizes; (void)n_in; (void)out_size; (void)ws_size;
  const float* x     = (const float*)d_in[0];
  const float* W_in  = (const float*)d_in[1];
  const float* b_in  = (const float*)d_in[2];
  const float* W_h   = (const float*)d_in[3];
  const float* b_h   = (const float*)d_in[4];
  const float* W_out = (const float*)d_in[5];
  const float* b_out = (const float*)d_in[6];
  const float* gamma = (const float*)d_in[7];
  const float* beta  = (const float*)d_in[8];
  const int*   ei    = (const int*)d_in[9];
  const int*   batch = (const int*)d_in[10];
  const int* src = ei;
  const int* dst = ei + NE;
  float* out = (float*)d_out;

  char* w = (char*)d_ws;
  size_t off = 0;
  auto alloc = [&](size_t bytes) -> void* {
    void* p = (void*)(w + off);
    off += (bytes + 511) & ~(size_t)511;
    return p;
  };
  int2*   rc    = (int2*)alloc((size_t)NN * 8);
  int*    col   = (int*)alloc((size_t)NBUCK * BCAP * 4);   // slotted, 6.4 MB
  // zeroed zone: stats (3*128 dbl = 3072) | pool (512) | pcnt (256) | tick (256) |
  //              bcur (782*4 = 3128) -> 7224 bytes
  char*   zzone = (char*)alloc(7680);
  double* stats = (double*)zzone;
  float*  pool  = (float*)(zzone + 3072);
  int*    pcnt  = (int*)(zzone + 3584);
  int*    tick  = (int*)(zzone + 3840);
  int*    bcur  = (int*)(zzone + 4096);
  __half* Ga    = (__half*)alloc((size_t)NN * HID * 2);   // G1 / G3
  __half* Gb    = (__half*)alloc((size_t)NN * HID * 2);   // G2
  __half* hA    = (__half*)alloc((size_t)NN * HID * 2);   // h1 (fp16)
  __half* hB    = (__half*)alloc((size_t)NN * HID * 2);   // h2 (fp16)
  __half* Th    = (__half*)alloc((size_t)NN * HID * 2);
  float*  T2    = (float*)alloc((size_t)NN * 2 * 4);
  // ebuf (slotted, 782*2048*8 = 12.81MB) aliases hA (12.80MB) + 12KB spill into
  // hB: consumed by k_bucket_csr (step 2); hA first written step 6, hB step 8
  unsigned long long* ebuf = (unsigned long long*)hA;

  hipMemsetAsync(zzone, 0, 7424, stream);

  // graph prep: slotted bucket-radix CSR build (no histogram/scan passes)
  k_escatter<<<293, 256, 0, stream>>>(src, dst, bcur, ebuf);
  k_bucket_csr<<<NBUCK, 256, 0, stream>>>(ebuf, bcur, rc, col);

  const int mmgrid = (NN + 63) / 64;   // 1563

  // layer 1: x(128) -> Th (fp16, pre-scaled) -> G1=Ga (fp16)
  k_mmA<<<mmgrid, 512, 0, stream>>>(x, W_in, rc, Th, NN);
  k_agg64<<<(NN + 3) / 4, 256, 0, stream>>>(Th, rc, col, b_in, Ga, 1);
  k_stats<<<512, 256, 0, stream>>>(Ga, stats);

  // layer 2: h1 = BN1(G1) (fp16 side-> hA); Th = h1@W_h0; G2 = Gb
  k_mmB<<<mmgrid, 512, 0, stream>>>(Ga, stats, gamma, beta, nullptr, hA, W_h,
                                    rc, Th, NN);
  k_agg64<<<(NN + 3) / 4, 256, 0, stream>>>(Th, rc, col, b_h, Gb, 1);
  k_stats<<<512, 256, 0, stream>>>(Gb, stats + 128);

  // layer 3: h2 = BN2(G2)+h1 (fp16 side-> hB); Th = h2@W_h1; G3 = Ga (G1 dead)
  k_mmB<<<mmgrid, 512, 0, stream>>>(Gb, stats + 128, gamma + 64, beta + 64, hA,
                                    hB, W_h + HID * HID, rc, Th, NN);
  k_agg64<<<(NN + 3) / 4, 256, 0, stream>>>(Th, rc, col, b_h + HID, Ga, 1);
  k_stats<<<512, 256, 0, stream>>>(Ga, stats + 256);

  // output: h3 = BN3(G3)+h2(hB) fused with mm 64->2 (T2 pre-scaled), then agg+pool+div
  k_bnmmout<<<(NN + 255) / 256, 256, 0, stream>>>(Ga, stats + 256, gamma + 128,
                                                  beta + 128, hB, W_out, rc, T2, NN);
  const int pgrid = (NN + 255) / 256;  // 391
  k_agg2pool<<<pgrid, 256, 0, stream>>>(T2, rc, col, b_out, batch, pool,
                                        pcnt, tick, out, pgrid);
}

// Round 17
// 361.485 us; speedup vs baseline: 1.2461x; 1.0211x over previous
//
#include <hip/hip_runtime.h>
#include <hip/hip_fp16.h>

// EnhancedGNN on MI355X.
// R19: R18's 8x8/float4 agg64 re-partition reverted -- it flipped the kernel
//      VALU-bound (VALUBusy 47->80%, 36->42us): 8 cvt+8 fma per lane-gather and
//      2.67x masked-slot waste at mean deg 12. Restored R17's 16 feature-lanes
//      x 4 edge-groups float2 gather. fp16 residuals + fp16 G/T + slotted CSR +
//      dinv-free + self-row hoist all kept. 13 launches.

#define NN 100000
#define NE 1200000
#define NBATCH 64
#define IND 128
#define HID 64
#define EPSF 1e-5f
#define NBUCK 782   // ceil(100000/128)
#define NPB 128     // nodes per bucket; bucket(d) = d >> 7
#define BCAP 2048   // slot capacity per bucket (mean 1536, sigma 39)

// scatter (src,dst) pairs into per-bucket SLOTS of ebuf; LDS hist + global cursor
__global__ void k_escatter(const int* __restrict__ src, const int* __restrict__ dst,
                           int* __restrict__ bcur, unsigned long long* __restrict__ ebuf) {
  __shared__ int lh[NBUCK];
  __shared__ int lbase[NBUCK];
  int tid = threadIdx.x;
  for (int i = tid; i < NBUCK; i += 256) lh[i] = 0;
  __syncthreads();
  int base4 = blockIdx.x * 1024;  // int4 units; block covers 4096 edges
  int sv[16], dv[16], rk[16];
#pragma unroll
  for (int j = 0; j < 4; j++) {
    int i4 = base4 + j * 256 + tid;
    if (i4 * 4 < NE) {
      int4 s4 = ((const int4*)src)[i4];
      int4 d4 = ((const int4*)dst)[i4];
      sv[4 * j + 0] = s4.x; dv[4 * j + 0] = d4.x;
      sv[4 * j + 1] = s4.y; dv[4 * j + 1] = d4.y;
      sv[4 * j + 2] = s4.z; dv[4 * j + 2] = d4.z;
      sv[4 * j + 3] = s4.w; dv[4 * j + 3] = d4.w;
      rk[4 * j + 0] = atomicAdd(&lh[d4.x >> 7], 1);
      rk[4 * j + 1] = atomicAdd(&lh[d4.y >> 7], 1);
      rk[4 * j + 2] = atomicAdd(&lh[d4.z >> 7], 1);
      rk[4 * j + 3] = atomicAdd(&lh[d4.w >> 7], 1);
    } else {
      dv[4 * j + 0] = -1; dv[4 * j + 1] = -1;
      dv[4 * j + 2] = -1; dv[4 * j + 3] = -1;
    }
  }
  __syncthreads();
  for (int i = tid; i < NBUCK; i += 256) {
    int v = lh[i];
    lbase[i] = v ? atomicAdd(&bcur[i], v) : 0;
  }
  __syncthreads();
#pragma unroll
  for (int j = 0; j < 16; j++) {
    if (dv[j] >= 0) {
      int b = dv[j] >> 7;
      ebuf[(size_t)b * BCAP + lbase[b] + rk[j]] =
          (unsigned long long)(unsigned)sv[j] | ((unsigned long long)(unsigned)dv[j] << 32);
    }
  }
}

// one block per bucket: local hist -> rc(int2), local scan, LDS-cursor fill -> col
__global__ void k_bucket_csr(const unsigned long long* __restrict__ ebuf,
                             const int* __restrict__ bcur, int2* __restrict__ rc,
                             int* __restrict__ col) {
  __shared__ int ldeg[NPB];
  __shared__ int lcur[NPB];
  __shared__ int sred[NPB];
  int b = blockIdx.x, tid = threadIdx.x;
  int nbase = b * NPB;
  int e0 = b * BCAP;
  int cnt = bcur[b];
  if (tid < NPB) ldeg[tid] = 0;
  __syncthreads();
  for (int e = tid; e < cnt; e += 256) {
    int d = (int)(ebuf[e0 + e] >> 32) - nbase;
    atomicAdd(&ldeg[d], 1);
  }
  __syncthreads();
  if (tid < NPB) sred[tid] = ldeg[tid];
  __syncthreads();
  for (int off = 1; off < NPB; off <<= 1) {
    int v = 0;
    if (tid < NPB && tid >= off) v = sred[tid - off];
    __syncthreads();
    if (tid < NPB) sred[tid] += v;
    __syncthreads();
  }
  if (tid < NPB) {
    int excl = sred[tid] - ldeg[tid];
    lcur[tid] = excl;
    int gn = nbase + tid;
    if (gn < NN) rc[gn] = make_int2(e0 + excl, ldeg[tid]);
  }
  __syncthreads();
  for (int e = tid; e < cnt; e += 256) {
    unsigned long long p = ebuf[e0 + e];
    int s = (int)(unsigned)p;
    int d = (int)(p >> 32) - nbase;
    int r = atomicAdd(&lcur[d], 1);
    col[e0 + r] = s;
  }
}

// ------ mm A: X[nrows,128] @ W[128,64] -> Th (fp16) * dinv[row] ------------------
__global__ __launch_bounds__(512) void k_mmA(const float* __restrict__ X,
                                             const float* __restrict__ W,
                                             const int2* __restrict__ rc,
                                             __half* __restrict__ T, int nrows) {
  __shared__ float xs[64 * 65];
  int tid = threadIdx.x;
  int rbase = blockIdx.x * 64;
  int q8 = __builtin_amdgcn_readfirstlane(tid >> 6);  // wave-uniform col eighth
  int r = tid & 63;
  int r65 = r * 65;
  float4 acc[2];
  acc[0] = {0.f, 0.f, 0.f, 0.f};
  acc[1] = {0.f, 0.f, 0.f, 0.f};

  for (int ch = 0; ch < 2; ch++) {
#pragma unroll
    for (int i = 0; i < 2; i++) {
      int f = i * 512 + tid;
      int rr = f >> 4, kq = f & 15;
      int gr = rbase + rr;
      int grc = gr < nrows ? gr : nrows - 1;
      float4 v = *(const float4*)(X + (size_t)grc * 128 + ch * 64 + 4 * kq);
      float* p = xs + rr * 65 + 4 * kq;
      p[0] = v.x; p[1] = v.y; p[2] = v.z; p[3] = v.w;
    }
    __syncthreads();
    const float* Wb = W + ch * 64 * 64 + q8 * 8;
#pragma unroll 4
    for (int k = 0; k < 64; k++) {
      float xk = xs[r65 + k];
      const float4* wr = (const float4*)(Wb + (size_t)k * 64);
      float4 w0 = wr[0], w1 = wr[1];
      acc[0].x = fmaf(xk, w0.x, acc[0].x);
      acc[0].y = fmaf(xk, w0.y, acc[0].y);
      acc[0].z = fmaf(xk, w0.z, acc[0].z);
      acc[0].w = fmaf(xk, w0.w, acc[0].w);
      acc[1].x = fmaf(xk, w1.x, acc[1].x);
      acc[1].y = fmaf(xk, w1.y, acc[1].y);
      acc[1].z = fmaf(xk, w1.z, acc[1].z);
      acc[1].w = fmaf(xk, w1.w, acc[1].w);
    }
    if (ch == 0) __syncthreads();
  }

  int row = rbase + r;
  if (row < nrows) {
    float dv = rsqrtf((float)rc[row].y + 1.0f);
    __half2 o2[4];
    o2[0] = __floats2half2_rn(acc[0].x * dv, acc[0].y * dv);
    o2[1] = __floats2half2_rn(acc[0].z * dv, acc[0].w * dv);
    o2[2] = __floats2half2_rn(acc[1].x * dv, acc[1].y * dv);
    o2[3] = __floats2half2_rn(acc[1].z * dv, acc[1].w * dv);
    *(float4*)(T + (size_t)row * 64 + q8 * 8) = *(float4*)&o2[0];
  }
}

// ------ mm B: G fp16; BN(G)(+res fp16) -> Hside fp16; Th = (h @ W)*dinv fp16 -----
__global__ __launch_bounds__(512) void k_mmB(const __half* __restrict__ G,
                                             const double* __restrict__ st,
                                             const float* __restrict__ gamma,
                                             const float* __restrict__ beta,
                                             const __half* __restrict__ res,
                                             __half* __restrict__ Hside,
                                             const float* __restrict__ W,
                                             const int2* __restrict__ rc,
                                             __half* __restrict__ T, int nrows) {
  __shared__ float xs[64 * 65];
  __shared__ float scl[128];
  int tid = threadIdx.x;
  if (tid < 64) {
    double m = st[tid] / (double)NN;
    double var = st[64 + tid] / (double)NN - m * m;
    float scale = gamma[tid] * rsqrtf((float)var + EPSF);
    scl[tid] = scale;
    scl[64 + tid] = beta[tid] - (float)m * scale;
  }
  __syncthreads();

  int rbase = blockIdx.x * 64;
  {
    int rr = tid >> 3;   // 0..63 row
    int kc = tid & 7;    // chunk of 8 features
    int gr = rbase + rr;
    int grc = gr < nrows ? gr : nrows - 1;
    int fb = kc * 8;
    float4 raw = *(const float4*)(G + (size_t)grc * 64 + fb);  // 8 halves
    const __half2* hp = (const __half2*)&raw;
    float v[8];
    float2 t0 = __half22float2(hp[0]); v[0] = t0.x; v[1] = t0.y;
    float2 t1 = __half22float2(hp[1]); v[2] = t1.x; v[3] = t1.y;
    float2 t2 = __half22float2(hp[2]); v[4] = t2.x; v[5] = t2.y;
    float2 t3 = __half22float2(hp[3]); v[6] = t3.x; v[7] = t3.y;
#pragma unroll
    for (int j = 0; j < 8; j++) v[j] = v[j] * scl[fb + j] + scl[64 + fb + j];
    if (res != nullptr) {
      float4 rraw = *(const float4*)(res + (size_t)grc * 64 + fb);  // 8 halves
      const __half2* rp = (const __half2*)&rraw;
      float2 a0 = __half22float2(rp[0]); v[0] += a0.x; v[1] += a0.y;
      float2 a1 = __half22float2(rp[1]); v[2] += a1.x; v[3] += a1.y;
      float2 a2 = __half22float2(rp[2]); v[4] += a2.x; v[5] += a2.y;
      float2 a3 = __half22float2(rp[3]); v[6] += a3.x; v[7] += a3.y;
    }
    if (gr < nrows) {
      __half2 hpk[4];
      hpk[0] = __floats2half2_rn(v[0], v[1]);
      hpk[1] = __floats2half2_rn(v[2], v[3]);
      hpk[2] = __floats2half2_rn(v[4], v[5]);
      hpk[3] = __floats2half2_rn(v[6], v[7]);
      *(float4*)(Hside + (size_t)gr * 64 + fb) = *(float4*)hpk;
    }
    float* p = xs + rr * 65 + fb;
#pragma unroll
    for (int j = 0; j < 8; j++) p[j] = v[j];
  }
  __syncthreads();

  int q8 = __builtin_amdgcn_readfirstlane(tid >> 6);
  int r = tid & 63;
  int r65 = r * 65;
  float4 acc[2];
  acc[0] = {0.f, 0.f, 0.f, 0.f};
  acc[1] = {0.f, 0.f, 0.f, 0.f};
  const float* Wb = W + q8 * 8;
#pragma unroll 4
  for (int k = 0; k < 64; k++) {
    float xk = xs[r65 + k];
    const float4* wr = (const float4*)(Wb + (size_t)k * 64);
    float4 w0 = wr[0], w1 = wr[1];
    acc[0].x = fmaf(xk, w0.x, acc[0].x);
    acc[0].y = fmaf(xk, w0.y, acc[0].y);
    acc[0].z = fmaf(xk, w0.z, acc[0].z);
    acc[0].w = fmaf(xk, w0.w, acc[0].w);
    acc[1].x = fmaf(xk, w1.x, acc[1].x);
    acc[1].y = fmaf(xk, w1.y, acc[1].y);
    acc[1].z = fmaf(xk, w1.z, acc[1].z);
    acc[1].w = fmaf(xk, w1.w, acc[1].w);
  }

  int row = rbase + r;
  if (row < nrows) {
    float dv = rsqrtf((float)rc[row].y + 1.0f);
    __half2 o2[4];
    o2[0] = __floats2half2_rn(acc[0].x * dv, acc[0].y * dv);
    o2[1] = __floats2half2_rn(acc[0].z * dv, acc[0].w * dv);
    o2[2] = __floats2half2_rn(acc[1].x * dv, acc[1].y * dv);
    o2[3] = __floats2half2_rn(acc[1].z * dv, acc[1].w * dv);
    *(float4*)(T + (size_t)row * 64 + q8 * 8) = *(float4*)&o2[0];
  }
}

// ---- aggregation: wave/node, 16 feature-lanes x 4 edge-groups, float2 gathers ----
// Th pre-scaled by dinv[row]: o = di*(sum Th[src] + Th[node]) + bias. G out fp16.
// dinv from rc.y; self-row gather hoisted above the edge loop.
__global__ void k_agg64(const __half* __restrict__ T, const int2* __restrict__ rc,
                        const int* __restrict__ col, const float* __restrict__ bias,
                        __half* __restrict__ G, int relu) {
  int lane = threadIdx.x & 63;
  int wv = threadIdx.x >> 6;
  int node = blockIdx.x * 4 + wv;
  if (node >= NN) return;
  int grp = lane >> 4;
  int q = lane & 15;
  int2 sc = rc[node];
  int s = sc.x;
  int c = sc.y;
  float di = rsqrtf((float)c + 1.0f);
  float2 rs = *(const float2*)(T + (size_t)node * 64 + q * 4);  // self row, early
  float4 acc = {0.f, 0.f, 0.f, 0.f};
  for (int i = 0; i < c; i += 16) {
    int j0 = i + grp, j1 = j0 + 4, j2 = j0 + 8, j3 = j0 + 12;
    int s0 = col[s + (j0 < c ? j0 : 0)];
    int s1 = col[s + (j1 < c ? j1 : 0)];
    int s2 = col[s + (j2 < c ? j2 : 0)];
    int s3 = col[s + (j3 < c ? j3 : 0)];
    float2 r0 = *(const float2*)(T + (size_t)s0 * 64 + q * 4);
    float2 r1 = *(const float2*)(T + (size_t)s1 * 64 + q * 4);
    float2 r2 = *(const float2*)(T + (size_t)s2 * 64 + q * 4);
    float2 r3 = *(const float2*)(T + (size_t)s3 * 64 + q * 4);
    float w0 = j0 < c ? 1.f : 0.f;
    float w1 = j1 < c ? 1.f : 0.f;
    float w2 = j2 < c ? 1.f : 0.f;
    float w3 = j3 < c ? 1.f : 0.f;
    {
      __half2* p = (__half2*)&r0;
      float2 lo = __half22float2(p[0]), hi = __half22float2(p[1]);
      acc.x = fmaf(w0, lo.x, acc.x); acc.y = fmaf(w0, lo.y, acc.y);
      acc.z = fmaf(w0, hi.x, acc.z); acc.w = fmaf(w0, hi.y, acc.w);
    }
    {
      __half2* p = (__half2*)&r1;
      float2 lo = __half22float2(p[0]), hi = __half22float2(p[1]);
      acc.x = fmaf(w1, lo.x, acc.x); acc.y = fmaf(w1, lo.y, acc.y);
      acc.z = fmaf(w1, hi.x, acc.z); acc.w = fmaf(w1, hi.y, acc.w);
    }
    {
      __half2* p = (__half2*)&r2;
      float2 lo = __half22float2(p[0]), hi = __half22float2(p[1]);
      acc.x = fmaf(w2, lo.x, acc.x); acc.y = fmaf(w2, lo.y, acc.y);
      acc.z = fmaf(w2, hi.x, acc.z); acc.w = fmaf(w2, hi.y, acc.w);
    }
    {
      __half2* p = (__half2*)&r3;
      float2 lo = __half22float2(p[0]), hi = __half22float2(p[1]);
      acc.x = fmaf(w3, lo.x, acc.x); acc.y = fmaf(w3, lo.y, acc.y);
      acc.z = fmaf(w3, hi.x, acc.z); acc.w = fmaf(w3, hi.y, acc.w);
    }
  }
  acc.x += __shfl_xor(acc.x, 16, 64);
  acc.y += __shfl_xor(acc.y, 16, 64);
  acc.z += __shfl_xor(acc.z, 16, 64);
  acc.w += __shfl_xor(acc.w, 16, 64);
  acc.x += __shfl_xor(acc.x, 32, 64);
  acc.y += __shfl_xor(acc.y, 32, 64);
  acc.z += __shfl_xor(acc.z, 32, 64);
  acc.w += __shfl_xor(acc.w, 32, 64);
  if (grp == 0) {
    __half2* p = (__half2*)&rs;
    float2 lo = __half22float2(p[0]), hi = __half22float2(p[1]);
    float4 bs = ((const float4*)bias)[q];
    float4 o;
    o.x = (acc.x + lo.x) * di + bs.x;
    o.y = (acc.y + lo.y) * di + bs.y;
    o.z = (acc.z + hi.x) * di + bs.z;
    o.w = (acc.w + hi.y) * di + bs.w;
    if (relu) {
      o.x = fmaxf(o.x, 0.f);
      o.y = fmaxf(o.y, 0.f);
      o.z = fmaxf(o.z, 0.f);
      o.w = fmaxf(o.w, 0.f);
    }
    float2 pk;
    ((__half2*)&pk)[0] = __floats2half2_rn(o.x, o.y);
    ((__half2*)&pk)[1] = __floats2half2_rn(o.z, o.w);
    *(float2*)(G + (size_t)node * 64 + q * 4) = pk;
  }
}

// ---------------- BN stats (fp16 input, fp32 accum, f64 atomics) ----------------
__global__ __launch_bounds__(256) void k_stats(const __half* __restrict__ H,
                                               double* __restrict__ st) {
  int q = threadIdx.x & 15;   // feature quarter (4 halves)
  int rg = threadIdx.x >> 4;  // 16 row-groups per block
  float4 s1 = {0.f, 0.f, 0.f, 0.f};
  float4 s2 = {0.f, 0.f, 0.f, 0.f};
  for (int r = blockIdx.x * 16 + rg; r < NN; r += gridDim.x * 16) {
    float2 raw = *(const float2*)(H + (size_t)r * 64 + q * 4);
    const __half2* hp = (const __half2*)&raw;
    float2 lo = __half22float2(hp[0]), hi = __half22float2(hp[1]);
    s1.x += lo.x; s1.y += lo.y; s1.z += hi.x; s1.w += hi.y;
    s2.x = fmaf(lo.x, lo.x, s2.x); s2.y = fmaf(lo.y, lo.y, s2.y);
    s2.z = fmaf(hi.x, hi.x, s2.z); s2.w = fmaf(hi.y, hi.y, s2.w);
  }
  __shared__ float a[16][16][8];
  a[rg][q][0] = s1.x; a[rg][q][1] = s1.y; a[rg][q][2] = s1.z; a[rg][q][3] = s1.w;
  a[rg][q][4] = s2.x; a[rg][q][5] = s2.y; a[rg][q][6] = s2.z; a[rg][q][7] = s2.w;
  __syncthreads();
  int tid = threadIdx.x;
  if (tid < 128) {
    int f = tid & 63;        // feature
    int which = tid >> 6;    // 0 = sum, 1 = sumsq
    int qq = f >> 2, jj = (f & 3) + which * 4;
    float t = 0.f;
#pragma unroll
    for (int g = 0; g < 16; g++) t += a[g][qq][jj];
    unsafeAtomicAdd(&st[which * 64 + f], (double)t);
  }
}

// ------- fused: BN3 (G fp16) + residual (fp16) + matmul 64->2, T2 *= dinv --------
__global__ void k_bnmmout(const __half* __restrict__ G, const double* __restrict__ st,
                          const float* __restrict__ gamma, const float* __restrict__ beta,
                          const __half* __restrict__ res, const float* __restrict__ W,
                          const int2* __restrict__ rc, float* __restrict__ T2,
                          int nrows) {
  __shared__ float Wl[128];
  __shared__ float scl[128];
  int tid = threadIdx.x;
  if (tid < 32) ((float4*)Wl)[tid] = ((const float4*)W)[tid];
  else if (tid >= 64 && tid < 128) {
    int f = tid - 64;
    double m = st[f] / (double)NN;
    double var = st[64 + f] / (double)NN - m * m;
    float scale = gamma[f] * rsqrtf((float)var + EPSF);
    scl[f] = scale;
    scl[64 + f] = beta[f] - (float)m * scale;
  }
  __syncthreads();
  int row = blockIdx.x * 256 + tid;
  if (row >= nrows) return;
  const __half* g = G + (size_t)row * 64;
  const __half* rr = res + (size_t)row * 64;
  float a0 = 0.f, a1 = 0.f;
#pragma unroll
  for (int qq = 0; qq < 8; qq++) {
    int fb = qq * 8;
    float4 graw = *(const float4*)(g + fb);   // 8 halves
    float4 rraw = *(const float4*)(rr + fb);  // 8 halves
    const __half2* gp = (const __half2*)&graw;
    const __half2* rp = (const __half2*)&rraw;
    float gv[8], rv[8];
    float2 t0 = __half22float2(gp[0]); gv[0] = t0.x; gv[1] = t0.y;
    float2 t1 = __half22float2(gp[1]); gv[2] = t1.x; gv[3] = t1.y;
    float2 t2 = __half22float2(gp[2]); gv[4] = t2.x; gv[5] = t2.y;
    float2 t3 = __half22float2(gp[3]); gv[6] = t3.x; gv[7] = t3.y;
    float2 u0 = __half22float2(rp[0]); rv[0] = u0.x; rv[1] = u0.y;
    float2 u1 = __half22float2(rp[1]); rv[2] = u1.x; rv[3] = u1.y;
    float2 u2 = __half22float2(rp[2]); rv[4] = u2.x; rv[5] = u2.y;
    float2 u3 = __half22float2(rp[3]); rv[6] = u3.x; rv[7] = u3.y;
#pragma unroll
    for (int j = 0; j < 8; j++) {
      float h = gv[j] * scl[fb + j] + scl[64 + fb + j] + rv[j];
      a0 = fmaf(h, Wl[(fb + j) * 2 + 0], a0);
      a1 = fmaf(h, Wl[(fb + j) * 2 + 1], a1);
    }
  }
  float dv = rsqrtf((float)rc[row].y + 1.0f);
  T2[(size_t)row * 2 + 0] = a0 * dv;
  T2[(size_t)row * 2 + 1] = a1 * dv;
}

// ---- fused final aggregation (dim 2, T2 pre-scaled) + pool + ticket finalize ----
__global__ void k_agg2pool(const float* __restrict__ T2, const int2* __restrict__ rc,
                           const int* __restrict__ col, const float* __restrict__ bias,
                           const int* __restrict__ batch, float* __restrict__ pool,
                           int* __restrict__ pcnt, int* __restrict__ tick,
                           float* __restrict__ out, int nblk) {
  __shared__ float pl[128];
  __shared__ int pc[64];
  __shared__ int lastflag;
  int tid = threadIdx.x;
  if (tid < 128) pl[tid] = 0.f;
  if (tid < 64) pc[tid] = 0;
  __syncthreads();
  int node = blockIdx.x * 256 + tid;
  if (node < NN) {
    int2 sc = rc[node];
    int s = sc.x;
    int c = sc.y;
    float a0 = 0.f, a1 = 0.f;
    for (int i = 0; i < c; i += 4) {
      int j0 = i, j1 = i + 1, j2 = i + 2, j3 = i + 3;
      int s0 = col[s + j0];
      int sA = col[s + (j1 < c ? j1 : j0)];
      int sB = col[s + (j2 < c ? j2 : j0)];
      int sC = col[s + (j3 < c ? j3 : j0)];
      float2 t0 = *(const float2*)(T2 + 2 * (size_t)s0);
      float2 t1 = *(const float2*)(T2 + 2 * (size_t)sA);
      float2 t2 = *(const float2*)(T2 + 2 * (size_t)sB);
      float2 t3 = *(const float2*)(T2 + 2 * (size_t)sC);
      float w1 = j1 < c ? 1.f : 0.f;
      float w2 = j2 < c ? 1.f : 0.f;
      float w3 = j3 < c ? 1.f : 0.f;
      a0 += t0.x; a1 += t0.y;
      a0 = fmaf(w1, t1.x, a0); a1 = fmaf(w1, t1.y, a1);
      a0 = fmaf(w2, t2.x, a0); a1 = fmaf(w2, t2.y, a1);
      a0 = fmaf(w3, t3.x, a0); a1 = fmaf(w3, t3.y, a1);
    }
    float di = rsqrtf((float)c + 1.0f);
    float2 tn = *(const float2*)(T2 + 2 * (size_t)node);
    float v0 = (a0 + tn.x) * di + bias[0];
    float v1 = (a1 + tn.y) * di + bias[1];
    int bb = batch[node];
    atomicAdd(&pl[bb * 2 + 0], v0);
    atomicAdd(&pl[bb * 2 + 1], v1);
    atomicAdd(&pc[bb], 1);
  }
  __syncthreads();
  if (tid < 128 && pl[tid] != 0.f) unsafeAtomicAdd(&pool[tid], pl[tid]);
  if (tid < 64 && pc[tid] != 0) atomicAdd(&pcnt[tid], pc[tid]);
  __syncthreads();
  if (tid == 0) {
    __threadfence();
    int old = atomicAdd(tick, 1);
    lastflag = (old == nblk - 1) ? 1 : 0;
  }
  __syncthreads();
  if (lastflag && tid < 128) {
    float v = unsafeAtomicAdd(&pool[tid], 0.f);       // coherent read
    int c = atomicAdd(&pcnt[tid >> 1], 0);            // coherent read
    out[tid] = v / (float)(c > 0 ? c : 1);
  }
}

extern "C" void kernel_launch(void* const* d_in, const int* in_sizes, int n_in,
                              void* d_out, int out_size, void* d_ws, size_t ws_size,
                              hipStream_t stream) {
  (void)in_sizes; (void)n_in; (void)out_size; (void)ws_size;
  const float* x     = (const float*)d_in[0];
  const float* W_in  = (const float*)d_in[1];
  const float* b_in  = (const float*)d_in[2];
  const float* W_h   = (const float*)d_in[3];
  const float* b_h   = (const float*)d_in[4];
  const float* W_out = (const float*)d_in[5];
  const float* b_out = (const float*)d_in[6];
  const float* gamma = (const float*)d_in[7];
  const float* beta  = (const float*)d_in[8];
  const int*   ei    = (const int*)d_in[9];
  const int*   batch = (const int*)d_in[10];
  const int* src = ei;
  const int* dst = ei + NE;
  float* out = (float*)d_out;

  char* w = (char*)d_ws;
  size_t off = 0;
  auto alloc = [&](size_t bytes) -> void* {
    void* p = (void*)(w + off);
    off += (bytes + 511) & ~(size_t)511;
    return p;
  };
  int2*   rc    = (int2*)alloc((size_t)NN * 8);
  int*    col   = (int*)alloc((size_t)NBUCK * BCAP * 4);   // slotted, 6.4 MB
  // zeroed zone: stats (3*128 dbl = 3072) | pool (512) | pcnt (256) | tick (256) |
  //              bcur (782*4 = 3128) -> 7224 bytes
  char*   zzone = (char*)alloc(7680);
  double* stats = (double*)zzone;
  float*  pool  = (float*)(zzone + 3072);
  int*    pcnt  = (int*)(zzone + 3584);
  int*    tick  = (int*)(zzone + 3840);
  int*    bcur  = (int*)(zzone + 4096);
  __half* Ga    = (__half*)alloc((size_t)NN * HID * 2);   // G1 / G3
  __half* Gb    = (__half*)alloc((size_t)NN * HID * 2);   // G2
  __half* hA    = (__half*)alloc((size_t)NN * HID * 2);   // h1 (fp16)
  __half* hB    = (__half*)alloc((size_t)NN * HID * 2);   // h2 (fp16)
  __half* Th    = (__half*)alloc((size_t)NN * HID * 2);
  float*  T2    = (float*)alloc((size_t)NN * 2 * 4);
  // ebuf (slotted, 782*2048*8 = 12.81MB) aliases hA (12.80MB) + 12KB spill into
  // hB: consumed by k_bucket_csr (step 2); hA first written step 6, hB step 8
  unsigned long long* ebuf = (unsigned long long*)hA;

  hipMemsetAsync(zzone, 0, 7424, stream);

  // graph prep: slotted bucket-radix CSR build (no histogram/scan passes)
  k_escatter<<<293, 256, 0, stream>>>(src, dst, bcur, ebuf);
  k_bucket_csr<<<NBUCK, 256, 0, stream>>>(ebuf, bcur, rc, col);

  const int mmgrid = (NN + 63) / 64;   // 1563

  // layer 1: x(128) -> Th (fp16, pre-scaled) -> G1=Ga (fp16)
  k_mmA<<<mmgrid, 512, 0, stream>>>(x, W_in, rc, Th, NN);
  k_agg64<<<(NN + 3) / 4, 256, 0, stream>>>(Th, rc, col, b_in, Ga, 1);
  k_stats<<<512, 256, 0, stream>>>(Ga, stats);

  // layer 2: h1 = BN1(G1) (fp16 side-> hA); Th = h1@W_h0; G2 = Gb
  k_mmB<<<mmgrid, 512, 0, stream>>>(Ga, stats, gamma, beta, nullptr, hA, W_h,
                                    rc, Th, NN);
  k_agg64<<<(NN + 3) / 4, 256, 0, stream>>>(Th, rc, col, b_h, Gb, 1);
  k_stats<<<512, 256, 0, stream>>>(Gb, stats + 128);

  // layer 3: h2 = BN2(G2)+h1 (fp16 side-> hB); Th = h2@W_h1; G3 = Ga (G1 dead)
  k_mmB<<<mmgrid, 512, 0, stream>>>(Gb, stats + 128, gamma + 64, beta + 64, hA,
                                    hB, W_h + HID * HID, rc, Th, NN);
  k_agg64<<<(NN + 3) / 4, 256, 0, stream>>>(Th, rc, col, b_h + HID, Ga, 1);
  k_stats<<<512, 256, 0, stream>>>(Ga, stats + 256);

  // output: h3 = BN3(G3)+h2(hB) fused with mm 64->2 (T2 pre-scaled), then agg+pool+div
  k_bnmmout<<<(NN + 255) / 256, 256, 0, stream>>>(Ga, stats + 256, gamma + 128,
                                                  beta + 128, hB, W_out, rc, T2, NN);
  const int pgrid = (NN + 255) / 256;  // 391
  k_agg2pool<<<pgrid, 256, 0, stream>>>(T2, rc, col, b_out, batch, pool,
                                        pcnt, tick, out, pgrid);
}